// Round 1
// baseline (428.455 us; speedup 1.0000x reference)
//
#include <hip/hip_runtime.h>
#include <hip/hip_bf16.h>
#include <hip/hip_cooperative_groups.h>

namespace cg = cooperative_groups;

// B=32, K=64, D=256, LS=128, rows = 2048
// R13: fuse k1l0+k23+k41+k23+k4_fin+k5 into ONE cooperative kernel (6 grid syncs).
//      Removes 5 kernel-boundary drains + k41's duplicated k4_core (parity trick).
//      prep stays a separate launch (64 KB LDS body, verified as-is).

using bf16 = __hip_bfloat16;
typedef short bf16x8 __attribute__((ext_vector_type(8)));
typedef float f32x4 __attribute__((ext_vector_type(4)));

__device__ __forceinline__ float bfu(unsigned short u) { return __uint_as_float(((unsigned)u) << 16); }

__device__ __forceinline__ unsigned short bfr(float v) {   // RNE fp32->bf16 bits
  unsigned u = __float_as_uint(v);
  u += 0x7FFFu + ((u >> 16) & 1u);
  return (unsigned short)(u >> 16);
}

__device__ __forceinline__ float gelu_e(float x) {
  return 0.5f * x * (1.0f + erff(x * 0.7071067811865475f));
}

__device__ __forceinline__ float load_f(const void* p, int i, int fl) {
  if (fl) return bfu(((const unsigned short*)p)[i]);
  return ((const float*)p)[i];
}

// per-block inline dtype detect: 1 = inputs are bf16
__device__ __forceinline__ int block_detect(const void* X) {
  __shared__ int bad_s;
  if (threadIdx.x == 0) bad_s = 0;
  __syncthreads();
  if (threadIdx.x < 256) {
    const float v = bfu(((const unsigned short*)X)[threadIdx.x]);
    if (!(fabsf(v) < 1e6f)) atomicOr(&bad_s, 1);
  }
  __syncthreads();
  return bad_s ? 0 : 1;
}

// stage one float4 (row, d0) into hi/lo MFMA A-fragments
__device__ __forceinline__ void stage_split4(unsigned short (&aF)[2][4096], int row, int d0, float4 v) {
  ushort4 h, lo;
  h.x = bfr(v.x); h.y = bfr(v.y); h.z = bfr(v.z); h.w = bfr(v.w);
  lo.x = bfr(v.x - bfu(h.x)); lo.y = bfr(v.y - bfu(h.y));
  lo.z = bfr(v.z - bfu(h.z)); lo.w = bfr(v.w - bfu(h.w));
  const int kt = d0 >> 5, lane = row | (((d0 >> 3) & 3) << 4), j = d0 & 7;
  *(ushort4*)&aF[0][kt*512 + lane*8 + j] = h;
  *(ushort4*)&aF[1][kt*512 + lane*8 + j] = lo;
}

// ---------------------------------------------------------------------------
// prep (89 blocks x 256 thr): weights -> ws   [unchanged from R9/R12]
// ---------------------------------------------------------------------------
__global__ __launch_bounds__(256) void prep_kernel(
    const void* __restrict__ X, const void* __restrict__ kw, const void* __restrict__ qw,
    const void* __restrict__ rw1, const void* __restrict__ rw2, const void* __restrict__ mw1,
    const void* __restrict__ mw2, const void* __restrict__ pw, const void* __restrict__ muw,
    const void* __restrict__ spw,
    const void* __restrict__ rb1, const void* __restrict__ rb2, const void* __restrict__ lng,
    const void* __restrict__ lnb, const void* __restrict__ mb1, const void* __restrict__ mb2,
    const void* __restrict__ pb, const void* __restrict__ mub, const void* __restrict__ spb,
    unsigned short* __restrict__ wfb, unsigned short* __restrict__ w3b,
    float* __restrict__ wh, float* __restrict__ bc)
{
  __shared__ __align__(16) char psm[65536];
  const int fl = block_detect(X);
  const int t = threadIdx.x;
  int blk = blockIdx.x;

  if (blk < 16) {   // ---- A: wfb (l,kt)
    unsigned short* ls = (unsigned short*)psm;
    unsigned* lsu = (unsigned*)psm;
    const int l = blk >> 3, kt = blk & 7;
    if (fl) {
      #pragma unroll
      for (int s = 0; s < 4; ++s) {
        const unsigned* sp = (const unsigned*)((s == 0) ? kw : (s == 1) ? qw : rw1);
        const int rstr = (s < 2) ? 128 : 256;
        const int coff = ((s == 3) ? 128 : 0) + kt*16;
        for (int i = t; i < 4096; i += 256) {
          const int e = i >> 4, d2 = i & 15;
          lsu[s*4096 + i] = sp[(l*256 + e)*rstr + coff + d2];
        }
      }
    } else {
      #pragma unroll
      for (int s = 0; s < 4; ++s) {
        const float* sp = (const float*)((s == 0) ? kw : (s == 1) ? qw : rw1);
        const int rstr = (s < 2) ? 256 : 512;
        const int coff = ((s == 3) ? 256 : 0) + kt*32;
        for (int i = t; i < 4096; i += 256) {
          const int e = i >> 4, d2 = i & 15;
          const float f0 = sp[(l*256 + e)*rstr + coff + d2*2];
          const float f1 = sp[(l*256 + e)*rstr + coff + d2*2 + 1];
          lsu[s*4096 + i] = (unsigned)bfr(f0) | ((unsigned)bfr(f1) << 16);
        }
      }
    }
    __syncthreads();
    unsigned* outp = (unsigned*)wfb + (l*8 + kt)*16384;
    for (int f2 = t; f2 < 16384; f2 += 256) {
      const int j2 = f2 & 3, lane = (f2 >> 2) & 63, ntg = f2 >> 8;
      const int seg = ntg >> 4;
      const int e = (ntg & 15)*16 + (lane & 15);
      const int dl = ((lane >> 4) & 3)*8 + j2*2;
      unsigned short r0 = ls[seg*8192 + e*32 + dl];
      unsigned short r1 = ls[seg*8192 + e*32 + dl + 1];
      if (seg == 1) { r0 = bfr(bfu(r0)*0.0625f); r1 = bfr(bfu(r1)*0.0625f); }
      else if (seg == 2) {
        const unsigned short w0 = ls[3*8192 + e*32 + dl];
        const unsigned short w1 = ls[3*8192 + e*32 + dl + 1];
        r0 = bfr(bfu(r0) + bfu(w0)); r1 = bfr(bfu(r1) + bfu(w1));
      }
      outp[f2] = (unsigned)r0 | ((unsigned)r1 << 16);
    }
    return;
  }
  blk -= 16;
  if (blk < 48) {   // ---- B: w3b (l,gm,kt)
    unsigned short* ls = (unsigned short*)psm;
    unsigned* lsu = (unsigned*)psm;
    const int l3 = blk >> 3, kt = blk & 7;
    const int l = l3 / 3, gm = l3 % 3;
    const void* src = (gm == 0) ? rw2 : (gm == 1) ? mw1 : mw2;
    if (fl) {
      const unsigned* sp = (const unsigned*)src;
      for (int i = t; i < 4096; i += 256) {
        const int e = i >> 4, d2 = i & 15;
        lsu[i] = sp[(l*256 + e)*128 + kt*16 + d2];
      }
    } else {
      const float* sp = (const float*)src;
      for (int i = t; i < 4096; i += 256) {
        const int e = i >> 4, d2 = i & 15;
        const float f0 = sp[(l*256 + e)*256 + kt*32 + d2*2];
        const float f1 = sp[(l*256 + e)*256 + kt*32 + d2*2 + 1];
        lsu[i] = (unsigned)bfr(f0) | ((unsigned)bfr(f1) << 16);
      }
    }
    __syncthreads();
    unsigned* outp = (unsigned*)w3b + (l3*8 + kt)*4096;
    for (int f2 = t; f2 < 4096; f2 += 256) {
      const int j2 = f2 & 3, lane = (f2 >> 2) & 63, nt = f2 >> 8;
      const int e = nt*16 + (lane & 15);
      const int dl = ((lane >> 4) & 3)*8 + j2*2;
      outp[f2] = (unsigned)ls[e*32 + dl] | ((unsigned)ls[e*32 + dl + 1] << 16);
    }
    return;
  }
  blk -= 48;
  if (blk < 24) {   // ---- D: wh transposes
    float* lsf = (float*)psm;
    if (blk < 8) {          // projT
      const int l0 = blk*16;
      if (fl) {
        const unsigned* sp = (const unsigned*)pw;
        for (int i = t; i < 2048; i += 256) {
          const int ll = i >> 7, d2 = i & 127;
          const unsigned u = sp[(l0 + ll)*128 + d2];
          lsf[ll*256 + d2*2]     = __uint_as_float(u << 16);
          lsf[ll*256 + d2*2 + 1] = __uint_as_float(u & 0xffff0000u);
        }
      } else {
        const float* sp = (const float*)pw;
        for (int i = t; i < 4096; i += 256) {
          const int ll = i >> 8, d = i & 255;
          lsf[ll*256 + d] = sp[(l0 + ll)*256 + d];
        }
      }
      __syncthreads();
      for (int i = t; i < 4096; i += 256) {
        const int d = i >> 4, ll = i & 15;
        wh[d*128 + l0 + ll] = lsf[ll*256 + d];
      }
    } else {                // muT / spT
      const int grp2 = blk - 8;
      const int isSp = grp2 >> 3;
      const int l0 = (grp2 & 7)*16;
      const void* src = isSp ? spw : muw;
      const int off = isSp ? 49152 : 32768;
      if (fl) {
        const unsigned* sp = (const unsigned*)src;
        for (int i = t; i < 1024; i += 256) {
          const int ll = i >> 6, c2 = i & 63;
          const unsigned u = sp[(l0 + ll)*64 + c2];
          lsf[ll*128 + c2*2]     = __uint_as_float(u << 16);
          lsf[ll*128 + c2*2 + 1] = __uint_as_float(u & 0xffff0000u);
        }
      } else {
        const float* sp = (const float*)src;
        for (int i = t; i < 2048; i += 256) {
          const int ll = i >> 7, c = i & 127;
          lsf[ll*128 + c] = sp[(l0 + ll)*128 + c];
        }
      }
      __syncthreads();
      for (int i = t; i < 2048; i += 256) {
        const int c = i >> 4, ll = i & 15;
        wh[off + c*128 + l0 + ll] = lsf[ll*128 + c];
      }
    }
    return;
  }
  // ---- E: bc
  for (int i = t; i < 3456; i += 256) {
    const void* src; int off;
    if (i < 512)       { src = rb1; off = i; }
    else if (i < 1024) { src = rb2; off = i - 512; }
    else if (i < 1536) { src = lng; off = i - 1024; }
    else if (i < 2048) { src = lnb; off = i - 1536; }
    else if (i < 2560) { src = mb1; off = i - 2048; }
    else if (i < 3072) { src = mb2; off = i - 2560; }
    else if (i < 3200) { src = pb;  off = i - 3072; }
    else if (i < 3328) { src = mub; off = i - 3200; }
    else               { src = spb; off = i - 3328; }
    bc[i] = load_f(src, off, fl);
  }
}

// ---------------------------------------------------------------------------
// k1 body: 16 rows x (waves*NTG*16) cols from staged A-frags
// (with 512 threads: w in 0..7, so one block covers 32 ntg; ntg0 in {0,32})
// ---------------------------------------------------------------------------
template<bool SPLIT, int NTG>
__device__ __forceinline__ void k1_body(
    const unsigned short (&aF)[2][4096],
    const unsigned short* __restrict__ wfb, const float* __restrict__ bc,
    float* __restrict__ kq, float* __restrict__ Pf, unsigned* __restrict__ Qpk,
    int l, int row0, int ntg0, int t)
{
  const int w = t >> 6, l64 = t & 63;
  const int col = l64 & 15, quad = l64 >> 4;
  f32x4 acc[NTG];
  #pragma unroll
  for (int i = 0; i < NTG; ++i) acc[i] = (f32x4){0.f, 0.f, 0.f, 0.f};
  for (int kt = 0; kt < 8; ++kt) {
    const bf16x8 ah = *(const bf16x8*)&aF[0][kt*512 + l64*8];
    bf16x8 al;
    if (SPLIT) al = *(const bf16x8*)&aF[1][kt*512 + l64*8];
    #pragma unroll
    for (int i = 0; i < NTG; ++i) {
      const int ntg = ntg0 + w*NTG + i;
      const bf16x8 b = *(const bf16x8*)&wfb[((l*8 + kt)*64 + ntg)*512 + l64*8];
      acc[i] = __builtin_amdgcn_mfma_f32_16x16x32_bf16(ah, b, acc[i], 0, 0, 0);
      if (SPLIT) acc[i] = __builtin_amdgcn_mfma_f32_16x16x32_bf16(al, b, acc[i], 0, 0, 0);
    }
  }
  #pragma unroll
  for (int i = 0; i < NTG; ++i) {
    const int ntg = ntg0 + w*NTG + i;
    if (ntg < 32) {
      const int n = ntg*16 + col;
      #pragma unroll
      for (int r = 0; r < 4; ++r)
        kq[(size_t)(row0 + quad*4 + r)*512 + n] = acc[i][r];
    } else if (ntg < 48) {
      const int c = (ntg - 32)*16 + col;
      const float bias = bc[l*256 + c];
      #pragma unroll
      for (int r = 0; r < 4; ++r)
        Pf[(size_t)(row0 + quad*4 + r)*256 + c] = acc[i][r] + bias;
    } else {
      #pragma unroll
      for (int r = 0; r < 4; ++r) {
        const float v = acc[i][r];
        const float pv = __shfl_xor(v, 1, 64);
        if (!(col & 1)) {
          const unsigned uu = (unsigned)bfr(v) | ((unsigned)bfr(pv) << 16);
          Qpk[(size_t)(row0 + quad*4 + r)*128 + (ntg - 48)*8 + (col >> 1)] = uu;
        }
      }
    }
  }
}

// ---------------------------------------------------------------------------
// k23 phase: fused scores + softmax + gelu-weighted aggregation.
// 512-thread block = 2 concurrent 256-thread halves x 2 iterations
// -> 4 (b, i-pair) units per block; 256 blocks cover all 1024 units.
// ---------------------------------------------------------------------------
__device__ __forceinline__ void k23_phase(
    const float* __restrict__ kq, const float* __restrict__ Pf,
    const unsigned* __restrict__ Qpk, float* __restrict__ g,
    int bid, int t,
    float (&qs)[2][2][256], float (&scp)[2][2][64], float (&als)[2][2][64])
{
  const int half = t >> 8, tt = t & 255;
  for (int it = 0; it < 2; ++it) {
    __syncthreads();                       // protect qs/als reuse across iterations
    const int unit = (bid << 2) | (half << 1) | it;
    const int b = unit >> 5, ip = unit & 31;
    const int base = b << 6, i0 = ip * 2;
    for (int i = tt; i < 512; i += 256)
      qs[half][i >> 8][i & 255] = kq[(size_t)(base + i0 + (i >> 8))*512 + 256 + (i & 255)];
    __syncthreads();
    {
      const int w = tt >> 6, lane = t & 63;
      const int jl = lane & 15, part = lane >> 4;
      const int j = w*16 + jl;
      const float* krow = kq + (size_t)(base + j)*512 + part*64;
      const float* q0p = &qs[half][0][part*64];
      const float* q1p = &qs[half][1][part*64];
      float s0 = 0.f, s1 = 0.f;
      for (int dd = 0; dd < 64; dd += 4) {
        const float4 kv = *(const float4*)&krow[dd];
        const float4 q0 = *(const float4*)&q0p[dd];
        const float4 q1 = *(const float4*)&q1p[dd];
        s0 = fmaf(kv.x, q0.x, s0); s0 = fmaf(kv.y, q0.y, s0);
        s0 = fmaf(kv.z, q0.z, s0); s0 = fmaf(kv.w, q0.w, s0);
        s1 = fmaf(kv.x, q1.x, s1); s1 = fmaf(kv.y, q1.y, s1);
        s1 = fmaf(kv.z, q1.z, s1); s1 = fmaf(kv.w, q1.w, s1);
      }
      s0 += __shfl_xor(s0, 16, 64); s0 += __shfl_xor(s0, 32, 64);
      s1 += __shfl_xor(s1, 16, 64); s1 += __shfl_xor(s1, 32, 64);
      if (part == 0) { scp[half][0][j] = s0; scp[half][1][j] = s1; }
    }
    __syncthreads();
    if (tt < 128) {
      const int row = tt >> 6, j = t & 63;
      float s = scp[half][row][j];
      float m = s;
      #pragma unroll
      for (int off = 32; off; off >>= 1) m = fmaxf(m, __shfl_xor(m, off, 64));
      const float e = __expf(s - m);
      float ss = e;
      #pragma unroll
      for (int off = 32; off; off >>= 1) ss += __shfl_xor(ss, off, 64);
      als[half][row][j] = e / ss;
    }
    __syncthreads();
    {
      const int rg = tt >> 7, cp = tt & 127;
      const int r = base + i0 + rg;
      const float2 P = *(const float2*)&Pf[(size_t)r*256 + cp*2];
      const float A0 = -1.702f * P.x, A1 = -1.702f * P.y;
      const float* ap = &als[half][rg][0];
      const unsigned* qp = Qpk + (size_t)base*128 + cp;
      float acc0 = 0.f, acc1 = 0.f;
      #pragma unroll 8
      for (int j = 0; j < 64; ++j) {
        const unsigned u = qp[j*128];
        const float wgt = ap[j];
        const float q0 = __uint_as_float(u << 16);
        const float q1 = __uint_as_float(u & 0xffff0000u);
        const float s0 = __builtin_amdgcn_rcpf(1.f + __expf(fmaf(1.702f, q0, A0)));
        const float s1 = __builtin_amdgcn_rcpf(1.f + __expf(fmaf(1.702f, q1, A1)));
        acc0 = fmaf(wgt * (P.x - q0), s0, acc0);
        acc1 = fmaf(wgt * (P.y - q1), s1, acc1);
      }
      *(float2*)&g[(size_t)r*256 + cp*2] = make_float2(acc0, acc1);
    }
  }
}

// ---------------------------------------------------------------------------
// k4 core (512 thr): agg=g@rw2^T+rb2; h=LN(xin+agg); out=xin+mlp(h)
// ---------------------------------------------------------------------------
__device__ __forceinline__ void k4_gemm8(
    f32x4 acc[2], const unsigned short (&aF)[2][4096],
    const unsigned short* __restrict__ wg, int w, int l64)
{
  acc[0] = (f32x4){0.f, 0.f, 0.f, 0.f};
  acc[1] = (f32x4){0.f, 0.f, 0.f, 0.f};
  for (int kt = 0; kt < 8; ++kt) {
    const bf16x8 ah = *(const bf16x8*)&aF[0][kt*512 + l64*8];
    const bf16x8 al = *(const bf16x8*)&aF[1][kt*512 + l64*8];
    #pragma unroll
    for (int nt = 0; nt < 2; ++nt) {
      const bf16x8 b = *(const bf16x8*)&wg[((kt*16 + (w*2 + nt))*64 + l64)*8];
      acc[nt] = __builtin_amdgcn_mfma_f32_16x16x32_bf16(ah, b, acc[nt], 0, 0, 0);
      acc[nt] = __builtin_amdgcn_mfma_f32_16x16x32_bf16(al, b, acc[nt], 0, 0, 0);
    }
  }
}

template<bool ADAPT, bool TAIL, int NR>
__device__ __forceinline__ void k4_core(
    const float* __restrict__ g, const void* __restrict__ xin, int fl,
    float* __restrict__ xout, const unsigned short* __restrict__ wg,
    const float* __restrict__ bc, int l, int row0, int t, bool writeX,
    unsigned short (&aF)[2][4096], float* bufB, float (&mv)[16][2])
{
  const int w = t >> 6, l64 = t & 63;
  const int col = l64 & 15, quad = l64 >> 4;
  const float* rb2c = bc + 512  + l*256;
  const float* lngc = bc + 1024 + l*256;
  const float* lnbc = bc + 1536 + l*256;
  const float* mb1c = bc + 2048 + l*256;
  const float* mb2c = bc + 2560 + l*256;

  for (int i = t; i < NR*64; i += 512) {
    const int row = i >> 6, d0 = (i & 63) * 4;
    stage_split4(aF, row, d0, *(const float4*)&g[(size_t)(row0 + row)*256 + d0]);
  }
  if (ADAPT && fl) {
    for (int c = t; c < NR*128; c += 512) {
      const int row = c >> 7, dp = c & 127;
      const unsigned u = ((const unsigned*)xin)[(size_t)(row0 + row)*128 + dp];
      bufB[row*260 + dp*2]     = __uint_as_float(u << 16);
      bufB[row*260 + dp*2 + 1] = __uint_as_float(u & 0xffff0000u);
    }
  } else {
    for (int c = t; c < NR*64; c += 512) {
      const int row = c >> 6, d0 = (c & 63) * 4;
      *(float4*)&bufB[row*260 + d0] = *(const float4*)((const float*)xin + (size_t)(row0 + row)*256 + d0);
    }
  }
  __syncthreads();
  float xtr[2][4];
  #pragma unroll
  for (int nt = 0; nt < 2; ++nt) {
    const int cn = (w*2 + nt)*16 + col;
    #pragma unroll
    for (int r = 0; r < 4; ++r) xtr[nt][r] = bufB[(quad*4 + r)*260 + cn];
  }
  __syncthreads();

  f32x4 acc[2];
  k4_gemm8(acc, aF, wg, w, l64);               // GEMM1
  #pragma unroll
  for (int nt = 0; nt < 2; ++nt) {
    const int cn = (w*2 + nt)*16 + col;
    #pragma unroll
    for (int r = 0; r < 4; ++r)
      bufB[(quad*4 + r)*260 + cn] = acc[nt][r] + rb2c[cn] + xtr[nt][r];
  }
  __syncthreads();
  {                                            // LN stats
    const int row = t >> 5, part = t & 31;
    if (row < NR) {
      float s = 0.f, s2 = 0.f;
      #pragma unroll
      for (int kk = 0; kk < 8; ++kk) {
        const float v = bufB[row*260 + part + kk*32];
        s += v; s2 = fmaf(v, v, s2);
      }
      #pragma unroll
      for (int off = 16; off; off >>= 1) {
        s  += __shfl_xor(s, off, 32);
        s2 += __shfl_xor(s2, off, 32);
      }
      if (part == 0) {
        const float mu = s * (1.f/256.f);
        mv[row][0] = mu;
        mv[row][1] = rsqrtf(fmaf(-mu, mu, s2 * (1.f/256.f)) + 1e-5f);
      }
    }
  }
  __syncthreads();
  for (int i = t; i < NR*64; i += 512) {       // LN apply + restage
    const int row = i >> 6, d0 = (i & 63) * 4;
    float4 v = *(const float4*)&bufB[row*260 + d0];
    const float m = mv[row][0], iv = mv[row][1];
    v.x = (v.x - m)*iv*lngc[d0]   + lnbc[d0];
    v.y = (v.y - m)*iv*lngc[d0+1] + lnbc[d0+1];
    v.z = (v.z - m)*iv*lngc[d0+2] + lnbc[d0+2];
    v.w = (v.w - m)*iv*lngc[d0+3] + lnbc[d0+3];
    stage_split4(aF, row, d0, v);
  }
  __syncthreads();
  k4_gemm8(acc, aF, wg + 65536, w, l64);       // GEMM2 + gelu
  #pragma unroll
  for (int nt = 0; nt < 2; ++nt) {
    const int cn = (w*2 + nt)*16 + col;
    #pragma unroll
    for (int r = 0; r < 4; ++r)
      if (quad*4 + r < NR)
        bufB[(quad*4 + r)*260 + cn] = gelu_e(acc[nt][r] + mb1c[cn]);
  }
  __syncthreads();
  for (int i = t; i < NR*64; i += 512) {       // restage
    const int row = i >> 6, d0 = (i & 63) * 4;
    stage_split4(aF, row, d0, *(const float4*)&bufB[row*260 + d0]);
  }
  __syncthreads();
  k4_gemm8(acc, aF, wg + 2*65536, w, l64);     // GEMM3 + residual
  if (TAIL) {
    #pragma unroll
    for (int nt = 0; nt < 2; ++nt) {
      const int cn = (w*2 + nt)*16 + col;
      #pragma unroll
      for (int r = 0; r < 4; ++r)
        bufB[(quad*4 + r)*260 + cn] = acc[nt][r] + mb2c[cn] + xtr[nt][r];
    }
    __syncthreads();
    for (int i = t; i < NR*64; i += 512) {     // coalesced x write + restage
      const int row = i >> 6, d0 = (i & 63) * 4;
      const float4 v = *(const float4*)&bufB[row*260 + d0];
      if (writeX) *(float4*)&xout[(size_t)(row0 + row)*256 + d0] = v;
      stage_split4(aF, row, d0, v);
    }
    __syncthreads();
  } else {
    #pragma unroll
    for (int nt = 0; nt < 2; ++nt) {
      const int cn = (w*2 + nt)*16 + col;
      #pragma unroll
      for (int r = 0; r < 4; ++r)
        if (quad*4 + r < NR)
          xout[(size_t)(row0 + quad*4 + r)*256 + cn] = acc[nt][r] + mb2c[cn] + xtr[nt][r];
    }
  }
}

// ---------------------------------------------------------------------------
// k5 phase: s=sum_K x ; h=gelu(s@projT+pb) ; mu=h@muT+mb ; scale=softplus(...)
// 512 threads: row-sum split across two 256-thread halves; rest as before.
// ---------------------------------------------------------------------------
__device__ __forceinline__ void k5_phase(
    const float* __restrict__ x, const float* __restrict__ wh,
    const float* __restrict__ bc, int fl, void* __restrict__ out,
    int b, int t, float (&ss2)[2][256], float (&hh)[128])
{
  const int half = t >> 8, tt = t & 255;
  {
    float s = 0.f;
    const float* xp = x + (size_t)((b << 6) + half*32)*256 + tt;
    #pragma unroll 8
    for (int i = 0; i < 32; ++i) s += xp[(size_t)i*256];
    ss2[half][tt] = s;
  }
  __syncthreads();
  if (t < 128) {
    float acc = bc[3072 + t];
    const float* projT = wh;
    for (int d = 0; d < 256; ++d) acc = fmaf(ss2[0][d] + ss2[1][d], projT[d*128 + t], acc);
    hh[t] = gelu_e(acc);
  }
  __syncthreads();
  if (t < 256) {
    float v; int oidx;
    if (t < 128) {
      float acc = bc[3200 + t];
      const float* muT = wh + 32768;
      for (int c = 0; c < 128; ++c) acc = fmaf(hh[c], muT[c*128 + t], acc);
      v = acc; oidx = b*128 + t;
    } else {
      const int u2 = t - 128;
      float acc = bc[3328 + u2];
      const float* spT = wh + 49152;
      for (int c = 0; c < 128; ++c) acc = fmaf(hh[c], spT[c*128 + u2], acc);
      v = (acc > 20.f) ? acc : log1pf(__expf(acc));
      oidx = 4096 + b*128 + u2;
    }
    if (fl) ((bf16*)out)[oidx] = __float2bfloat16(v);
    else    ((float*)out)[oidx] = v;
  }
}

// ---------------------------------------------------------------------------
// mega: the whole post-prep pipeline in ONE cooperative kernel.
// 256 blocks x 512 thr (1 block/CU), 6 grid syncs.
// ---------------------------------------------------------------------------
__global__ __launch_bounds__(512) void mega(
    const void* __restrict__ X, const unsigned short* __restrict__ wfb,
    const unsigned short* __restrict__ w3b, const float* __restrict__ wh,
    const float* __restrict__ bc, float* __restrict__ x,
    float* __restrict__ kq, float* __restrict__ Pf, unsigned* __restrict__ Qpk,
    float* __restrict__ g, void* __restrict__ out)
{
  cg::grid_group grid = cg::this_grid();
  const int fl = block_detect(X);
  __shared__ __align__(16) unsigned short aF[2][4096];
  __shared__ float bufB[16*260];
  __shared__ float mv[16][2];
  __shared__ float qs[2][2][256];
  __shared__ float scp[2][2][64];
  __shared__ float als[2][2][64];
  __shared__ float ss2[2][256];
  __shared__ float hh[128];
  const int t = threadIdx.x;
  const int bid = (int)blockIdx.x;

  // ---- P1: layer-0 k1 (was k1l0; 128 row-tiles x 2 n-halves) ----
  {
    const int row0 = (bid >> 1) * 16, ntg0 = (bid & 1) * 32;
    if (fl) {
      const int i = t;
      if (i < 512) {
        const int row = i >> 5;
        const uint4 u = *(const uint4*)((const unsigned*)X + (size_t)(row0 + row)*128 + (i & 31)*4);
        const int d0 = (i & 31) * 8;
        const int kt = d0 >> 5, lane = row | (((d0 >> 3) & 3) << 4);
        *(uint4*)&aF[0][kt*512 + lane*8] = u;
      }
    } else {
      for (int i = t; i < 1024; i += 512) {
        const int row = i >> 6, d0 = (i & 63) * 4;
        stage_split4(aF, row, d0, *(const float4*)((const float*)X + (size_t)(row0 + row)*256 + d0));
      }
    }
    __syncthreads();
    if (fl) k1_body<false, 4>(aF, wfb, bc, kq, Pf, Qpk, 0, row0, ntg0, t);
    else    k1_body<true,  4>(aF, wfb, bc, kq, Pf, Qpk, 0, row0, ntg0, t);
  }
  grid.sync();

  // ---- P2: layer-0 attention ----
  k23_phase(kq, Pf, Qpk, g, bid, t, qs, scp, als);
  grid.sync();

  // ---- P3: layer-0 mix -> x (no parity duplication; NR=8 over 256 blocks) ----
  k4_core<true, false, 8>(g, X, fl, x, w3b, bc, 0, bid*8, t, true, aF, bufB, mv);
  grid.sync();

  // ---- P4: layer-1 k1 (restage from x) ----
  {
    const int row0 = (bid >> 1) * 16, ntg0 = (bid & 1) * 32;
    for (int i = t; i < 1024; i += 512) {
      const int row = i >> 6, d0 = (i & 63) * 4;
      stage_split4(aF, row, d0, *(const float4*)&x[(size_t)(row0 + row)*256 + d0]);
    }
    __syncthreads();
    k1_body<true, 4>(aF, wfb, bc, kq, Pf, Qpk, 1, row0, ntg0, t);
  }
  grid.sync();

  // ---- P5: layer-1 attention ----
  k23_phase(kq, Pf, Qpk, g, bid, t, qs, scp, als);
  grid.sync();

  // ---- P6: layer-1 mix -> x (was k4_fin) ----
  k4_core<false, false, 8>(g, x, 0, x, w3b + 3*65536, bc, 1, bid*8, t, true, aF, bufB, mv);
  grid.sync();

  // ---- P7: head (blocks 0..31) ----
  if (bid < 32) k5_phase(x, wh, bc, fl, out, bid, t, ss2, hh);
}

// ---------------------------------------------------------------------------
extern "C" void kernel_launch(void* const* d_in, const int* in_sizes, int n_in,
                              void* d_out, int out_size, void* d_ws, size_t ws_size,
                              hipStream_t stream)
{
  (void)in_sizes; (void)n_in; (void)out_size; (void)ws_size;
  float* ws    = (float*)d_ws;
  float* x     = ws + 16;                          // 524288
  float* kq    = x + 524288;                       // 1048576
  float* Pf    = kq + 1048576;                     // 524288
  unsigned* Qpk = (unsigned*)(Pf + 524288);        // 262144
  float* g     = (float*)(Qpk + 262144);           // 524288
  unsigned short* wfb = (unsigned short*)(g + 524288);   // 524288 shorts
  unsigned short* w3b = wfb + 524288;              // 393216 shorts
  float* wh    = (float*)(w3b + 393216);           // 65536
  float* bc    = wh + 65536;                       // 3456

  prep_kernel<<<dim3(89), dim3(256), 0, stream>>>(
      d_in[0], d_in[1], d_in[2], d_in[3], d_in[5], d_in[9], d_in[11],
      d_in[13], d_in[15], d_in[17],
      d_in[4], d_in[6], d_in[7], d_in[8], d_in[10], d_in[12],
      d_in[14], d_in[16], d_in[18],
      wfb, w3b, wh, bc);

  const void* Xp = d_in[0];
  void* outp = d_out;
  void* args[] = { (void*)&Xp, (void*)&wfb, (void*)&w3b, (void*)&wh, (void*)&bc,
                   (void*)&x, (void*)&kq, (void*)&Pf, (void*)&Qpk, (void*)&g,
                   (void*)&outp };
  hipLaunchCooperativeKernel((const void*)mega, dim3(256), dim3(512), args, 0, stream);
}

// Round 2
// 265.474 us; speedup vs baseline: 1.6139x; 1.6139x over previous
//
#include <hip/hip_runtime.h>
#include <hip/hip_bf16.h>

// B=32, K=64, D=256, LS=128, rows = 2048
// R14 = R12 (best measured 206.5 us) + k5 folded into k4_fin behind a
//       device-scope atomic barrier (all 256 blocks co-resident; spinners<=32 CUs)
//       + k5 widened to 512 thr (halved dot chains). Mega/cooperative approach
//       reverted (R13 post-mortem: per-block chain serialization + grid.sync cost).

using bf16 = __hip_bfloat16;
typedef short bf16x8 __attribute__((ext_vector_type(8)));
typedef float f32x4 __attribute__((ext_vector_type(4)));

__device__ __forceinline__ float bfu(unsigned short u) { return __uint_as_float(((unsigned)u) << 16); }

__device__ __forceinline__ unsigned short bfr(float v) {   // RNE fp32->bf16 bits
  unsigned u = __float_as_uint(v);
  u += 0x7FFFu + ((u >> 16) & 1u);
  return (unsigned short)(u >> 16);
}

__device__ __forceinline__ float gelu_e(float x) {
  return 0.5f * x * (1.0f + erff(x * 0.7071067811865475f));
}

__device__ __forceinline__ float load_f(const void* p, int i, int fl) {
  if (fl) return bfu(((const unsigned short*)p)[i]);
  return ((const float*)p)[i];
}

// per-block inline dtype detect: 1 = inputs are bf16
__device__ __forceinline__ int block_detect(const void* X) {
  __shared__ int bad_s;
  if (threadIdx.x == 0) bad_s = 0;
  __syncthreads();
  if (threadIdx.x < 256) {
    const float v = bfu(((const unsigned short*)X)[threadIdx.x]);
    if (!(fabsf(v) < 1e6f)) atomicOr(&bad_s, 1);
  }
  __syncthreads();
  return bad_s ? 0 : 1;
}

// stage one float4 (row, d0) into hi/lo MFMA A-fragments
__device__ __forceinline__ void stage_split4(unsigned short (&aF)[2][4096], int row, int d0, float4 v) {
  ushort4 h, lo;
  h.x = bfr(v.x); h.y = bfr(v.y); h.z = bfr(v.z); h.w = bfr(v.w);
  lo.x = bfr(v.x - bfu(h.x)); lo.y = bfr(v.y - bfu(h.y));
  lo.z = bfr(v.z - bfu(h.z)); lo.w = bfr(v.w - bfu(h.w));
  const int kt = d0 >> 5, lane = row | (((d0 >> 3) & 3) << 4), j = d0 & 7;
  *(ushort4*)&aF[0][kt*512 + lane*8 + j] = h;
  *(ushort4*)&aF[1][kt*512 + lane*8 + j] = lo;
}

// ---------------------------------------------------------------------------
// prep (89 blocks x 256 thr): weights -> ws  (+ zero the barrier counter)
// ---------------------------------------------------------------------------
__global__ __launch_bounds__(256) void prep_kernel(
    const void* __restrict__ X, const void* __restrict__ kw, const void* __restrict__ qw,
    const void* __restrict__ rw1, const void* __restrict__ rw2, const void* __restrict__ mw1,
    const void* __restrict__ mw2, const void* __restrict__ pw, const void* __restrict__ muw,
    const void* __restrict__ spw,
    const void* __restrict__ rb1, const void* __restrict__ rb2, const void* __restrict__ lng,
    const void* __restrict__ lnb, const void* __restrict__ mb1, const void* __restrict__ mb2,
    const void* __restrict__ pb, const void* __restrict__ mub, const void* __restrict__ spb,
    unsigned short* __restrict__ wfb, unsigned short* __restrict__ w3b,
    float* __restrict__ wh, float* __restrict__ bc, unsigned* __restrict__ cnt)
{
  __shared__ __align__(16) char psm[65536];
  const int fl = block_detect(X);
  const int t = threadIdx.x;
  int blk = blockIdx.x;

  if (blk < 16) {   // ---- A: wfb (l,kt)
    unsigned short* ls = (unsigned short*)psm;
    unsigned* lsu = (unsigned*)psm;
    const int l = blk >> 3, kt = blk & 7;
    if (fl) {
      #pragma unroll
      for (int s = 0; s < 4; ++s) {
        const unsigned* sp = (const unsigned*)((s == 0) ? kw : (s == 1) ? qw : rw1);
        const int rstr = (s < 2) ? 128 : 256;
        const int coff = ((s == 3) ? 128 : 0) + kt*16;
        for (int i = t; i < 4096; i += 256) {
          const int e = i >> 4, d2 = i & 15;
          lsu[s*4096 + i] = sp[(l*256 + e)*rstr + coff + d2];
        }
      }
    } else {
      #pragma unroll
      for (int s = 0; s < 4; ++s) {
        const float* sp = (const float*)((s == 0) ? kw : (s == 1) ? qw : rw1);
        const int rstr = (s < 2) ? 256 : 512;
        const int coff = ((s == 3) ? 256 : 0) + kt*32;
        for (int i = t; i < 4096; i += 256) {
          const int e = i >> 4, d2 = i & 15;
          const float f0 = sp[(l*256 + e)*rstr + coff + d2*2];
          const float f1 = sp[(l*256 + e)*rstr + coff + d2*2 + 1];
          lsu[s*4096 + i] = (unsigned)bfr(f0) | ((unsigned)bfr(f1) << 16);
        }
      }
    }
    __syncthreads();
    unsigned* outp = (unsigned*)wfb + (l*8 + kt)*16384;
    for (int f2 = t; f2 < 16384; f2 += 256) {
      const int j2 = f2 & 3, lane = (f2 >> 2) & 63, ntg = f2 >> 8;
      const int seg = ntg >> 4;
      const int e = (ntg & 15)*16 + (lane & 15);
      const int dl = ((lane >> 4) & 3)*8 + j2*2;
      unsigned short r0 = ls[seg*8192 + e*32 + dl];
      unsigned short r1 = ls[seg*8192 + e*32 + dl + 1];
      if (seg == 1) { r0 = bfr(bfu(r0)*0.0625f); r1 = bfr(bfu(r1)*0.0625f); }
      else if (seg == 2) {
        const unsigned short w0 = ls[3*8192 + e*32 + dl];
        const unsigned short w1 = ls[3*8192 + e*32 + dl + 1];
        r0 = bfr(bfu(r0) + bfu(w0)); r1 = bfr(bfu(r1) + bfu(w1));
      }
      outp[f2] = (unsigned)r0 | ((unsigned)r1 << 16);
    }
    return;
  }
  blk -= 16;
  if (blk < 48) {   // ---- B: w3b (l,gm,kt)
    unsigned short* ls = (unsigned short*)psm;
    unsigned* lsu = (unsigned*)psm;
    const int l3 = blk >> 3, kt = blk & 7;
    const int l = l3 / 3, gm = l3 % 3;
    const void* src = (gm == 0) ? rw2 : (gm == 1) ? mw1 : mw2;
    if (fl) {
      const unsigned* sp = (const unsigned*)src;
      for (int i = t; i < 4096; i += 256) {
        const int e = i >> 4, d2 = i & 15;
        lsu[i] = sp[(l*256 + e)*128 + kt*16 + d2];
      }
    } else {
      const float* sp = (const float*)src;
      for (int i = t; i < 4096; i += 256) {
        const int e = i >> 4, d2 = i & 15;
        const float f0 = sp[(l*256 + e)*256 + kt*32 + d2*2];
        const float f1 = sp[(l*256 + e)*256 + kt*32 + d2*2 + 1];
        lsu[i] = (unsigned)bfr(f0) | ((unsigned)bfr(f1) << 16);
      }
    }
    __syncthreads();
    unsigned* outp = (unsigned*)w3b + (l3*8 + kt)*4096;
    for (int f2 = t; f2 < 4096; f2 += 256) {
      const int j2 = f2 & 3, lane = (f2 >> 2) & 63, nt = f2 >> 8;
      const int e = nt*16 + (lane & 15);
      const int dl = ((lane >> 4) & 3)*8 + j2*2;
      outp[f2] = (unsigned)ls[e*32 + dl] | ((unsigned)ls[e*32 + dl + 1] << 16);
    }
    return;
  }
  blk -= 48;
  if (blk < 24) {   // ---- D: wh transposes
    float* lsf = (float*)psm;
    if (blk < 8) {          // projT
      const int l0 = blk*16;
      if (fl) {
        const unsigned* sp = (const unsigned*)pw;
        for (int i = t; i < 2048; i += 256) {
          const int ll = i >> 7, d2 = i & 127;
          const unsigned u = sp[(l0 + ll)*128 + d2];
          lsf[ll*256 + d2*2]     = __uint_as_float(u << 16);
          lsf[ll*256 + d2*2 + 1] = __uint_as_float(u & 0xffff0000u);
        }
      } else {
        const float* sp = (const float*)pw;
        for (int i = t; i < 4096; i += 256) {
          const int ll = i >> 8, d = i & 255;
          lsf[ll*256 + d] = sp[(l0 + ll)*256 + d];
        }
      }
      __syncthreads();
      for (int i = t; i < 4096; i += 256) {
        const int d = i >> 4, ll = i & 15;
        wh[d*128 + l0 + ll] = lsf[ll*256 + d];
      }
    } else {                // muT / spT
      const int grp2 = blk - 8;
      const int isSp = grp2 >> 3;
      const int l0 = (grp2 & 7)*16;
      const void* src = isSp ? spw : muw;
      const int off = isSp ? 49152 : 32768;
      if (fl) {
        const unsigned* sp = (const unsigned*)src;
        for (int i = t; i < 1024; i += 256) {
          const int ll = i >> 6, c2 = i & 63;
          const unsigned u = sp[(l0 + ll)*64 + c2];
          lsf[ll*128 + c2*2]     = __uint_as_float(u << 16);
          lsf[ll*128 + c2*2 + 1] = __uint_as_float(u & 0xffff0000u);
        }
      } else {
        const float* sp = (const float*)src;
        for (int i = t; i < 2048; i += 256) {
          const int ll = i >> 7, c = i & 127;
          lsf[ll*128 + c] = sp[(l0 + ll)*128 + c];
        }
      }
      __syncthreads();
      for (int i = t; i < 2048; i += 256) {
        const int c = i >> 4, ll = i & 15;
        wh[off + c*128 + l0 + ll] = lsf[ll*128 + c];
      }
    }
    return;
  }
  // ---- E: bc (+ zero barrier counter)
  if (t == 0) *cnt = 0u;
  for (int i = t; i < 3456; i += 256) {
    const void* src; int off;
    if (i < 512)       { src = rb1; off = i; }
    else if (i < 1024) { src = rb2; off = i - 512; }
    else if (i < 1536) { src = lng; off = i - 1024; }
    else if (i < 2048) { src = lnb; off = i - 1536; }
    else if (i < 2560) { src = mb1; off = i - 2048; }
    else if (i < 3072) { src = mb2; off = i - 2560; }
    else if (i < 3200) { src = pb;  off = i - 3072; }
    else if (i < 3328) { src = mub; off = i - 3200; }
    else               { src = spb; off = i - 3328; }
    bc[i] = load_f(src, off, fl);
  }
}

// ---------------------------------------------------------------------------
// k1 body: 16 rows x (waves*NTG*16) cols from staged A-frags
// ---------------------------------------------------------------------------
template<bool SPLIT, int NTG>
__device__ __forceinline__ void k1_body(
    const unsigned short (&aF)[2][4096],
    const unsigned short* __restrict__ wfb, const float* __restrict__ bc,
    float* __restrict__ kq, float* __restrict__ Pf, unsigned* __restrict__ Qpk,
    int l, int row0, int ntg0, int t)
{
  const int w = t >> 6, l64 = t & 63;
  const int col = l64 & 15, quad = l64 >> 4;
  f32x4 acc[NTG];
  #pragma unroll
  for (int i = 0; i < NTG; ++i) acc[i] = (f32x4){0.f, 0.f, 0.f, 0.f};
  for (int kt = 0; kt < 8; ++kt) {
    const bf16x8 ah = *(const bf16x8*)&aF[0][kt*512 + l64*8];
    bf16x8 al;
    if (SPLIT) al = *(const bf16x8*)&aF[1][kt*512 + l64*8];
    #pragma unroll
    for (int i = 0; i < NTG; ++i) {
      const int ntg = ntg0 + w*NTG + i;
      const bf16x8 b = *(const bf16x8*)&wfb[((l*8 + kt)*64 + ntg)*512 + l64*8];
      acc[i] = __builtin_amdgcn_mfma_f32_16x16x32_bf16(ah, b, acc[i], 0, 0, 0);
      if (SPLIT) acc[i] = __builtin_amdgcn_mfma_f32_16x16x32_bf16(al, b, acc[i], 0, 0, 0);
    }
  }
  #pragma unroll
  for (int i = 0; i < NTG; ++i) {
    const int ntg = ntg0 + w*NTG + i;
    if (ntg < 32) {
      const int n = ntg*16 + col;
      #pragma unroll
      for (int r = 0; r < 4; ++r)
        kq[(size_t)(row0 + quad*4 + r)*512 + n] = acc[i][r];
    } else if (ntg < 48) {
      const int c = (ntg - 32)*16 + col;
      const float bias = bc[l*256 + c];
      #pragma unroll
      for (int r = 0; r < 4; ++r)
        Pf[(size_t)(row0 + quad*4 + r)*256 + c] = acc[i][r] + bias;
    } else {
      #pragma unroll
      for (int r = 0; r < 4; ++r) {
        const float v = acc[i][r];
        const float pv = __shfl_xor(v, 1, 64);
        if (!(col & 1)) {
          const unsigned uu = (unsigned)bfr(v) | ((unsigned)bfr(pv) << 16);
          Qpk[(size_t)(row0 + quad*4 + r)*128 + (ntg - 48)*8 + (col >> 1)] = uu;
        }
      }
    }
  }
}

// ---------------------------------------------------------------------------
// k1 layer-0: 512 blocks (128 m x 4 n) x 256 thr
// ---------------------------------------------------------------------------
__global__ __launch_bounds__(256) void k1l0(
    const void* __restrict__ X, const unsigned short* __restrict__ wfb,
    const float* __restrict__ bc, float* __restrict__ kq, float* __restrict__ Pf,
    unsigned* __restrict__ Qpk)
{
  const int fl = block_detect(X);
  __shared__ __align__(16) unsigned short aF[2][4096];
  const int t = threadIdx.x;
  const int mb = (int)blockIdx.x >> 2, nb4 = (int)blockIdx.x & 3;
  const int row0 = mb * 16, ntg0 = nb4 * 16;
  if (fl) {
    for (int i = t; i < 512; i += 256) {
      const int row = i >> 5, d0 = (i & 31) * 8;
      const uint4 u = *(const uint4*)((const unsigned*)X + (size_t)(row0 + row)*128 + (i & 31)*4);
      const int kt = d0 >> 5, lane = row | (((d0 >> 3) & 3) << 4);
      *(uint4*)&aF[0][kt*512 + lane*8] = u;
    }
  } else {
    for (int i = t; i < 1024; i += 256) {
      const int row = i >> 6, d0 = (i & 63) * 4;
      stage_split4(aF, row, d0, *(const float4*)((const float*)X + (size_t)(row0 + row)*256 + d0));
    }
  }
  __syncthreads();
  if (fl) k1_body<false, 4>(aF, wfb, bc, kq, Pf, Qpk, 0, row0, ntg0, t);
  else    k1_body<true,  4>(aF, wfb, bc, kq, Pf, Qpk, 0, row0, ntg0, t);
}

// ---------------------------------------------------------------------------
// k23: fused scores + softmax + gelu-weighted aggregation
// grid 1024 (b, i-pair), 256 thr / 4 waves; Q read from L2
// ---------------------------------------------------------------------------
__global__ __launch_bounds__(256) void k23_attn(
    const float* __restrict__ kq, const float* __restrict__ Pf,
    const unsigned* __restrict__ Qpk, float* __restrict__ g)
{
  __shared__ float qs[2][256];
  __shared__ float scp[2][64];
  __shared__ float als[2][64];
  const int t = threadIdx.x;
  const int b = (int)blockIdx.x >> 5, ip = (int)blockIdx.x & 31;
  const int base = b << 6, i0 = ip * 2;
  for (int i = t; i < 512; i += 256)
    qs[i >> 8][i & 255] = kq[(size_t)(base + i0 + (i >> 8))*512 + 256 + (i & 255)];
  __syncthreads();
  {
    const int w = t >> 6, lane = t & 63;
    const int jl = lane & 15, part = lane >> 4;
    const int j = w*16 + jl;
    const float* krow = kq + (size_t)(base + j)*512 + part*64;
    const float* q0p = &qs[0][part*64];
    const float* q1p = &qs[1][part*64];
    float s0 = 0.f, s1 = 0.f;
    for (int dd = 0; dd < 64; dd += 4) {
      const float4 kv = *(const float4*)&krow[dd];
      const float4 q0 = *(const float4*)&q0p[dd];
      const float4 q1 = *(const float4*)&q1p[dd];
      s0 = fmaf(kv.x, q0.x, s0); s0 = fmaf(kv.y, q0.y, s0);
      s0 = fmaf(kv.z, q0.z, s0); s0 = fmaf(kv.w, q0.w, s0);
      s1 = fmaf(kv.x, q1.x, s1); s1 = fmaf(kv.y, q1.y, s1);
      s1 = fmaf(kv.z, q1.z, s1); s1 = fmaf(kv.w, q1.w, s1);
    }
    s0 += __shfl_xor(s0, 16, 64); s0 += __shfl_xor(s0, 32, 64);
    s1 += __shfl_xor(s1, 16, 64); s1 += __shfl_xor(s1, 32, 64);
    if (part == 0) { scp[0][j] = s0; scp[1][j] = s1; }
  }
  __syncthreads();
  if (t < 128) {
    const int row = t >> 6, j = t & 63;
    float s = scp[row][j];
    float m = s;
    #pragma unroll
    for (int off = 32; off; off >>= 1) m = fmaxf(m, __shfl_xor(m, off, 64));
    const float e = __expf(s - m);
    float ss = e;
    #pragma unroll
    for (int off = 32; off; off >>= 1) ss += __shfl_xor(ss, off, 64);
    als[row][j] = e / ss;
  }
  __syncthreads();
  const int rg = t >> 7, cp = t & 127;
  const int r = base + i0 + rg;
  const float2 P = *(const float2*)&Pf[(size_t)r*256 + cp*2];
  const float A0 = -1.702f * P.x, A1 = -1.702f * P.y;
  const float* ap = &als[rg][0];
  const unsigned* qp = Qpk + (size_t)base*128 + cp;
  float acc0 = 0.f, acc1 = 0.f;
  #pragma unroll 8
  for (int j = 0; j < 64; ++j) {
    const unsigned u = qp[j*128];
    const float wgt = ap[j];
    const float q0 = __uint_as_float(u << 16);
    const float q1 = __uint_as_float(u & 0xffff0000u);
    const float s0 = __builtin_amdgcn_rcpf(1.f + __expf(fmaf(1.702f, q0, A0)));
    const float s1 = __builtin_amdgcn_rcpf(1.f + __expf(fmaf(1.702f, q1, A1)));
    acc0 = fmaf(wgt * (P.x - q0), s0, acc0);
    acc1 = fmaf(wgt * (P.y - q1), s1, acc1);
  }
  *(float2*)&g[(size_t)r*256 + cp*2] = make_float2(acc0, acc1);
}

// ---------------------------------------------------------------------------
// k4 core (512 thr): agg=g@rw2^T+rb2; h=LN(xin+agg); out=xin+mlp(h)
// ---------------------------------------------------------------------------
__device__ __forceinline__ void k4_gemm8(
    f32x4 acc[2], const unsigned short (&aF)[2][4096],
    const unsigned short* __restrict__ wg, int w, int l64)
{
  acc[0] = (f32x4){0.f, 0.f, 0.f, 0.f};
  acc[1] = (f32x4){0.f, 0.f, 0.f, 0.f};
  for (int kt = 0; kt < 8; ++kt) {
    const bf16x8 ah = *(const bf16x8*)&aF[0][kt*512 + l64*8];
    const bf16x8 al = *(const bf16x8*)&aF[1][kt*512 + l64*8];
    #pragma unroll
    for (int nt = 0; nt < 2; ++nt) {
      const bf16x8 b = *(const bf16x8*)&wg[((kt*16 + (w*2 + nt))*64 + l64)*8];
      acc[nt] = __builtin_amdgcn_mfma_f32_16x16x32_bf16(ah, b, acc[nt], 0, 0, 0);
      acc[nt] = __builtin_amdgcn_mfma_f32_16x16x32_bf16(al, b, acc[nt], 0, 0, 0);
    }
  }
}

template<bool ADAPT, bool TAIL, int NR>
__device__ __forceinline__ void k4_core(
    const float* __restrict__ g, const void* __restrict__ xin, int fl,
    float* __restrict__ xout, const unsigned short* __restrict__ wg,
    const float* __restrict__ bc, int l, int row0, int t, bool writeX,
    unsigned short (&aF)[2][4096], float* bufB, float (&mv)[16][2])
{
  const int w = t >> 6, l64 = t & 63;
  const int col = l64 & 15, quad = l64 >> 4;
  const float* rb2c = bc + 512  + l*256;
  const float* lngc = bc + 1024 + l*256;
  const float* lnbc = bc + 1536 + l*256;
  const float* mb1c = bc + 2048 + l*256;
  const float* mb2c = bc + 2560 + l*256;

  for (int i = t; i < NR*64; i += 512) {
    const int row = i >> 6, d0 = (i & 63) * 4;
    stage_split4(aF, row, d0, *(const float4*)&g[(size_t)(row0 + row)*256 + d0]);
  }
  if (ADAPT && fl) {
    for (int c = t; c < NR*128; c += 512) {
      const int row = c >> 7, dp = c & 127;
      const unsigned u = ((const unsigned*)xin)[(size_t)(row0 + row)*128 + dp];
      bufB[row*260 + dp*2]     = __uint_as_float(u << 16);
      bufB[row*260 + dp*2 + 1] = __uint_as_float(u & 0xffff0000u);
    }
  } else {
    for (int c = t; c < NR*64; c += 512) {
      const int row = c >> 6, d0 = (c & 63) * 4;
      *(float4*)&bufB[row*260 + d0] = *(const float4*)((const float*)xin + (size_t)(row0 + row)*256 + d0);
    }
  }
  __syncthreads();
  float xtr[2][4];
  #pragma unroll
  for (int nt = 0; nt < 2; ++nt) {
    const int cn = (w*2 + nt)*16 + col;
    #pragma unroll
    for (int r = 0; r < 4; ++r) xtr[nt][r] = bufB[(quad*4 + r)*260 + cn];
  }
  __syncthreads();

  f32x4 acc[2];
  k4_gemm8(acc, aF, wg, w, l64);               // GEMM1
  #pragma unroll
  for (int nt = 0; nt < 2; ++nt) {
    const int cn = (w*2 + nt)*16 + col;
    #pragma unroll
    for (int r = 0; r < 4; ++r)
      bufB[(quad*4 + r)*260 + cn] = acc[nt][r] + rb2c[cn] + xtr[nt][r];
  }
  __syncthreads();
  {                                            // LN stats
    const int row = t >> 5, part = t & 31;
    if (row < NR) {
      float s = 0.f, s2 = 0.f;
      #pragma unroll
      for (int kk = 0; kk < 8; ++kk) {
        const float v = bufB[row*260 + part + kk*32];
        s += v; s2 = fmaf(v, v, s2);
      }
      #pragma unroll
      for (int off = 16; off; off >>= 1) {
        s  += __shfl_xor(s, off, 32);
        s2 += __shfl_xor(s2, off, 32);
      }
      if (part == 0) {
        const float mu = s * (1.f/256.f);
        mv[row][0] = mu;
        mv[row][1] = rsqrtf(fmaf(-mu, mu, s2 * (1.f/256.f)) + 1e-5f);
      }
    }
  }
  __syncthreads();
  for (int i = t; i < NR*64; i += 512) {       // LN apply + restage
    const int row = i >> 6, d0 = (i & 63) * 4;
    float4 v = *(const float4*)&bufB[row*260 + d0];
    const float m = mv[row][0], iv = mv[row][1];
    v.x = (v.x - m)*iv*lngc[d0]   + lnbc[d0];
    v.y = (v.y - m)*iv*lngc[d0+1] + lnbc[d0+1];
    v.z = (v.z - m)*iv*lngc[d0+2] + lnbc[d0+2];
    v.w = (v.w - m)*iv*lngc[d0+3] + lnbc[d0+3];
    stage_split4(aF, row, d0, v);
  }
  __syncthreads();
  k4_gemm8(acc, aF, wg + 65536, w, l64);       // GEMM2 + gelu
  #pragma unroll
  for (int nt = 0; nt < 2; ++nt) {
    const int cn = (w*2 + nt)*16 + col;
    #pragma unroll
    for (int r = 0; r < 4; ++r)
      if (quad*4 + r < NR)
        bufB[(quad*4 + r)*260 + cn] = gelu_e(acc[nt][r] + mb1c[cn]);
  }
  __syncthreads();
  for (int i = t; i < NR*64; i += 512) {       // restage
    const int row = i >> 6, d0 = (i & 63) * 4;
    stage_split4(aF, row, d0, *(const float4*)&bufB[row*260 + d0]);
  }
  __syncthreads();
  k4_gemm8(acc, aF, wg + 2*65536, w, l64);     // GEMM3 + residual
  if (TAIL) {
    #pragma unroll
    for (int nt = 0; nt < 2; ++nt) {
      const int cn = (w*2 + nt)*16 + col;
      #pragma unroll
      for (int r = 0; r < 4; ++r)
        bufB[(quad*4 + r)*260 + cn] = acc[nt][r] + mb2c[cn] + xtr[nt][r];
    }
    __syncthreads();
    for (int i = t; i < NR*64; i += 512) {     // coalesced x write + restage
      const int row = i >> 6, d0 = (i & 63) * 4;
      const float4 v = *(const float4*)&bufB[row*260 + d0];
      if (writeX) *(float4*)&xout[(size_t)(row0 + row)*256 + d0] = v;
      stage_split4(aF, row, d0, v);
    }
    __syncthreads();
  } else {
    #pragma unroll
    for (int nt = 0; nt < 2; ++nt) {
      const int cn = (w*2 + nt)*16 + col;
      #pragma unroll
      for (int r = 0; r < 4; ++r)
        if (quad*4 + r < NR)
          xout[(size_t)(row0 + quad*4 + r)*256 + cn] = acc[nt][r] + mb2c[cn] + xtr[nt][r];
    }
  }
}

// k41: layer-0 mix + layer-1 k1; 256 blocks (128 row-tiles x 2 parity), 512 thr
__global__ __launch_bounds__(512) void k41_mix_kq(
    const float* __restrict__ g, const unsigned short* __restrict__ w3b,
    const unsigned short* __restrict__ wfb, const float* __restrict__ bc,
    const void* __restrict__ X, float* __restrict__ x,
    float* __restrict__ kq, float* __restrict__ Pf, unsigned* __restrict__ Qpk)
{
  const int fl = block_detect(X);
  __shared__ __align__(16) unsigned short aF[2][4096];
  __shared__ float bufB[16*260];
  __shared__ float mv[16][2];
  const int t = threadIdx.x;
  const int rb = (int)blockIdx.x >> 1, parity = (int)blockIdx.x & 1;
  const int row0 = rb * 16;
  k4_core<true, true, 16>(g, X, fl, x, w3b, bc, 0, row0, t, parity == 0, aF, bufB, mv);
  k1_body<true, 4>(aF, wfb, bc, kq, Pf, Qpk, 1, row0, parity*32, t);
}

// ---------------------------------------------------------------------------
// k4fin5: layer-1 mix (256 blocks x 8 rows, 512 thr) + device barrier +
//         head phase on blocks 0..31 (k5 folded in; all 256 blocks co-resident)
// ---------------------------------------------------------------------------
__global__ __launch_bounds__(512) void k4fin5(
    const float* __restrict__ g, const unsigned short* __restrict__ w3b,
    const float* __restrict__ bc, float* __restrict__ x,
    const float* __restrict__ wh, const void* __restrict__ X,
    void* __restrict__ out, unsigned* __restrict__ cnt)
{
  const int fl = block_detect(X);
  __shared__ __align__(16) unsigned short aF[2][4096];
  __shared__ float bufB[16*260];
  __shared__ float mv[16][2];
  const int t = threadIdx.x;
  const int bid = (int)blockIdx.x;
  const int row0 = bid * 8;
  k4_core<false, false, 8>(g, x, 0, x, w3b + 3*65536, bc, 1, row0, t, true, aF, bufB, mv);

  // ---- device barrier: release x, count blocks ----
  __threadfence();
  __syncthreads();
  if (t == 0) __hip_atomic_fetch_add(cnt, 1u, __ATOMIC_RELEASE, __HIP_MEMORY_SCOPE_AGENT);
  if (bid >= 32) return;
  if (t == 0) {
    while (__hip_atomic_load(cnt, __ATOMIC_ACQUIRE, __HIP_MEMORY_SCOPE_AGENT) < 256u)
      __builtin_amdgcn_s_sleep(2);
  }
  __syncthreads();
  __threadfence();

  // ---- head phase (b = bid): s=sum_K x; h=gelu(s@projT+pb); mu; softplus ----
  float* ss2 = bufB;          // [2][256]
  float* hh  = bufB + 512;    // [128]
  float* red = bufB + 640;    // [512]
  {
    const int half = t >> 8, tt = t & 255;
    float s = 0.f;
    const float* xp = x + (size_t)((bid << 6) + half*32)*256 + tt;
    #pragma unroll 8
    for (int i = 0; i < 32; ++i) s += xp[(size_t)i*256];
    ss2[half*256 + tt] = s;
  }
  __syncthreads();
  if (t < 256) {
    const int o = t & 127, dh = t >> 7;
    float acc = 0.f;
    #pragma unroll 4
    for (int d = dh*128; d < dh*128 + 128; ++d)
      acc = fmaf(ss2[d] + ss2[256 + d], wh[d*128 + o], acc);
    red[t] = acc;
  }
  __syncthreads();
  if (t < 128) hh[t] = gelu_e(red[t] + red[128 + t] + bc[3072 + t]);
  __syncthreads();
  {
    const int grp = t >> 7, o = t & 127;
    const int isSp = grp >> 1, ch = grp & 1;
    const float* W = wh + (isSp ? 49152 : 32768);
    float acc = 0.f;
    #pragma unroll 4
    for (int c = ch*64; c < ch*64 + 64; ++c)
      acc = fmaf(hh[c], W[c*128 + o], acc);
    red[t] = acc;
  }
  __syncthreads();
  if (t < 256) {
    const int isSp = t >> 7, o = t & 127;
    float v; int oidx;
    if (isSp == 0) {
      v = red[o] + red[128 + o] + bc[3200 + o];
      oidx = bid*128 + o;
    } else {
      const float a = red[256 + o] + red[384 + o] + bc[3328 + o];
      v = (a > 20.f) ? a : log1pf(__expf(a));
      oidx = 4096 + bid*128 + o;
    }
    if (fl) ((bf16*)out)[oidx] = __float2bfloat16(v);
    else    ((float*)out)[oidx] = v;
  }
}

// ---------------------------------------------------------------------------
extern "C" void kernel_launch(void* const* d_in, const int* in_sizes, int n_in,
                              void* d_out, int out_size, void* d_ws, size_t ws_size,
                              hipStream_t stream)
{
  (void)in_sizes; (void)n_in; (void)out_size; (void)ws_size;
  float* ws    = (float*)d_ws;
  unsigned* cnt = (unsigned*)ws;                   // barrier counter in ws[0]
  float* x     = ws + 16;                          // 524288
  float* kq    = x + 524288;                       // 1048576
  float* Pf    = kq + 1048576;                     // 524288
  unsigned* Qpk = (unsigned*)(Pf + 524288);        // 262144
  float* g     = (float*)(Qpk + 262144);           // 524288
  unsigned short* wfb = (unsigned short*)(g + 524288);   // 524288 shorts
  unsigned short* w3b = wfb + 524288;              // 393216 shorts
  float* wh    = (float*)(w3b + 393216);           // 65536
  float* bc    = wh + 65536;                       // 3456

  prep_kernel<<<dim3(89), dim3(256), 0, stream>>>(
      d_in[0], d_in[1], d_in[2], d_in[3], d_in[5], d_in[9], d_in[11],
      d_in[13], d_in[15], d_in[17],
      d_in[4], d_in[6], d_in[7], d_in[8], d_in[10], d_in[12],
      d_in[14], d_in[16], d_in[18],
      wfb, w3b, wh, bc, cnt);
  k1l0<<<dim3(512), dim3(256), 0, stream>>>(d_in[0], wfb, bc, kq, Pf, Qpk);
  k23_attn<<<dim3(1024), dim3(256), 0, stream>>>(kq, Pf, Qpk, g);
  k41_mix_kq<<<dim3(256), dim3(512), 0, stream>>>(g, w3b, wfb, bc, d_in[0], x, kq, Pf, Qpk);
  k23_attn<<<dim3(1024), dim3(256), 0, stream>>>(kq, Pf, Qpk, g);
  k4fin5<<<dim3(256), dim3(512), 0, stream>>>(g, w3b, bc, x, wh, d_in[0], (void*)d_out, cnt);
}

// Round 3
// 215.712 us; speedup vs baseline: 1.9862x; 1.2307x over previous
//
#include <hip/hip_runtime.h>
#include <hip/hip_bf16.h>

// B=32, K=64, D=256, LS=128, rows = 2048
// R15 = R12 structure with both k23 launches folded into their consumers:
//       kA = attn(l0, own rows, g in LDS) + k4_core(l0) + k1_body(l1)
//       kB = attn(l1, own rows) + k4_core(l1)
//       kq/Pf/Qpk double-buffered per layer (removes read/write race).
//       7 -> 5 kernel boundaries; no in-kernel global barriers (R13/R14 lesson:
//       grid.sync and release-atomic barriers cost 2-3x a launch boundary).

using bf16 = __hip_bfloat16;
typedef short bf16x8 __attribute__((ext_vector_type(8)));
typedef float f32x4 __attribute__((ext_vector_type(4)));

__device__ __forceinline__ float bfu(unsigned short u) { return __uint_as_float(((unsigned)u) << 16); }

__device__ __forceinline__ unsigned short bfr(float v) {   // RNE fp32->bf16 bits
  unsigned u = __float_as_uint(v);
  u += 0x7FFFu + ((u >> 16) & 1u);
  return (unsigned short)(u >> 16);
}

__device__ __forceinline__ float gelu_e(float x) {
  return 0.5f * x * (1.0f + erff(x * 0.7071067811865475f));
}

__device__ __forceinline__ float load_f(const void* p, int i, int fl) {
  if (fl) return bfu(((const unsigned short*)p)[i]);
  return ((const float*)p)[i];
}

// per-block inline dtype detect: 1 = inputs are bf16
__device__ __forceinline__ int block_detect(const void* X) {
  __shared__ int bad_s;
  if (threadIdx.x == 0) bad_s = 0;
  __syncthreads();
  if (threadIdx.x < 256) {
    const float v = bfu(((const unsigned short*)X)[threadIdx.x]);
    if (!(fabsf(v) < 1e6f)) atomicOr(&bad_s, 1);
  }
  __syncthreads();
  return bad_s ? 0 : 1;
}

// stage one float4 (row, d0) into hi/lo MFMA A-fragments
__device__ __forceinline__ void stage_split4(unsigned short (&aF)[2][4096], int row, int d0, float4 v) {
  ushort4 h, lo;
  h.x = bfr(v.x); h.y = bfr(v.y); h.z = bfr(v.z); h.w = bfr(v.w);
  lo.x = bfr(v.x - bfu(h.x)); lo.y = bfr(v.y - bfu(h.y));
  lo.z = bfr(v.z - bfu(h.z)); lo.w = bfr(v.w - bfu(h.w));
  const int kt = d0 >> 5, lane = row | (((d0 >> 3) & 3) << 4), j = d0 & 7;
  *(ushort4*)&aF[0][kt*512 + lane*8 + j] = h;
  *(ushort4*)&aF[1][kt*512 + lane*8 + j] = lo;
}

// ---------------------------------------------------------------------------
// prep (89 blocks x 256 thr): weights -> ws   [unchanged from R12]
// ---------------------------------------------------------------------------
__global__ __launch_bounds__(256) void prep_kernel(
    const void* __restrict__ X, const void* __restrict__ kw, const void* __restrict__ qw,
    const void* __restrict__ rw1, const void* __restrict__ rw2, const void* __restrict__ mw1,
    const void* __restrict__ mw2, const void* __restrict__ pw, const void* __restrict__ muw,
    const void* __restrict__ spw,
    const void* __restrict__ rb1, const void* __restrict__ rb2, const void* __restrict__ lng,
    const void* __restrict__ lnb, const void* __restrict__ mb1, const void* __restrict__ mb2,
    const void* __restrict__ pb, const void* __restrict__ mub, const void* __restrict__ spb,
    unsigned short* __restrict__ wfb, unsigned short* __restrict__ w3b,
    float* __restrict__ wh, float* __restrict__ bc)
{
  __shared__ __align__(16) char psm[65536];
  const int fl = block_detect(X);
  const int t = threadIdx.x;
  int blk = blockIdx.x;

  if (blk < 16) {   // ---- A: wfb (l,kt)
    unsigned short* ls = (unsigned short*)psm;
    unsigned* lsu = (unsigned*)psm;
    const int l = blk >> 3, kt = blk & 7;
    if (fl) {
      #pragma unroll
      for (int s = 0; s < 4; ++s) {
        const unsigned* sp = (const unsigned*)((s == 0) ? kw : (s == 1) ? qw : rw1);
        const int rstr = (s < 2) ? 128 : 256;
        const int coff = ((s == 3) ? 128 : 0) + kt*16;
        for (int i = t; i < 4096; i += 256) {
          const int e = i >> 4, d2 = i & 15;
          lsu[s*4096 + i] = sp[(l*256 + e)*rstr + coff + d2];
        }
      }
    } else {
      #pragma unroll
      for (int s = 0; s < 4; ++s) {
        const float* sp = (const float*)((s == 0) ? kw : (s == 1) ? qw : rw1);
        const int rstr = (s < 2) ? 256 : 512;
        const int coff = ((s == 3) ? 256 : 0) + kt*32;
        for (int i = t; i < 4096; i += 256) {
          const int e = i >> 4, d2 = i & 15;
          const float f0 = sp[(l*256 + e)*rstr + coff + d2*2];
          const float f1 = sp[(l*256 + e)*rstr + coff + d2*2 + 1];
          lsu[s*4096 + i] = (unsigned)bfr(f0) | ((unsigned)bfr(f1) << 16);
        }
      }
    }
    __syncthreads();
    unsigned* outp = (unsigned*)wfb + (l*8 + kt)*16384;
    for (int f2 = t; f2 < 16384; f2 += 256) {
      const int j2 = f2 & 3, lane = (f2 >> 2) & 63, ntg = f2 >> 8;
      const int seg = ntg >> 4;
      const int e = (ntg & 15)*16 + (lane & 15);
      const int dl = ((lane >> 4) & 3)*8 + j2*2;
      unsigned short r0 = ls[seg*8192 + e*32 + dl];
      unsigned short r1 = ls[seg*8192 + e*32 + dl + 1];
      if (seg == 1) { r0 = bfr(bfu(r0)*0.0625f); r1 = bfr(bfu(r1)*0.0625f); }
      else if (seg == 2) {
        const unsigned short w0 = ls[3*8192 + e*32 + dl];
        const unsigned short w1 = ls[3*8192 + e*32 + dl + 1];
        r0 = bfr(bfu(r0) + bfu(w0)); r1 = bfr(bfu(r1) + bfu(w1));
      }
      outp[f2] = (unsigned)r0 | ((unsigned)r1 << 16);
    }
    return;
  }
  blk -= 16;
  if (blk < 48) {   // ---- B: w3b (l,gm,kt)
    unsigned short* ls = (unsigned short*)psm;
    unsigned* lsu = (unsigned*)psm;
    const int l3 = blk >> 3, kt = blk & 7;
    const int l = l3 / 3, gm = l3 % 3;
    const void* src = (gm == 0) ? rw2 : (gm == 1) ? mw1 : mw2;
    if (fl) {
      const unsigned* sp = (const unsigned*)src;
      for (int i = t; i < 4096; i += 256) {
        const int e = i >> 4, d2 = i & 15;
        lsu[i] = sp[(l*256 + e)*128 + kt*16 + d2];
      }
    } else {
      const float* sp = (const float*)src;
      for (int i = t; i < 4096; i += 256) {
        const int e = i >> 4, d2 = i & 15;
        const float f0 = sp[(l*256 + e)*256 + kt*32 + d2*2];
        const float f1 = sp[(l*256 + e)*256 + kt*32 + d2*2 + 1];
        lsu[i] = (unsigned)bfr(f0) | ((unsigned)bfr(f1) << 16);
      }
    }
    __syncthreads();
    unsigned* outp = (unsigned*)w3b + (l3*8 + kt)*4096;
    for (int f2 = t; f2 < 4096; f2 += 256) {
      const int j2 = f2 & 3, lane = (f2 >> 2) & 63, nt = f2 >> 8;
      const int e = nt*16 + (lane & 15);
      const int dl = ((lane >> 4) & 3)*8 + j2*2;
      outp[f2] = (unsigned)ls[e*32 + dl] | ((unsigned)ls[e*32 + dl + 1] << 16);
    }
    return;
  }
  blk -= 48;
  if (blk < 24) {   // ---- D: wh transposes
    float* lsf = (float*)psm;
    if (blk < 8) {          // projT
      const int l0 = blk*16;
      if (fl) {
        const unsigned* sp = (const unsigned*)pw;
        for (int i = t; i < 2048; i += 256) {
          const int ll = i >> 7, d2 = i & 127;
          const unsigned u = sp[(l0 + ll)*128 + d2];
          lsf[ll*256 + d2*2]     = __uint_as_float(u << 16);
          lsf[ll*256 + d2*2 + 1] = __uint_as_float(u & 0xffff0000u);
        }
      } else {
        const float* sp = (const float*)pw;
        for (int i = t; i < 4096; i += 256) {
          const int ll = i >> 8, d = i & 255;
          lsf[ll*256 + d] = sp[(l0 + ll)*256 + d];
        }
      }
      __syncthreads();
      for (int i = t; i < 4096; i += 256) {
        const int d = i >> 4, ll = i & 15;
        wh[d*128 + l0 + ll] = lsf[ll*256 + d];
      }
    } else {                // muT / spT
      const int grp2 = blk - 8;
      const int isSp = grp2 >> 3;
      const int l0 = (grp2 & 7)*16;
      const void* src = isSp ? spw : muw;
      const int off = isSp ? 49152 : 32768;
      if (fl) {
        const unsigned* sp = (const unsigned*)src;
        for (int i = t; i < 1024; i += 256) {
          const int ll = i >> 6, c2 = i & 63;
          const unsigned u = sp[(l0 + ll)*64 + c2];
          lsf[ll*128 + c2*2]     = __uint_as_float(u << 16);
          lsf[ll*128 + c2*2 + 1] = __uint_as_float(u & 0xffff0000u);
        }
      } else {
        const float* sp = (const float*)src;
        for (int i = t; i < 2048; i += 256) {
          const int ll = i >> 7, c = i & 127;
          lsf[ll*128 + c] = sp[(l0 + ll)*128 + c];
        }
      }
      __syncthreads();
      for (int i = t; i < 2048; i += 256) {
        const int c = i >> 4, ll = i & 15;
        wh[off + c*128 + l0 + ll] = lsf[ll*128 + c];
      }
    }
    return;
  }
  // ---- E: bc
  for (int i = t; i < 3456; i += 256) {
    const void* src; int off;
    if (i < 512)       { src = rb1; off = i; }
    else if (i < 1024) { src = rb2; off = i - 512; }
    else if (i < 1536) { src = lng; off = i - 1024; }
    else if (i < 2048) { src = lnb; off = i - 1536; }
    else if (i < 2560) { src = mb1; off = i - 2048; }
    else if (i < 3072) { src = mb2; off = i - 2560; }
    else if (i < 3200) { src = pb;  off = i - 3072; }
    else if (i < 3328) { src = mub; off = i - 3200; }
    else               { src = spb; off = i - 3328; }
    bc[i] = load_f(src, off, fl);
  }
}

// ---------------------------------------------------------------------------
// k1 body: 16 rows x (waves*NTG*16) cols from staged A-frags
// ---------------------------------------------------------------------------
template<bool SPLIT, int NTG>
__device__ __forceinline__ void k1_body(
    const unsigned short (&aF)[2][4096],
    const unsigned short* __restrict__ wfb, const float* __restrict__ bc,
    float* __restrict__ kq, float* __restrict__ Pf, unsigned* __restrict__ Qpk,
    int l, int row0, int ntg0, int t)
{
  const int w = t >> 6, l64 = t & 63;
  const int col = l64 & 15, quad = l64 >> 4;
  f32x4 acc[NTG];
  #pragma unroll
  for (int i = 0; i < NTG; ++i) acc[i] = (f32x4){0.f, 0.f, 0.f, 0.f};
  for (int kt = 0; kt < 8; ++kt) {
    const bf16x8 ah = *(const bf16x8*)&aF[0][kt*512 + l64*8];
    bf16x8 al;
    if (SPLIT) al = *(const bf16x8*)&aF[1][kt*512 + l64*8];
    #pragma unroll
    for (int i = 0; i < NTG; ++i) {
      const int ntg = ntg0 + w*NTG + i;
      const bf16x8 b = *(const bf16x8*)&wfb[((l*8 + kt)*64 + ntg)*512 + l64*8];
      acc[i] = __builtin_amdgcn_mfma_f32_16x16x32_bf16(ah, b, acc[i], 0, 0, 0);
      if (SPLIT) acc[i] = __builtin_amdgcn_mfma_f32_16x16x32_bf16(al, b, acc[i], 0, 0, 0);
    }
  }
  #pragma unroll
  for (int i = 0; i < NTG; ++i) {
    const int ntg = ntg0 + w*NTG + i;
    if (ntg < 32) {
      const int n = ntg*16 + col;
      #pragma unroll
      for (int r = 0; r < 4; ++r)
        kq[(size_t)(row0 + quad*4 + r)*512 + n] = acc[i][r];
    } else if (ntg < 48) {
      const int c = (ntg - 32)*16 + col;
      const float bias = bc[l*256 + c];
      #pragma unroll
      for (int r = 0; r < 4; ++r)
        Pf[(size_t)(row0 + quad*4 + r)*256 + c] = acc[i][r] + bias;
    } else {
      #pragma unroll
      for (int r = 0; r < 4; ++r) {
        const float v = acc[i][r];
        const float pv = __shfl_xor(v, 1, 64);
        if (!(col & 1)) {
          const unsigned uu = (unsigned)bfr(v) | ((unsigned)bfr(pv) << 16);
          Qpk[(size_t)(row0 + quad*4 + r)*128 + (ntg - 48)*8 + (col >> 1)] = uu;
        }
      }
    }
  }
}

// ---------------------------------------------------------------------------
// k1 layer-0: 512 blocks (128 m x 4 n) x 256 thr   [unchanged from R12]
// ---------------------------------------------------------------------------
__global__ __launch_bounds__(256) void k1l0(
    const void* __restrict__ X, const unsigned short* __restrict__ wfb,
    const float* __restrict__ bc, float* __restrict__ kq, float* __restrict__ Pf,
    unsigned* __restrict__ Qpk)
{
  const int fl = block_detect(X);
  __shared__ __align__(16) unsigned short aF[2][4096];
  const int t = threadIdx.x;
  const int mb = (int)blockIdx.x >> 2, nb4 = (int)blockIdx.x & 3;
  const int row0 = mb * 16, ntg0 = nb4 * 16;
  if (fl) {
    for (int i = t; i < 512; i += 256) {
      const int row = i >> 5, d0 = (i & 31) * 8;
      const uint4 u = *(const uint4*)((const unsigned*)X + (size_t)(row0 + row)*128 + (i & 31)*4);
      const int kt = d0 >> 5, lane = row | (((d0 >> 3) & 3) << 4);
      *(uint4*)&aF[0][kt*512 + lane*8] = u;
    }
  } else {
    for (int i = t; i < 1024; i += 256) {
      const int row = i >> 6, d0 = (i & 63) * 4;
      stage_split4(aF, row, d0, *(const float4*)((const float*)X + (size_t)(row0 + row)*256 + d0));
    }
  }
  __syncthreads();
  if (fl) k1_body<false, 4>(aF, wfb, bc, kq, Pf, Qpk, 0, row0, ntg0, t);
  else    k1_body<true,  4>(aF, wfb, bc, kq, Pf, Qpk, 0, row0, ntg0, t);
}

// ---------------------------------------------------------------------------
// attn_phase<NR>: scores + softmax + gelu-weighted agg for OWN NR rows.
// 512 thr. g result left in qg (aliases the q staging buffer). Math is
// op-for-op identical to the old k23 (same dot split, reduce order, sigmoid).
// ---------------------------------------------------------------------------
template<int NR>
__device__ __forceinline__ void attn_phase(
    const float* __restrict__ kq, const float* __restrict__ Pf,
    const unsigned* __restrict__ Qpk,
    int row0, int t, float* qg, float* scp, float* als)
{
  const int base = row0 & ~63;               // b*64
  // 1. stage own q rows
  for (int i = t; i < NR*64; i += 512) {
    const int il = i >> 6, d0 = (i & 63)*4;
    *(float4*)&qg[il*256 + d0] = *(const float4*)&kq[(size_t)(row0 + il)*512 + 256 + d0];
  }
  __syncthreads();
  const int w = t >> 6, lane = t & 63;
  // 2. scores: wave-group (w>>2) handles alternating i-pairs; j = (w&3)*16+jl
  {
    const int jl = lane & 15, part = lane >> 4;
    const int j = (w & 3)*16 + jl;
    for (int p = 0; p < NR/4; ++p) {
      const int i0 = (p*2 + (w >> 2))*2;
      const float* krow = kq + (size_t)(base + j)*512 + part*64;
      const float* q0p = &qg[i0*256 + part*64];
      const float* q1p = &qg[(i0+1)*256 + part*64];
      float s0 = 0.f, s1 = 0.f;
      for (int dd = 0; dd < 64; dd += 4) {
        const float4 kv = *(const float4*)&krow[dd];
        const float4 q0 = *(const float4*)&q0p[dd];
        const float4 q1 = *(const float4*)&q1p[dd];
        s0 = fmaf(kv.x, q0.x, s0); s0 = fmaf(kv.y, q0.y, s0);
        s0 = fmaf(kv.z, q0.z, s0); s0 = fmaf(kv.w, q0.w, s0);
        s1 = fmaf(kv.x, q1.x, s1); s1 = fmaf(kv.y, q1.y, s1);
        s1 = fmaf(kv.z, q1.z, s1); s1 = fmaf(kv.w, q1.w, s1);
      }
      s0 += __shfl_xor(s0, 16, 64); s0 += __shfl_xor(s0, 32, 64);
      s1 += __shfl_xor(s1, 16, 64); s1 += __shfl_xor(s1, 32, 64);
      if (part == 0) { scp[i0*64 + j] = s0; scp[(i0+1)*64 + j] = s1; }
    }
  }
  __syncthreads();
  // 3. softmax per row (one row per wave per pass)
  for (int r = w; r < NR; r += 8) {
    float s = scp[r*64 + lane];
    float m = s;
    #pragma unroll
    for (int off = 32; off; off >>= 1) m = fmaxf(m, __shfl_xor(m, off, 64));
    const float e = __expf(s - m);
    float ss = e;
    #pragma unroll
    for (int off = 32; off; off >>= 1) ss += __shfl_xor(ss, off, 64);
    als[r*64 + lane] = e / ss;
  }
  __syncthreads();
  // 4. agg: thread = (row-block, col-pair); Qpk load reused across RK rows
  {
    constexpr int RK = NR/4;
    const int cp = t & 127, rb4 = t >> 7;
    float Px[RK], Py[RK], A0[RK], A1[RK], a0[RK], a1[RK];
    #pragma unroll
    for (int k = 0; k < RK; ++k) {
      const float2 P = *(const float2*)&Pf[(size_t)(row0 + rb4*RK + k)*256 + cp*2];
      Px[k] = P.x; Py[k] = P.y;
      A0[k] = -1.702f * P.x; A1[k] = -1.702f * P.y;
      a0[k] = 0.f; a1[k] = 0.f;
    }
    const unsigned* qp = Qpk + (size_t)base*128 + cp;
    #pragma unroll 4
    for (int j = 0; j < 64; ++j) {
      const unsigned u = qp[j*128];
      const float q0 = __uint_as_float(u << 16);
      const float q1 = __uint_as_float(u & 0xffff0000u);
      #pragma unroll
      for (int k = 0; k < RK; ++k) {
        const float wgt = als[(rb4*RK + k)*64 + j];
        const float s0 = __builtin_amdgcn_rcpf(1.f + __expf(fmaf(1.702f, q0, A0[k])));
        const float s1 = __builtin_amdgcn_rcpf(1.f + __expf(fmaf(1.702f, q1, A1[k])));
        a0[k] = fmaf(wgt * (Px[k] - q0), s0, a0[k]);
        a1[k] = fmaf(wgt * (Py[k] - q1), s1, a1[k]);
      }
    }
    #pragma unroll
    for (int k = 0; k < RK; ++k) {       // qg last read 2 syncs ago -> safe
      qg[(rb4*RK + k)*256 + cp*2]     = a0[k];
      qg[(rb4*RK + k)*256 + cp*2 + 1] = a1[k];
    }
  }
  __syncthreads();                        // g (in qg) ready for k4_core
}

// ---------------------------------------------------------------------------
// k4 core (512 thr): agg=g@rw2^T+rb2; h=LN(xin+agg); out=xin+mlp(h)
// g now comes from LDS (gl), not global.
// ---------------------------------------------------------------------------
__device__ __forceinline__ void k4_gemm8(
    f32x4 acc[2], const unsigned short (&aF)[2][4096],
    const unsigned short* __restrict__ wg, int w, int l64)
{
  acc[0] = (f32x4){0.f, 0.f, 0.f, 0.f};
  acc[1] = (f32x4){0.f, 0.f, 0.f, 0.f};
  for (int kt = 0; kt < 8; ++kt) {
    const bf16x8 ah = *(const bf16x8*)&aF[0][kt*512 + l64*8];
    const bf16x8 al = *(const bf16x8*)&aF[1][kt*512 + l64*8];
    #pragma unroll
    for (int nt = 0; nt < 2; ++nt) {
      const bf16x8 b = *(const bf16x8*)&wg[((kt*16 + (w*2 + nt))*64 + l64)*8];
      acc[nt] = __builtin_amdgcn_mfma_f32_16x16x32_bf16(ah, b, acc[nt], 0, 0, 0);
      acc[nt] = __builtin_amdgcn_mfma_f32_16x16x32_bf16(al, b, acc[nt], 0, 0, 0);
    }
  }
}

template<bool ADAPT, bool TAIL, int NR>
__device__ __forceinline__ void k4_core(
    const float* gl, const void* __restrict__ xin, int fl,
    float* __restrict__ xout, const unsigned short* __restrict__ wg,
    const float* __restrict__ bc, int l, int row0, int t, bool writeX,
    unsigned short (&aF)[2][4096], float* bufB, float (&mv)[16][2])
{
  const int w = t >> 6, l64 = t & 63;
  const int col = l64 & 15, quad = l64 >> 4;
  const float* rb2c = bc + 512  + l*256;
  const float* lngc = bc + 1024 + l*256;
  const float* lnbc = bc + 1536 + l*256;
  const float* mb1c = bc + 2048 + l*256;
  const float* mb2c = bc + 2560 + l*256;

  for (int i = t; i < NR*64; i += 512) {
    const int row = i >> 6, d0 = (i & 63) * 4;
    stage_split4(aF, row, d0, *(const float4*)&gl[row*256 + d0]);
  }
  if (ADAPT && fl) {
    for (int c = t; c < NR*128; c += 512) {
      const int row = c >> 7, dp = c & 127;
      const unsigned u = ((const unsigned*)xin)[(size_t)(row0 + row)*128 + dp];
      bufB[row*260 + dp*2]     = __uint_as_float(u << 16);
      bufB[row*260 + dp*2 + 1] = __uint_as_float(u & 0xffff0000u);
    }
  } else {
    for (int c = t; c < NR*64; c += 512) {
      const int row = c >> 6, d0 = (c & 63) * 4;
      *(float4*)&bufB[row*260 + d0] = *(const float4*)((const float*)xin + (size_t)(row0 + row)*256 + d0);
    }
  }
  __syncthreads();
  float xtr[2][4];
  #pragma unroll
  for (int nt = 0; nt < 2; ++nt) {
    const int cn = (w*2 + nt)*16 + col;
    #pragma unroll
    for (int r = 0; r < 4; ++r) xtr[nt][r] = bufB[(quad*4 + r)*260 + cn];
  }
  __syncthreads();

  f32x4 acc[2];
  k4_gemm8(acc, aF, wg, w, l64);               // GEMM1
  #pragma unroll
  for (int nt = 0; nt < 2; ++nt) {
    const int cn = (w*2 + nt)*16 + col;
    #pragma unroll
    for (int r = 0; r < 4; ++r)
      bufB[(quad*4 + r)*260 + cn] = acc[nt][r] + rb2c[cn] + xtr[nt][r];
  }
  __syncthreads();
  {                                            // LN stats
    const int row = t >> 5, part = t & 31;
    if (row < NR) {
      float s = 0.f, s2 = 0.f;
      #pragma unroll
      for (int kk = 0; kk < 8; ++kk) {
        const float v = bufB[row*260 + part + kk*32];
        s += v; s2 = fmaf(v, v, s2);
      }
      #pragma unroll
      for (int off = 16; off; off >>= 1) {
        s  += __shfl_xor(s, off, 32);
        s2 += __shfl_xor(s2, off, 32);
      }
      if (part == 0) {
        const float mu = s * (1.f/256.f);
        mv[row][0] = mu;
        mv[row][1] = rsqrtf(fmaf(-mu, mu, s2 * (1.f/256.f)) + 1e-5f);
      }
    }
  }
  __syncthreads();
  for (int i = t; i < NR*64; i += 512) {       // LN apply + restage
    const int row = i >> 6, d0 = (i & 63) * 4;
    float4 v = *(const float4*)&bufB[row*260 + d0];
    const float m = mv[row][0], iv = mv[row][1];
    v.x = (v.x - m)*iv*lngc[d0]   + lnbc[d0];
    v.y = (v.y - m)*iv*lngc[d0+1] + lnbc[d0+1];
    v.z = (v.z - m)*iv*lngc[d0+2] + lnbc[d0+2];
    v.w = (v.w - m)*iv*lngc[d0+3] + lnbc[d0+3];
    stage_split4(aF, row, d0, v);
  }
  __syncthreads();
  k4_gemm8(acc, aF, wg + 65536, w, l64);       // GEMM2 + gelu
  #pragma unroll
  for (int nt = 0; nt < 2; ++nt) {
    const int cn = (w*2 + nt)*16 + col;
    #pragma unroll
    for (int r = 0; r < 4; ++r)
      if (quad*4 + r < NR)
        bufB[(quad*4 + r)*260 + cn] = gelu_e(acc[nt][r] + mb1c[cn]);
  }
  __syncthreads();
  for (int i = t; i < NR*64; i += 512) {       // restage
    const int row = i >> 6, d0 = (i & 63) * 4;
    stage_split4(aF, row, d0, *(const float4*)&bufB[row*260 + d0]);
  }
  __syncthreads();
  k4_gemm8(acc, aF, wg + 2*65536, w, l64);     // GEMM3 + residual
  if (TAIL) {
    #pragma unroll
    for (int nt = 0; nt < 2; ++nt) {
      const int cn = (w*2 + nt)*16 + col;
      #pragma unroll
      for (int r = 0; r < 4; ++r)
        bufB[(quad*4 + r)*260 + cn] = acc[nt][r] + mb2c[cn] + xtr[nt][r];
    }
    __syncthreads();
    for (int i = t; i < NR*64; i += 512) {     // coalesced x write + restage
      const int row = i >> 6, d0 = (i & 63) * 4;
      const float4 v = *(const float4*)&bufB[row*260 + d0];
      if (writeX) *(float4*)&xout[(size_t)(row0 + row)*256 + d0] = v;
      stage_split4(aF, row, d0, v);
    }
    __syncthreads();
  } else {
    #pragma unroll
    for (int nt = 0; nt < 2; ++nt) {
      const int cn = (w*2 + nt)*16 + col;
      #pragma unroll
      for (int r = 0; r < 4; ++r)
        if (quad*4 + r < NR)
          xout[(size_t)(row0 + quad*4 + r)*256 + cn] = acc[nt][r] + mb2c[cn] + xtr[nt][r];
    }
  }
}

// ---------------------------------------------------------------------------
// kA: attn(l0) + layer-0 mix + layer-1 k1
// 256 blocks (128 row-tiles x 2 parity), 512 thr.
// Reads l0 kq/Pf/Qpk; writes l1 kq1/Pf1/Qpk1 (double-buffered -> no race).
// ---------------------------------------------------------------------------
__global__ __launch_bounds__(512) void kA_attn_mix_kq(
    const unsigned short* __restrict__ w3b, const unsigned short* __restrict__ wfb,
    const float* __restrict__ bc, const void* __restrict__ X, float* __restrict__ x,
    const float* __restrict__ kq, const float* __restrict__ Pf,
    const unsigned* __restrict__ Qpk,
    float* __restrict__ kq1, float* __restrict__ Pf1, unsigned* __restrict__ Qpk1)
{
  const int fl = block_detect(X);
  __shared__ __align__(16) unsigned short aF[2][4096];
  __shared__ __align__(16) float bufB[16*260];
  __shared__ float mv[16][2];
  __shared__ __align__(16) float qg[16*256];
  __shared__ float scp[16*64];
  __shared__ float als[16*64];
  const int t = threadIdx.x;
  const int rb = (int)blockIdx.x >> 1, parity = (int)blockIdx.x & 1;
  const int row0 = rb * 16;
  attn_phase<16>(kq, Pf, Qpk, row0, t, qg, scp, als);
  k4_core<true, true, 16>(qg, X, fl, x, w3b, bc, 0, row0, t, parity == 0, aF, bufB, mv);
  k1_body<true, 4>(aF, wfb, bc, kq1, Pf1, Qpk1, 1, row0, parity*32, t);
}

// ---------------------------------------------------------------------------
// kB: attn(l1) + layer-1 mix -> x; 256 blocks x 8 rows, 512 thr
// ---------------------------------------------------------------------------
__global__ __launch_bounds__(512) void kB_attn_fin(
    const unsigned short* __restrict__ w3b, const float* __restrict__ bc,
    float* __restrict__ x, const float* __restrict__ kq1,
    const float* __restrict__ Pf1, const unsigned* __restrict__ Qpk1)
{
  __shared__ __align__(16) unsigned short aF[2][4096];
  __shared__ __align__(16) float bufB[16*260];
  __shared__ float mv[16][2];
  __shared__ __align__(16) float qg[8*256];
  __shared__ float scp[8*64];
  __shared__ float als[8*64];
  const int t = threadIdx.x;
  const int row0 = (int)blockIdx.x * 8;
  attn_phase<8>(kq1, Pf1, Qpk1, row0, t, qg, scp, als);
  k4_core<false, false, 8>(qg, x, 0, x, w3b + 3*65536, bc, 1, row0, t, true, aF, bufB, mv);
}

// ---------------------------------------------------------------------------
// k5: s=sum_K x ; h=gelu(s@projT+pb) ; mu=h@muT+mb ; scale=softplus(h@spT+sb)
// [unchanged from R12]
// ---------------------------------------------------------------------------
__global__ __launch_bounds__(256) void k5_head(
    const float* __restrict__ x, const float* __restrict__ wh,
    const float* __restrict__ bc, const void* __restrict__ X,
    void* __restrict__ out)
{
  const int fl = block_detect(X);
  __shared__ float ss[256];
  __shared__ float hh[128];
  const int b = blockIdx.x, t = threadIdx.x;
  float s = 0.f;
  for (int i = 0; i < 64; ++i) s += x[(size_t)((b << 6) + i)*256 + t];
  ss[t] = s;
  __syncthreads();
  if (t < 128) {
    float acc = bc[3072 + t];
    const float* projT = wh;
    for (int d = 0; d < 256; ++d) acc = fmaf(ss[d], projT[d*128 + t], acc);
    hh[t] = gelu_e(acc);
  }
  __syncthreads();
  float v; int oidx;
  if (t < 128) {
    float acc = bc[3200 + t];
    const float* muT = wh + 32768;
    for (int c = 0; c < 128; ++c) acc = fmaf(hh[c], muT[c*128 + t], acc);
    v = acc; oidx = b*128 + t;
  } else {
    const int u = t - 128;
    float acc = bc[3328 + u];
    const float* spT = wh + 49152;
    for (int c = 0; c < 128; ++c) acc = fmaf(hh[c], spT[c*128 + u], acc);
    v = (acc > 20.f) ? acc : log1pf(__expf(acc));
    oidx = 4096 + b*128 + u;
  }
  if (fl) ((bf16*)out)[oidx] = __float2bfloat16(v);
  else    ((float*)out)[oidx] = v;
}

// ---------------------------------------------------------------------------
extern "C" void kernel_launch(void* const* d_in, const int* in_sizes, int n_in,
                              void* d_out, int out_size, void* d_ws, size_t ws_size,
                              hipStream_t stream)
{
  (void)in_sizes; (void)n_in; (void)out_size; (void)ws_size;
  float* ws    = (float*)d_ws;
  float* x     = ws + 16;                          // 524288
  float* kq    = x + 524288;                       // 1048576  (layer 0)
  float* Pf    = kq + 1048576;                     // 524288   (layer 0)
  unsigned* Qpk = (unsigned*)(Pf + 524288);        // 262144   (layer 0)
  float* g     = (float*)(Qpk + 262144);           // 524288   (unused now)
  unsigned short* wfb = (unsigned short*)(g + 524288);   // 524288 shorts
  unsigned short* w3b = wfb + 524288;              // 393216 shorts
  float* wh    = (float*)(w3b + 393216);           // 65536
  float* bc    = wh + 65536;                       // 3456
  float* kq1   = bc + 4096;                        // 1048576  (layer 1)
  float* Pf1   = kq1 + 1048576;                    // 524288   (layer 1)
  unsigned* Qpk1 = (unsigned*)(Pf1 + 524288);      // 262144   (layer 1)

  prep_kernel<<<dim3(89), dim3(256), 0, stream>>>(
      d_in[0], d_in[1], d_in[2], d_in[3], d_in[5], d_in[9], d_in[11],
      d_in[13], d_in[15], d_in[17],
      d_in[4], d_in[6], d_in[7], d_in[8], d_in[10], d_in[12],
      d_in[14], d_in[16], d_in[18],
      wfb, w3b, wh, bc);
  k1l0<<<dim3(512), dim3(256), 0, stream>>>(d_in[0], wfb, bc, kq, Pf, Qpk);
  kA_attn_mix_kq<<<dim3(256), dim3(512), 0, stream>>>(
      w3b, wfb, bc, d_in[0], x, kq, Pf, Qpk, kq1, Pf1, Qpk1);
  kB_attn_fin<<<dim3(256), dim3(512), 0, stream>>>(w3b, bc, x, kq1, Pf1, Qpk1);
  k5_head<<<dim3(32), dim3(256), 0, stream>>>(x, wh, bc, d_in[0], (void*)d_out);
}

// Round 4
// 208.098 us; speedup vs baseline: 2.0589x; 1.0366x over previous
//
#include <hip/hip_runtime.h>
#include <hip/hip_bf16.h>

// B=32, K=64, D=256, LS=128, rows = 2048
// R16 = R15 with kA's parity-twin duplication removed:
//       kA' = 256 blocks x 8 rows: attn<8> + k4_core<8> + k1_body(l1, NTG=8,
//             row-guarded). No block computes anything twice (R15's kA ran
//             attn<16>+k4_core<16> identically in both parity twins).
//       kB unchanged (attn<8> + mix, already duplication-free). 5 launches.

using bf16 = __hip_bfloat16;
typedef short bf16x8 __attribute__((ext_vector_type(8)));
typedef float f32x4 __attribute__((ext_vector_type(4)));

__device__ __forceinline__ float bfu(unsigned short u) { return __uint_as_float(((unsigned)u) << 16); }

__device__ __forceinline__ unsigned short bfr(float v) {   // RNE fp32->bf16 bits
  unsigned u = __float_as_uint(v);
  u += 0x7FFFu + ((u >> 16) & 1u);
  return (unsigned short)(u >> 16);
}

__device__ __forceinline__ float gelu_e(float x) {
  return 0.5f * x * (1.0f + erff(x * 0.7071067811865475f));
}

__device__ __forceinline__ float load_f(const void* p, int i, int fl) {
  if (fl) return bfu(((const unsigned short*)p)[i]);
  return ((const float*)p)[i];
}

// per-block inline dtype detect: 1 = inputs are bf16
__device__ __forceinline__ int block_detect(const void* X) {
  __shared__ int bad_s;
  if (threadIdx.x == 0) bad_s = 0;
  __syncthreads();
  if (threadIdx.x < 256) {
    const float v = bfu(((const unsigned short*)X)[threadIdx.x]);
    if (!(fabsf(v) < 1e6f)) atomicOr(&bad_s, 1);
  }
  __syncthreads();
  return bad_s ? 0 : 1;
}

// stage one float4 (row, d0) into hi/lo MFMA A-fragments
__device__ __forceinline__ void stage_split4(unsigned short (&aF)[2][4096], int row, int d0, float4 v) {
  ushort4 h, lo;
  h.x = bfr(v.x); h.y = bfr(v.y); h.z = bfr(v.z); h.w = bfr(v.w);
  lo.x = bfr(v.x - bfu(h.x)); lo.y = bfr(v.y - bfu(h.y));
  lo.z = bfr(v.z - bfu(h.z)); lo.w = bfr(v.w - bfu(h.w));
  const int kt = d0 >> 5, lane = row | (((d0 >> 3) & 3) << 4), j = d0 & 7;
  *(ushort4*)&aF[0][kt*512 + lane*8 + j] = h;
  *(ushort4*)&aF[1][kt*512 + lane*8 + j] = lo;
}

// ---------------------------------------------------------------------------
// prep (89 blocks x 256 thr): weights -> ws   [unchanged]
// ---------------------------------------------------------------------------
__global__ __launch_bounds__(256) void prep_kernel(
    const void* __restrict__ X, const void* __restrict__ kw, const void* __restrict__ qw,
    const void* __restrict__ rw1, const void* __restrict__ rw2, const void* __restrict__ mw1,
    const void* __restrict__ mw2, const void* __restrict__ pw, const void* __restrict__ muw,
    const void* __restrict__ spw,
    const void* __restrict__ rb1, const void* __restrict__ rb2, const void* __restrict__ lng,
    const void* __restrict__ lnb, const void* __restrict__ mb1, const void* __restrict__ mb2,
    const void* __restrict__ pb, const void* __restrict__ mub, const void* __restrict__ spb,
    unsigned short* __restrict__ wfb, unsigned short* __restrict__ w3b,
    float* __restrict__ wh, float* __restrict__ bc)
{
  __shared__ __align__(16) char psm[65536];
  const int fl = block_detect(X);
  const int t = threadIdx.x;
  int blk = blockIdx.x;

  if (blk < 16) {   // ---- A: wfb (l,kt)
    unsigned short* ls = (unsigned short*)psm;
    unsigned* lsu = (unsigned*)psm;
    const int l = blk >> 3, kt = blk & 7;
    if (fl) {
      #pragma unroll
      for (int s = 0; s < 4; ++s) {
        const unsigned* sp = (const unsigned*)((s == 0) ? kw : (s == 1) ? qw : rw1);
        const int rstr = (s < 2) ? 128 : 256;
        const int coff = ((s == 3) ? 128 : 0) + kt*16;
        for (int i = t; i < 4096; i += 256) {
          const int e = i >> 4, d2 = i & 15;
          lsu[s*4096 + i] = sp[(l*256 + e)*rstr + coff + d2];
        }
      }
    } else {
      #pragma unroll
      for (int s = 0; s < 4; ++s) {
        const float* sp = (const float*)((s == 0) ? kw : (s == 1) ? qw : rw1);
        const int rstr = (s < 2) ? 256 : 512;
        const int coff = ((s == 3) ? 256 : 0) + kt*32;
        for (int i = t; i < 4096; i += 256) {
          const int e = i >> 4, d2 = i & 15;
          const float f0 = sp[(l*256 + e)*rstr + coff + d2*2];
          const float f1 = sp[(l*256 + e)*rstr + coff + d2*2 + 1];
          lsu[s*4096 + i] = (unsigned)bfr(f0) | ((unsigned)bfr(f1) << 16);
        }
      }
    }
    __syncthreads();
    unsigned* outp = (unsigned*)wfb + (l*8 + kt)*16384;
    for (int f2 = t; f2 < 16384; f2 += 256) {
      const int j2 = f2 & 3, lane = (f2 >> 2) & 63, ntg = f2 >> 8;
      const int seg = ntg >> 4;
      const int e = (ntg & 15)*16 + (lane & 15);
      const int dl = ((lane >> 4) & 3)*8 + j2*2;
      unsigned short r0 = ls[seg*8192 + e*32 + dl];
      unsigned short r1 = ls[seg*8192 + e*32 + dl + 1];
      if (seg == 1) { r0 = bfr(bfu(r0)*0.0625f); r1 = bfr(bfu(r1)*0.0625f); }
      else if (seg == 2) {
        const unsigned short w0 = ls[3*8192 + e*32 + dl];
        const unsigned short w1 = ls[3*8192 + e*32 + dl + 1];
        r0 = bfr(bfu(r0) + bfu(w0)); r1 = bfr(bfu(r1) + bfu(w1));
      }
      outp[f2] = (unsigned)r0 | ((unsigned)r1 << 16);
    }
    return;
  }
  blk -= 16;
  if (blk < 48) {   // ---- B: w3b (l,gm,kt)
    unsigned short* ls = (unsigned short*)psm;
    unsigned* lsu = (unsigned*)psm;
    const int l3 = blk >> 3, kt = blk & 7;
    const int l = l3 / 3, gm = l3 % 3;
    const void* src = (gm == 0) ? rw2 : (gm == 1) ? mw1 : mw2;
    if (fl) {
      const unsigned* sp = (const unsigned*)src;
      for (int i = t; i < 4096; i += 256) {
        const int e = i >> 4, d2 = i & 15;
        lsu[i] = sp[(l*256 + e)*128 + kt*16 + d2];
      }
    } else {
      const float* sp = (const float*)src;
      for (int i = t; i < 4096; i += 256) {
        const int e = i >> 4, d2 = i & 15;
        const float f0 = sp[(l*256 + e)*256 + kt*32 + d2*2];
        const float f1 = sp[(l*256 + e)*256 + kt*32 + d2*2 + 1];
        lsu[i] = (unsigned)bfr(f0) | ((unsigned)bfr(f1) << 16);
      }
    }
    __syncthreads();
    unsigned* outp = (unsigned*)w3b + (l3*8 + kt)*4096;
    for (int f2 = t; f2 < 4096; f2 += 256) {
      const int j2 = f2 & 3, lane = (f2 >> 2) & 63, nt = f2 >> 8;
      const int e = nt*16 + (lane & 15);
      const int dl = ((lane >> 4) & 3)*8 + j2*2;
      outp[f2] = (unsigned)ls[e*32 + dl] | ((unsigned)ls[e*32 + dl + 1] << 16);
    }
    return;
  }
  blk -= 48;
  if (blk < 24) {   // ---- D: wh transposes
    float* lsf = (float*)psm;
    if (blk < 8) {          // projT
      const int l0 = blk*16;
      if (fl) {
        const unsigned* sp = (const unsigned*)pw;
        for (int i = t; i < 2048; i += 256) {
          const int ll = i >> 7, d2 = i & 127;
          const unsigned u = sp[(l0 + ll)*128 + d2];
          lsf[ll*256 + d2*2]     = __uint_as_float(u << 16);
          lsf[ll*256 + d2*2 + 1] = __uint_as_float(u & 0xffff0000u);
        }
      } else {
        const float* sp = (const float*)pw;
        for (int i = t; i < 4096; i += 256) {
          const int ll = i >> 8, d = i & 255;
          lsf[ll*256 + d] = sp[(l0 + ll)*256 + d];
        }
      }
      __syncthreads();
      for (int i = t; i < 4096; i += 256) {
        const int d = i >> 4, ll = i & 15;
        wh[d*128 + l0 + ll] = lsf[ll*256 + d];
      }
    } else {                // muT / spT
      const int grp2 = blk - 8;
      const int isSp = grp2 >> 3;
      const int l0 = (grp2 & 7)*16;
      const void* src = isSp ? spw : muw;
      const int off = isSp ? 49152 : 32768;
      if (fl) {
        const unsigned* sp = (const unsigned*)src;
        for (int i = t; i < 1024; i += 256) {
          const int ll = i >> 6, c2 = i & 63;
          const unsigned u = sp[(l0 + ll)*64 + c2];
          lsf[ll*128 + c2*2]     = __uint_as_float(u << 16);
          lsf[ll*128 + c2*2 + 1] = __uint_as_float(u & 0xffff0000u);
        }
      } else {
        const float* sp = (const float*)src;
        for (int i = t; i < 2048; i += 256) {
          const int ll = i >> 7, c = i & 127;
          lsf[ll*128 + c] = sp[(l0 + ll)*128 + c];
        }
      }
      __syncthreads();
      for (int i = t; i < 2048; i += 256) {
        const int c = i >> 4, ll = i & 15;
        wh[off + c*128 + l0 + ll] = lsf[ll*128 + c];
      }
    }
    return;
  }
  // ---- E: bc
  for (int i = t; i < 3456; i += 256) {
    const void* src; int off;
    if (i < 512)       { src = rb1; off = i; }
    else if (i < 1024) { src = rb2; off = i - 512; }
    else if (i < 1536) { src = lng; off = i - 1024; }
    else if (i < 2048) { src = lnb; off = i - 1536; }
    else if (i < 2560) { src = mb1; off = i - 2048; }
    else if (i < 3072) { src = mb2; off = i - 2560; }
    else if (i < 3200) { src = pb;  off = i - 3072; }
    else if (i < 3328) { src = mub; off = i - 3200; }
    else               { src = spb; off = i - 3328; }
    bc[i] = load_f(src, off, fl);
  }
}

// ---------------------------------------------------------------------------
// k1 body: NRR rows x (waves*NTG*16) cols from staged A-frags.
// NRR<16: aF rows NRR..15 are garbage; MFMA D rows are row-independent, so
// outputs for those rows are discarded by the guards.
// ---------------------------------------------------------------------------
template<bool SPLIT, int NTG, int NRR>
__device__ __forceinline__ void k1_body(
    const unsigned short (&aF)[2][4096],
    const unsigned short* __restrict__ wfb, const float* __restrict__ bc,
    float* __restrict__ kq, float* __restrict__ Pf, unsigned* __restrict__ Qpk,
    int l, int row0, int ntg0, int t)
{
  const int w = t >> 6, l64 = t & 63;
  const int col = l64 & 15, quad = l64 >> 4;
  f32x4 acc[NTG];
  #pragma unroll
  for (int i = 0; i < NTG; ++i) acc[i] = (f32x4){0.f, 0.f, 0.f, 0.f};
  for (int kt = 0; kt < 8; ++kt) {
    const bf16x8 ah = *(const bf16x8*)&aF[0][kt*512 + l64*8];
    bf16x8 al;
    if (SPLIT) al = *(const bf16x8*)&aF[1][kt*512 + l64*8];
    #pragma unroll
    for (int i = 0; i < NTG; ++i) {
      const int ntg = ntg0 + w*NTG + i;
      const bf16x8 b = *(const bf16x8*)&wfb[((l*8 + kt)*64 + ntg)*512 + l64*8];
      acc[i] = __builtin_amdgcn_mfma_f32_16x16x32_bf16(ah, b, acc[i], 0, 0, 0);
      if (SPLIT) acc[i] = __builtin_amdgcn_mfma_f32_16x16x32_bf16(al, b, acc[i], 0, 0, 0);
    }
  }
  #pragma unroll
  for (int i = 0; i < NTG; ++i) {
    const int ntg = ntg0 + w*NTG + i;
    if (ntg < 32) {
      const int n = ntg*16 + col;
      #pragma unroll
      for (int r = 0; r < 4; ++r)
        if (NRR == 16 || quad*4 + r < NRR)
          kq[(size_t)(row0 + quad*4 + r)*512 + n] = acc[i][r];
    } else if (ntg < 48) {
      const int c = (ntg - 32)*16 + col;
      const float bias = bc[l*256 + c];
      #pragma unroll
      for (int r = 0; r < 4; ++r)
        if (NRR == 16 || quad*4 + r < NRR)
          Pf[(size_t)(row0 + quad*4 + r)*256 + c] = acc[i][r] + bias;
    } else {
      #pragma unroll
      for (int r = 0; r < 4; ++r) {
        const float v = acc[i][r];
        const float pv = __shfl_xor(v, 1, 64);
        if (!(col & 1) && (NRR == 16 || quad*4 + r < NRR)) {
          const unsigned uu = (unsigned)bfr(v) | ((unsigned)bfr(pv) << 16);
          Qpk[(size_t)(row0 + quad*4 + r)*128 + (ntg - 48)*8 + (col >> 1)] = uu;
        }
      }
    }
  }
}

// ---------------------------------------------------------------------------
// k1 layer-0: 512 blocks (128 m x 4 n) x 256 thr   [unchanged]
// ---------------------------------------------------------------------------
__global__ __launch_bounds__(256) void k1l0(
    const void* __restrict__ X, const unsigned short* __restrict__ wfb,
    const float* __restrict__ bc, float* __restrict__ kq, float* __restrict__ Pf,
    unsigned* __restrict__ Qpk)
{
  const int fl = block_detect(X);
  __shared__ __align__(16) unsigned short aF[2][4096];
  const int t = threadIdx.x;
  const int mb = (int)blockIdx.x >> 2, nb4 = (int)blockIdx.x & 3;
  const int row0 = mb * 16, ntg0 = nb4 * 16;
  if (fl) {
    for (int i = t; i < 512; i += 256) {
      const int row = i >> 5, d0 = (i & 31) * 8;
      const uint4 u = *(const uint4*)((const unsigned*)X + (size_t)(row0 + row)*128 + (i & 31)*4);
      const int kt = d0 >> 5, lane = row | (((d0 >> 3) & 3) << 4);
      *(uint4*)&aF[0][kt*512 + lane*8] = u;
    }
  } else {
    for (int i = t; i < 1024; i += 256) {
      const int row = i >> 6, d0 = (i & 63) * 4;
      stage_split4(aF, row, d0, *(const float4*)((const float*)X + (size_t)(row0 + row)*256 + d0));
    }
  }
  __syncthreads();
  if (fl) k1_body<false, 4, 16>(aF, wfb, bc, kq, Pf, Qpk, 0, row0, ntg0, t);
  else    k1_body<true,  4, 16>(aF, wfb, bc, kq, Pf, Qpk, 0, row0, ntg0, t);
}

// ---------------------------------------------------------------------------
// attn_phase<NR>: scores + softmax + gelu-weighted agg for OWN NR rows.
// 512 thr. g result left in qg. Math op-for-op identical to the old k23.
// ---------------------------------------------------------------------------
template<int NR>
__device__ __forceinline__ void attn_phase(
    const float* __restrict__ kq, const float* __restrict__ Pf,
    const unsigned* __restrict__ Qpk,
    int row0, int t, float* qg, float* scp, float* als)
{
  const int base = row0 & ~63;               // b*64
  // 1. stage own q rows
  for (int i = t; i < NR*64; i += 512) {
    const int il = i >> 6, d0 = (i & 63)*4;
    *(float4*)&qg[il*256 + d0] = *(const float4*)&kq[(size_t)(row0 + il)*512 + 256 + d0];
  }
  __syncthreads();
  const int w = t >> 6, lane = t & 63;
  // 2. scores
  {
    const int jl = lane & 15, part = lane >> 4;
    const int j = (w & 3)*16 + jl;
    for (int p = 0; p < NR/4; ++p) {
      const int i0 = (p*2 + (w >> 2))*2;
      const float* krow = kq + (size_t)(base + j)*512 + part*64;
      const float* q0p = &qg[i0*256 + part*64];
      const float* q1p = &qg[(i0+1)*256 + part*64];
      float s0 = 0.f, s1 = 0.f;
      for (int dd = 0; dd < 64; dd += 4) {
        const float4 kv = *(const float4*)&krow[dd];
        const float4 q0 = *(const float4*)&q0p[dd];
        const float4 q1 = *(const float4*)&q1p[dd];
        s0 = fmaf(kv.x, q0.x, s0); s0 = fmaf(kv.y, q0.y, s0);
        s0 = fmaf(kv.z, q0.z, s0); s0 = fmaf(kv.w, q0.w, s0);
        s1 = fmaf(kv.x, q1.x, s1); s1 = fmaf(kv.y, q1.y, s1);
        s1 = fmaf(kv.z, q1.z, s1); s1 = fmaf(kv.w, q1.w, s1);
      }
      s0 += __shfl_xor(s0, 16, 64); s0 += __shfl_xor(s0, 32, 64);
      s1 += __shfl_xor(s1, 16, 64); s1 += __shfl_xor(s1, 32, 64);
      if (part == 0) { scp[i0*64 + j] = s0; scp[(i0+1)*64 + j] = s1; }
    }
  }
  __syncthreads();
  // 3. softmax per row
  for (int r = w; r < NR; r += 8) {
    float s = scp[r*64 + lane];
    float m = s;
    #pragma unroll
    for (int off = 32; off; off >>= 1) m = fmaxf(m, __shfl_xor(m, off, 64));
    const float e = __expf(s - m);
    float ss = e;
    #pragma unroll
    for (int off = 32; off; off >>= 1) ss += __shfl_xor(ss, off, 64);
    als[r*64 + lane] = e / ss;
  }
  __syncthreads();
  // 4. agg
  {
    constexpr int RK = NR/4;
    const int cp = t & 127, rb4 = t >> 7;
    float Px[RK], Py[RK], A0[RK], A1[RK], a0[RK], a1[RK];
    #pragma unroll
    for (int k = 0; k < RK; ++k) {
      const float2 P = *(const float2*)&Pf[(size_t)(row0 + rb4*RK + k)*256 + cp*2];
      Px[k] = P.x; Py[k] = P.y;
      A0[k] = -1.702f * P.x; A1[k] = -1.702f * P.y;
      a0[k] = 0.f; a1[k] = 0.f;
    }
    const unsigned* qp = Qpk + (size_t)base*128 + cp;
    #pragma unroll 4
    for (int j = 0; j < 64; ++j) {
      const unsigned u = qp[j*128];
      const float q0 = __uint_as_float(u << 16);
      const float q1 = __uint_as_float(u & 0xffff0000u);
      #pragma unroll
      for (int k = 0; k < RK; ++k) {
        const float wgt = als[(rb4*RK + k)*64 + j];
        const float s0 = __builtin_amdgcn_rcpf(1.f + __expf(fmaf(1.702f, q0, A0[k])));
        const float s1 = __builtin_amdgcn_rcpf(1.f + __expf(fmaf(1.702f, q1, A1[k])));
        a0[k] = fmaf(wgt * (Px[k] - q0), s0, a0[k]);
        a1[k] = fmaf(wgt * (Py[k] - q1), s1, a1[k]);
      }
    }
    #pragma unroll
    for (int k = 0; k < RK; ++k) {
      qg[(rb4*RK + k)*256 + cp*2]     = a0[k];
      qg[(rb4*RK + k)*256 + cp*2 + 1] = a1[k];
    }
  }
  __syncthreads();                        // g (in qg) ready for k4_core
}

// ---------------------------------------------------------------------------
// k4 core (512 thr): agg=g@rw2^T+rb2; h=LN(xin+agg); out=xin+mlp(h)
// ---------------------------------------------------------------------------
__device__ __forceinline__ void k4_gemm8(
    f32x4 acc[2], const unsigned short (&aF)[2][4096],
    const unsigned short* __restrict__ wg, int w, int l64)
{
  acc[0] = (f32x4){0.f, 0.f, 0.f, 0.f};
  acc[1] = (f32x4){0.f, 0.f, 0.f, 0.f};
  for (int kt = 0; kt < 8; ++kt) {
    const bf16x8 ah = *(const bf16x8*)&aF[0][kt*512 + l64*8];
    const bf16x8 al = *(const bf16x8*)&aF[1][kt*512 + l64*8];
    #pragma unroll
    for (int nt = 0; nt < 2; ++nt) {
      const bf16x8 b = *(const bf16x8*)&wg[((kt*16 + (w*2 + nt))*64 + l64)*8];
      acc[nt] = __builtin_amdgcn_mfma_f32_16x16x32_bf16(ah, b, acc[nt], 0, 0, 0);
      acc[nt] = __builtin_amdgcn_mfma_f32_16x16x32_bf16(al, b, acc[nt], 0, 0, 0);
    }
  }
}

template<bool ADAPT, bool TAIL, int NR>
__device__ __forceinline__ void k4_core(
    const float* gl, const void* __restrict__ xin, int fl,
    float* __restrict__ xout, const unsigned short* __restrict__ wg,
    const float* __restrict__ bc, int l, int row0, int t, bool writeX,
    unsigned short (&aF)[2][4096], float* bufB, float (&mv)[16][2])
{
  const int w = t >> 6, l64 = t & 63;
  const int col = l64 & 15, quad = l64 >> 4;
  const float* rb2c = bc + 512  + l*256;
  const float* lngc = bc + 1024 + l*256;
  const float* lnbc = bc + 1536 + l*256;
  const float* mb1c = bc + 2048 + l*256;
  const float* mb2c = bc + 2560 + l*256;

  for (int i = t; i < NR*64; i += 512) {
    const int row = i >> 6, d0 = (i & 63) * 4;
    stage_split4(aF, row, d0, *(const float4*)&gl[row*256 + d0]);
  }
  if (ADAPT && fl) {
    for (int c = t; c < NR*128; c += 512) {
      const int row = c >> 7, dp = c & 127;
      const unsigned u = ((const unsigned*)xin)[(size_t)(row0 + row)*128 + dp];
      bufB[row*260 + dp*2]     = __uint_as_float(u << 16);
      bufB[row*260 + dp*2 + 1] = __uint_as_float(u & 0xffff0000u);
    }
  } else {
    for (int c = t; c < NR*64; c += 512) {
      const int row = c >> 6, d0 = (c & 63) * 4;
      *(float4*)&bufB[row*260 + d0] = *(const float4*)((const float*)xin + (size_t)(row0 + row)*256 + d0);
    }
  }
  __syncthreads();
  float xtr[2][4];
  #pragma unroll
  for (int nt = 0; nt < 2; ++nt) {
    const int cn = (w*2 + nt)*16 + col;
    #pragma unroll
    for (int r = 0; r < 4; ++r) xtr[nt][r] = bufB[(quad*4 + r)*260 + cn];
  }
  __syncthreads();

  f32x4 acc[2];
  k4_gemm8(acc, aF, wg, w, l64);               // GEMM1
  #pragma unroll
  for (int nt = 0; nt < 2; ++nt) {
    const int cn = (w*2 + nt)*16 + col;
    #pragma unroll
    for (int r = 0; r < 4; ++r)
      bufB[(quad*4 + r)*260 + cn] = acc[nt][r] + rb2c[cn] + xtr[nt][r];
  }
  __syncthreads();
  {                                            // LN stats
    const int row = t >> 5, part = t & 31;
    if (row < NR) {
      float s = 0.f, s2 = 0.f;
      #pragma unroll
      for (int kk = 0; kk < 8; ++kk) {
        const float v = bufB[row*260 + part + kk*32];
        s += v; s2 = fmaf(v, v, s2);
      }
      #pragma unroll
      for (int off = 16; off; off >>= 1) {
        s  += __shfl_xor(s, off, 32);
        s2 += __shfl_xor(s2, off, 32);
      }
      if (part == 0) {
        const float mu = s * (1.f/256.f);
        mv[row][0] = mu;
        mv[row][1] = rsqrtf(fmaf(-mu, mu, s2 * (1.f/256.f)) + 1e-5f);
      }
    }
  }
  __syncthreads();
  for (int i = t; i < NR*64; i += 512) {       // LN apply + restage
    const int row = i >> 6, d0 = (i & 63) * 4;
    float4 v = *(const float4*)&bufB[row*260 + d0];
    const float m = mv[row][0], iv = mv[row][1];
    v.x = (v.x - m)*iv*lngc[d0]   + lnbc[d0];
    v.y = (v.y - m)*iv*lngc[d0+1] + lnbc[d0+1];
    v.z = (v.z - m)*iv*lngc[d0+2] + lnbc[d0+2];
    v.w = (v.w - m)*iv*lngc[d0+3] + lnbc[d0+3];
    stage_split4(aF, row, d0, v);
  }
  __syncthreads();
  k4_gemm8(acc, aF, wg + 65536, w, l64);       // GEMM2 + gelu
  #pragma unroll
  for (int nt = 0; nt < 2; ++nt) {
    const int cn = (w*2 + nt)*16 + col;
    #pragma unroll
    for (int r = 0; r < 4; ++r)
      if (quad*4 + r < NR)
        bufB[(quad*4 + r)*260 + cn] = gelu_e(acc[nt][r] + mb1c[cn]);
  }
  __syncthreads();
  for (int i = t; i < NR*64; i += 512) {       // restage
    const int row = i >> 6, d0 = (i & 63) * 4;
    stage_split4(aF, row, d0, *(const float4*)&bufB[row*260 + d0]);
  }
  __syncthreads();
  k4_gemm8(acc, aF, wg + 2*65536, w, l64);     // GEMM3 + residual
  if (TAIL) {
    #pragma unroll
    for (int nt = 0; nt < 2; ++nt) {
      const int cn = (w*2 + nt)*16 + col;
      #pragma unroll
      for (int r = 0; r < 4; ++r)
        bufB[(quad*4 + r)*260 + cn] = acc[nt][r] + mb2c[cn] + xtr[nt][r];
    }
    __syncthreads();
    for (int i = t; i < NR*64; i += 512) {     // coalesced x write + restage
      const int row = i >> 6, d0 = (i & 63) * 4;
      const float4 v = *(const float4*)&bufB[row*260 + d0];
      if (writeX) *(float4*)&xout[(size_t)(row0 + row)*256 + d0] = v;
      stage_split4(aF, row, d0, v);
    }
    __syncthreads();
  } else {
    #pragma unroll
    for (int nt = 0; nt < 2; ++nt) {
      const int cn = (w*2 + nt)*16 + col;
      #pragma unroll
      for (int r = 0; r < 4; ++r)
        if (quad*4 + r < NR)
          xout[(size_t)(row0 + quad*4 + r)*256 + cn] = acc[nt][r] + mb2c[cn] + xtr[nt][r];
    }
  }
}

// ---------------------------------------------------------------------------
// kA': attn(l0) + layer-0 mix + layer-1 k1; 256 blocks x 8 rows, 512 thr.
// No duplication: each block owns rows [bid*8, bid*8+8).
// ---------------------------------------------------------------------------
__global__ __launch_bounds__(512) void kA_attn_mix_kq(
    const unsigned short* __restrict__ w3b, const unsigned short* __restrict__ wfb,
    const float* __restrict__ bc, const void* __restrict__ X, float* __restrict__ x,
    const float* __restrict__ kq, const float* __restrict__ Pf,
    const unsigned* __restrict__ Qpk,
    float* __restrict__ kq1, float* __restrict__ Pf1, unsigned* __restrict__ Qpk1)
{
  const int fl = block_detect(X);
  __shared__ __align__(16) unsigned short aF[2][4096];
  __shared__ __align__(16) float bufB[16*260];
  __shared__ float mv[16][2];
  __shared__ __align__(16) float qg[8*256];
  __shared__ float scp[8*64];
  __shared__ float als[8*64];
  const int t = threadIdx.x;
  const int row0 = (int)blockIdx.x * 8;
  attn_phase<8>(kq, Pf, Qpk, row0, t, qg, scp, als);
  k4_core<true, true, 8>(qg, X, fl, x, w3b, bc, 0, row0, t, true, aF, bufB, mv);
  k1_body<true, 8, 8>(aF, wfb, bc, kq1, Pf1, Qpk1, 1, row0, 0, t);
}

// ---------------------------------------------------------------------------
// kB: attn(l1) + layer-1 mix -> x; 256 blocks x 8 rows, 512 thr  [unchanged]
// ---------------------------------------------------------------------------
__global__ __launch_bounds__(512) void kB_attn_fin(
    const unsigned short* __restrict__ w3b, const float* __restrict__ bc,
    float* __restrict__ x, const float* __restrict__ kq1,
    const float* __restrict__ Pf1, const unsigned* __restrict__ Qpk1)
{
  __shared__ __align__(16) unsigned short aF[2][4096];
  __shared__ __align__(16) float bufB[16*260];
  __shared__ float mv[16][2];
  __shared__ __align__(16) float qg[8*256];
  __shared__ float scp[8*64];
  __shared__ float als[8*64];
  const int t = threadIdx.x;
  const int row0 = (int)blockIdx.x * 8;
  attn_phase<8>(kq1, Pf1, Qpk1, row0, t, qg, scp, als);
  k4_core<false, false, 8>(qg, x, 0, x, w3b + 3*65536, bc, 1, row0, t, true, aF, bufB, mv);
}

// ---------------------------------------------------------------------------
// k5: s=sum_K x ; h=gelu(s@projT+pb) ; mu=h@muT+mb ; scale=softplus(h@spT+sb)
// [unchanged]
// ---------------------------------------------------------------------------
__global__ __launch_bounds__(256) void k5_head(
    const float* __restrict__ x, const float* __restrict__ wh,
    const float* __restrict__ bc, const void* __restrict__ X,
    void* __restrict__ out)
{
  const int fl = block_detect(X);
  __shared__ float ss[256];
  __shared__ float hh[128];
  const int b = blockIdx.x, t = threadIdx.x;
  float s = 0.f;
  for (int i = 0; i < 64; ++i) s += x[(size_t)((b << 6) + i)*256 + t];
  ss[t] = s;
  __syncthreads();
  if (t < 128) {
    float acc = bc[3072 + t];
    const float* projT = wh;
    for (int d = 0; d < 256; ++d) acc = fmaf(ss[d], projT[d*128 + t], acc);
    hh[t] = gelu_e(acc);
  }
  __syncthreads();
  float v; int oidx;
  if (t < 128) {
    float acc = bc[3200 + t];
    const float* muT = wh + 32768;
    for (int c = 0; c < 128; ++c) acc = fmaf(hh[c], muT[c*128 + t], acc);
    v = acc; oidx = b*128 + t;
  } else {
    const int u = t - 128;
    float acc = bc[3328 + u];
    const float* spT = wh + 49152;
    for (int c = 0; c < 128; ++c) acc = fmaf(hh[c], spT[c*128 + u], acc);
    v = (acc > 20.f) ? acc : log1pf(__expf(acc));
    oidx = 4096 + b*128 + u;
  }
  if (fl) ((bf16*)out)[oidx] = __float2bfloat16(v);
  else    ((float*)out)[oidx] = v;
}

// ---------------------------------------------------------------------------
extern "C" void kernel_launch(void* const* d_in, const int* in_sizes, int n_in,
                              void* d_out, int out_size, void* d_ws, size_t ws_size,
                              hipStream_t stream)
{
  (void)in_sizes; (void)n_in; (void)out_size; (void)ws_size;
  float* ws    = (float*)d_ws;
  float* x     = ws + 16;                          // 524288
  float* kq    = x + 524288;                       // 1048576  (layer 0)
  float* Pf    = kq + 1048576;                     // 524288   (layer 0)
  unsigned* Qpk = (unsigned*)(Pf + 524288);        // 262144   (layer 0)
  float* g     = (float*)(Qpk + 262144);           // 524288   (unused)
  unsigned short* wfb = (unsigned short*)(g + 524288);   // 524288 shorts
  unsigned short* w3b = wfb + 524288;              // 393216 shorts
  float* wh    = (float*)(w3b + 393216);           // 65536
  float* bc    = wh + 65536;                       // 3456
  float* kq1   = bc + 4096;                        // 1048576  (layer 1)
  float* Pf1   = kq1 + 1048576;                    // 524288   (layer 1)
  unsigned* Qpk1 = (unsigned*)(Pf1 + 524288);      // 262144   (layer 1)

  prep_kernel<<<dim3(89), dim3(256), 0, stream>>>(
      d_in[0], d_in[1], d_in[2], d_in[3], d_in[5], d_in[9], d_in[11],
      d_in[13], d_in[15], d_in[17],
      d_in[4], d_in[6], d_in[7], d_in[8], d_in[10], d_in[12],
      d_in[14], d_in[16], d_in[18],
      wfb, w3b, wh, bc);
  k1l0<<<dim3(512), dim3(256), 0, stream>>>(d_in[0], wfb, bc, kq, Pf, Qpk);
  kA_attn_mix_kq<<<dim3(256), dim3(512), 0, stream>>>(
      w3b, wfb, bc, d_in[0], x, kq, Pf, Qpk, kq1, Pf1, Qpk1);
  kB_attn_fin<<<dim3(256), dim3(512), 0, stream>>>(w3b, bc, x, kq1, Pf1, Qpk1);
  k5_head<<<dim3(32), dim3(256), 0, stream>>>(x, wh, bc, d_in[0], (void*)d_out);
}

// Round 5
// 202.362 us; speedup vs baseline: 2.1173x; 1.0283x over previous
//
#include <hip/hip_runtime.h>
#include <hip/hip_bf16.h>

// B=32, K=64, D=256, LS=128, rows = 2048
// R17 = R16 + attn made MLP-friendly: K rows (bf16-packed) and Qpk block staged
//       into LDS with wide cooperative loads; scores+agg read LDS only.
//       (R16 post-mortem: kA latency-bound at 500 GB/s — scattered per-thread
//       global loads with VGPR=52 can't fill the memory pipe.)
//       + k5 row-sum with 4 independent accumulators.

using bf16 = __hip_bfloat16;
typedef short bf16x8 __attribute__((ext_vector_type(8)));
typedef float f32x4 __attribute__((ext_vector_type(4)));

__device__ __forceinline__ float bfu(unsigned short u) { return __uint_as_float(((unsigned)u) << 16); }

__device__ __forceinline__ unsigned short bfr(float v) {   // RNE fp32->bf16 bits
  unsigned u = __float_as_uint(v);
  u += 0x7FFFu + ((u >> 16) & 1u);
  return (unsigned short)(u >> 16);
}

__device__ __forceinline__ float gelu_e(float x) {
  return 0.5f * x * (1.0f + erff(x * 0.7071067811865475f));
}

__device__ __forceinline__ float load_f(const void* p, int i, int fl) {
  if (fl) return bfu(((const unsigned short*)p)[i]);
  return ((const float*)p)[i];
}

// per-block inline dtype detect: 1 = inputs are bf16
__device__ __forceinline__ int block_detect(const void* X) {
  __shared__ int bad_s;
  if (threadIdx.x == 0) bad_s = 0;
  __syncthreads();
  if (threadIdx.x < 256) {
    const float v = bfu(((const unsigned short*)X)[threadIdx.x]);
    if (!(fabsf(v) < 1e6f)) atomicOr(&bad_s, 1);
  }
  __syncthreads();
  return bad_s ? 0 : 1;
}

// stage one float4 (row, d0) into hi/lo MFMA A-fragments
__device__ __forceinline__ void stage_split4(unsigned short (&aF)[2][4096], int row, int d0, float4 v) {
  ushort4 h, lo;
  h.x = bfr(v.x); h.y = bfr(v.y); h.z = bfr(v.z); h.w = bfr(v.w);
  lo.x = bfr(v.x - bfu(h.x)); lo.y = bfr(v.y - bfu(h.y));
  lo.z = bfr(v.z - bfu(h.z)); lo.w = bfr(v.w - bfu(h.w));
  const int kt = d0 >> 5, lane = row | (((d0 >> 3) & 3) << 4), j = d0 & 7;
  *(ushort4*)&aF[0][kt*512 + lane*8 + j] = h;
  *(ushort4*)&aF[1][kt*512 + lane*8 + j] = lo;
}

// ---------------------------------------------------------------------------
// prep (89 blocks x 256 thr): weights -> ws   [unchanged]
// ---------------------------------------------------------------------------
__global__ __launch_bounds__(256) void prep_kernel(
    const void* __restrict__ X, const void* __restrict__ kw, const void* __restrict__ qw,
    const void* __restrict__ rw1, const void* __restrict__ rw2, const void* __restrict__ mw1,
    const void* __restrict__ mw2, const void* __restrict__ pw, const void* __restrict__ muw,
    const void* __restrict__ spw,
    const void* __restrict__ rb1, const void* __restrict__ rb2, const void* __restrict__ lng,
    const void* __restrict__ lnb, const void* __restrict__ mb1, const void* __restrict__ mb2,
    const void* __restrict__ pb, const void* __restrict__ mub, const void* __restrict__ spb,
    unsigned short* __restrict__ wfb, unsigned short* __restrict__ w3b,
    float* __restrict__ wh, float* __restrict__ bc)
{
  __shared__ __align__(16) char psm[65536];
  const int fl = block_detect(X);
  const int t = threadIdx.x;
  int blk = blockIdx.x;

  if (blk < 16) {   // ---- A: wfb (l,kt)
    unsigned short* ls = (unsigned short*)psm;
    unsigned* lsu = (unsigned*)psm;
    const int l = blk >> 3, kt = blk & 7;
    if (fl) {
      #pragma unroll
      for (int s = 0; s < 4; ++s) {
        const unsigned* sp = (const unsigned*)((s == 0) ? kw : (s == 1) ? qw : rw1);
        const int rstr = (s < 2) ? 128 : 256;
        const int coff = ((s == 3) ? 128 : 0) + kt*16;
        for (int i = t; i < 4096; i += 256) {
          const int e = i >> 4, d2 = i & 15;
          lsu[s*4096 + i] = sp[(l*256 + e)*rstr + coff + d2];
        }
      }
    } else {
      #pragma unroll
      for (int s = 0; s < 4; ++s) {
        const float* sp = (const float*)((s == 0) ? kw : (s == 1) ? qw : rw1);
        const int rstr = (s < 2) ? 256 : 512;
        const int coff = ((s == 3) ? 256 : 0) + kt*32;
        for (int i = t; i < 4096; i += 256) {
          const int e = i >> 4, d2 = i & 15;
          const float f0 = sp[(l*256 + e)*rstr + coff + d2*2];
          const float f1 = sp[(l*256 + e)*rstr + coff + d2*2 + 1];
          lsu[s*4096 + i] = (unsigned)bfr(f0) | ((unsigned)bfr(f1) << 16);
        }
      }
    }
    __syncthreads();
    unsigned* outp = (unsigned*)wfb + (l*8 + kt)*16384;
    for (int f2 = t; f2 < 16384; f2 += 256) {
      const int j2 = f2 & 3, lane = (f2 >> 2) & 63, ntg = f2 >> 8;
      const int seg = ntg >> 4;
      const int e = (ntg & 15)*16 + (lane & 15);
      const int dl = ((lane >> 4) & 3)*8 + j2*2;
      unsigned short r0 = ls[seg*8192 + e*32 + dl];
      unsigned short r1 = ls[seg*8192 + e*32 + dl + 1];
      if (seg == 1) { r0 = bfr(bfu(r0)*0.0625f); r1 = bfr(bfu(r1)*0.0625f); }
      else if (seg == 2) {
        const unsigned short w0 = ls[3*8192 + e*32 + dl];
        const unsigned short w1 = ls[3*8192 + e*32 + dl + 1];
        r0 = bfr(bfu(r0) + bfu(w0)); r1 = bfr(bfu(r1) + bfu(w1));
      }
      outp[f2] = (unsigned)r0 | ((unsigned)r1 << 16);
    }
    return;
  }
  blk -= 16;
  if (blk < 48) {   // ---- B: w3b (l,gm,kt)
    unsigned short* ls = (unsigned short*)psm;
    unsigned* lsu = (unsigned*)psm;
    const int l3 = blk >> 3, kt = blk & 7;
    const int l = l3 / 3, gm = l3 % 3;
    const void* src = (gm == 0) ? rw2 : (gm == 1) ? mw1 : mw2;
    if (fl) {
      const unsigned* sp = (const unsigned*)src;
      for (int i = t; i < 4096; i += 256) {
        const int e = i >> 4, d2 = i & 15;
        lsu[i] = sp[(l*256 + e)*128 + kt*16 + d2];
      }
    } else {
      const float* sp = (const float*)src;
      for (int i = t; i < 4096; i += 256) {
        const int e = i >> 4, d2 = i & 15;
        const float f0 = sp[(l*256 + e)*256 + kt*32 + d2*2];
        const float f1 = sp[(l*256 + e)*256 + kt*32 + d2*2 + 1];
        lsu[i] = (unsigned)bfr(f0) | ((unsigned)bfr(f1) << 16);
      }
    }
    __syncthreads();
    unsigned* outp = (unsigned*)w3b + (l3*8 + kt)*4096;
    for (int f2 = t; f2 < 4096; f2 += 256) {
      const int j2 = f2 & 3, lane = (f2 >> 2) & 63, nt = f2 >> 8;
      const int e = nt*16 + (lane & 15);
      const int dl = ((lane >> 4) & 3)*8 + j2*2;
      outp[f2] = (unsigned)ls[e*32 + dl] | ((unsigned)ls[e*32 + dl + 1] << 16);
    }
    return;
  }
  blk -= 48;
  if (blk < 24) {   // ---- D: wh transposes
    float* lsf = (float*)psm;
    if (blk < 8) {          // projT
      const int l0 = blk*16;
      if (fl) {
        const unsigned* sp = (const unsigned*)pw;
        for (int i = t; i < 2048; i += 256) {
          const int ll = i >> 7, d2 = i & 127;
          const unsigned u = sp[(l0 + ll)*128 + d2];
          lsf[ll*256 + d2*2]     = __uint_as_float(u << 16);
          lsf[ll*256 + d2*2 + 1] = __uint_as_float(u & 0xffff0000u);
        }
      } else {
        const float* sp = (const float*)pw;
        for (int i = t; i < 4096; i += 256) {
          const int ll = i >> 8, d = i & 255;
          lsf[ll*256 + d] = sp[(l0 + ll)*256 + d];
        }
      }
      __syncthreads();
      for (int i = t; i < 4096; i += 256) {
        const int d = i >> 4, ll = i & 15;
        wh[d*128 + l0 + ll] = lsf[ll*256 + d];
      }
    } else {                // muT / spT
      const int grp2 = blk - 8;
      const int isSp = grp2 >> 3;
      const int l0 = (grp2 & 7)*16;
      const void* src = isSp ? spw : muw;
      const int off = isSp ? 49152 : 32768;
      if (fl) {
        const unsigned* sp = (const unsigned*)src;
        for (int i = t; i < 1024; i += 256) {
          const int ll = i >> 6, c2 = i & 63;
          const unsigned u = sp[(l0 + ll)*64 + c2];
          lsf[ll*128 + c2*2]     = __uint_as_float(u << 16);
          lsf[ll*128 + c2*2 + 1] = __uint_as_float(u & 0xffff0000u);
        }
      } else {
        const float* sp = (const float*)src;
        for (int i = t; i < 2048; i += 256) {
          const int ll = i >> 7, c = i & 127;
          lsf[ll*128 + c] = sp[(l0 + ll)*128 + c];
        }
      }
      __syncthreads();
      for (int i = t; i < 2048; i += 256) {
        const int c = i >> 4, ll = i & 15;
        wh[off + c*128 + l0 + ll] = lsf[ll*128 + c];
      }
    }
    return;
  }
  // ---- E: bc
  for (int i = t; i < 3456; i += 256) {
    const void* src; int off;
    if (i < 512)       { src = rb1; off = i; }
    else if (i < 1024) { src = rb2; off = i - 512; }
    else if (i < 1536) { src = lng; off = i - 1024; }
    else if (i < 2048) { src = lnb; off = i - 1536; }
    else if (i < 2560) { src = mb1; off = i - 2048; }
    else if (i < 3072) { src = mb2; off = i - 2560; }
    else if (i < 3200) { src = pb;  off = i - 3072; }
    else if (i < 3328) { src = mub; off = i - 3200; }
    else               { src = spb; off = i - 3328; }
    bc[i] = load_f(src, off, fl);
  }
}

// ---------------------------------------------------------------------------
// k1 body: NRR rows x (waves*NTG*16) cols from staged A-frags.
// ---------------------------------------------------------------------------
template<bool SPLIT, int NTG, int NRR>
__device__ __forceinline__ void k1_body(
    const unsigned short (&aF)[2][4096],
    const unsigned short* __restrict__ wfb, const float* __restrict__ bc,
    float* __restrict__ kq, float* __restrict__ Pf, unsigned* __restrict__ Qpk,
    int l, int row0, int ntg0, int t)
{
  const int w = t >> 6, l64 = t & 63;
  const int col = l64 & 15, quad = l64 >> 4;
  f32x4 acc[NTG];
  #pragma unroll
  for (int i = 0; i < NTG; ++i) acc[i] = (f32x4){0.f, 0.f, 0.f, 0.f};
  for (int kt = 0; kt < 8; ++kt) {
    const bf16x8 ah = *(const bf16x8*)&aF[0][kt*512 + l64*8];
    bf16x8 al;
    if (SPLIT) al = *(const bf16x8*)&aF[1][kt*512 + l64*8];
    #pragma unroll
    for (int i = 0; i < NTG; ++i) {
      const int ntg = ntg0 + w*NTG + i;
      const bf16x8 b = *(const bf16x8*)&wfb[((l*8 + kt)*64 + ntg)*512 + l64*8];
      acc[i] = __builtin_amdgcn_mfma_f32_16x16x32_bf16(ah, b, acc[i], 0, 0, 0);
      if (SPLIT) acc[i] = __builtin_amdgcn_mfma_f32_16x16x32_bf16(al, b, acc[i], 0, 0, 0);
    }
  }
  #pragma unroll
  for (int i = 0; i < NTG; ++i) {
    const int ntg = ntg0 + w*NTG + i;
    if (ntg < 32) {
      const int n = ntg*16 + col;
      #pragma unroll
      for (int r = 0; r < 4; ++r)
        if (NRR == 16 || quad*4 + r < NRR)
          kq[(size_t)(row0 + quad*4 + r)*512 + n] = acc[i][r];
    } else if (ntg < 48) {
      const int c = (ntg - 32)*16 + col;
      const float bias = bc[l*256 + c];
      #pragma unroll
      for (int r = 0; r < 4; ++r)
        if (NRR == 16 || quad*4 + r < NRR)
          Pf[(size_t)(row0 + quad*4 + r)*256 + c] = acc[i][r] + bias;
    } else {
      #pragma unroll
      for (int r = 0; r < 4; ++r) {
        const float v = acc[i][r];
        const float pv = __shfl_xor(v, 1, 64);
        if (!(col & 1) && (NRR == 16 || quad*4 + r < NRR)) {
          const unsigned uu = (unsigned)bfr(v) | ((unsigned)bfr(pv) << 16);
          Qpk[(size_t)(row0 + quad*4 + r)*128 + (ntg - 48)*8 + (col >> 1)] = uu;
        }
      }
    }
  }
}

// ---------------------------------------------------------------------------
// k1 layer-0: 512 blocks (128 m x 4 n) x 256 thr   [unchanged]
// ---------------------------------------------------------------------------
__global__ __launch_bounds__(256) void k1l0(
    const void* __restrict__ X, const unsigned short* __restrict__ wfb,
    const float* __restrict__ bc, float* __restrict__ kq, float* __restrict__ Pf,
    unsigned* __restrict__ Qpk)
{
  const int fl = block_detect(X);
  __shared__ __align__(16) unsigned short aF[2][4096];
  const int t = threadIdx.x;
  const int mb = (int)blockIdx.x >> 2, nb4 = (int)blockIdx.x & 3;
  const int row0 = mb * 16, ntg0 = nb4 * 16;
  if (fl) {
    for (int i = t; i < 512; i += 256) {
      const int row = i >> 5, d0 = (i & 31) * 8;
      const uint4 u = *(const uint4*)((const unsigned*)X + (size_t)(row0 + row)*128 + (i & 31)*4);
      const int kt = d0 >> 5, lane = row | (((d0 >> 3) & 3) << 4);
      *(uint4*)&aF[0][kt*512 + lane*8] = u;
    }
  } else {
    for (int i = t; i < 1024; i += 256) {
      const int row = i >> 6, d0 = (i & 63) * 4;
      stage_split4(aF, row, d0, *(const float4*)((const float*)X + (size_t)(row0 + row)*256 + d0));
    }
  }
  __syncthreads();
  if (fl) k1_body<false, 4, 16>(aF, wfb, bc, kq, Pf, Qpk, 0, row0, ntg0, t);
  else    k1_body<true,  4, 16>(aF, wfb, bc, kq, Pf, Qpk, 0, row0, ntg0, t);
}

// ---------------------------------------------------------------------------
// attn_phase<NR>: scores + softmax + gelu-weighted agg for OWN NR rows.
// 512 thr. K rows (bf16-packed) + Qpk block staged into LDS with wide
// cooperative loads (MLP burst); scores+agg read LDS only. g left in qg.
// ---------------------------------------------------------------------------
template<int NR>
__device__ __forceinline__ void attn_phase(
    const float* __restrict__ kq, const float* __restrict__ Pf,
    const unsigned* __restrict__ Qpk,
    int row0, int t, float* qg, float* scp, float* als,
    unsigned* Kst, unsigned* Qst)
{
  const int base = row0 & ~63;               // b*64
  // 1a. stage own q rows (fp32)
  for (int i = t; i < NR*64; i += 512) {
    const int il = i >> 6, d0 = (i & 63)*4;
    *(float4*)&qg[il*256 + d0] = *(const float4*)&kq[(size_t)(row0 + il)*512 + 256 + d0];
  }
  // 1b. stage K rows bf16-packed: Kst[64][132] u32 (132-stride breaks banks)
  for (int i = t; i < 4096; i += 512) {
    const int row = i >> 6, c4 = i & 63;
    const float4 v = *(const float4*)&kq[(size_t)(base + row)*512 + c4*4];
    Kst[row*132 + c4*2]     = (unsigned)bfr(v.x) | ((unsigned)bfr(v.y) << 16);
    Kst[row*132 + c4*2 + 1] = (unsigned)bfr(v.z) | ((unsigned)bfr(v.w) << 16);
  }
  // 1c. stage Qpk block: Qst[64][128] u32
  for (int i = t; i < 2048; i += 512) {
    const int row = i >> 5, c4 = i & 31;
    *(uint4*)&Qst[row*128 + c4*4] = *(const uint4*)&Qpk[(size_t)(base + row)*128 + c4*4];
  }
  __syncthreads();
  const int w = t >> 6, lane = t & 63;
  // 2. scores (K bf16 from LDS; q fp32 from LDS)
  {
    const int jl = lane & 15, part = lane >> 4;
    const int j = (w & 3)*16 + jl;
    for (int p = 0; p < NR/4; ++p) {
      const int i0 = (p*2 + (w >> 2))*2;
      const unsigned* kr = &Kst[j*132 + part*32];
      const float* q0p = &qg[i0*256 + part*64];
      const float* q1p = &qg[(i0+1)*256 + part*64];
      float s0 = 0.f, s1 = 0.f;
      #pragma unroll
      for (int d2 = 0; d2 < 32; d2 += 2) {
        const unsigned ka = kr[d2], kb = kr[d2 + 1];
        const float4 q0 = *(const float4*)&q0p[d2*2];
        const float4 q1 = *(const float4*)&q1p[d2*2];
        const float k0 = bfu((unsigned short)ka), k1 = bfu((unsigned short)(ka >> 16));
        const float k2 = bfu((unsigned short)kb), k3 = bfu((unsigned short)(kb >> 16));
        s0 = fmaf(k0, q0.x, s0); s0 = fmaf(k1, q0.y, s0);
        s0 = fmaf(k2, q0.z, s0); s0 = fmaf(k3, q0.w, s0);
        s1 = fmaf(k0, q1.x, s1); s1 = fmaf(k1, q1.y, s1);
        s1 = fmaf(k2, q1.z, s1); s1 = fmaf(k3, q1.w, s1);
      }
      s0 += __shfl_xor(s0, 16, 64); s0 += __shfl_xor(s0, 32, 64);
      s1 += __shfl_xor(s1, 16, 64); s1 += __shfl_xor(s1, 32, 64);
      if (part == 0) { scp[i0*64 + j] = s0; scp[(i0+1)*64 + j] = s1; }
    }
  }
  __syncthreads();
  // 3. softmax per row
  for (int r = w; r < NR; r += 8) {
    float s = scp[r*64 + lane];
    float m = s;
    #pragma unroll
    for (int off = 32; off; off >>= 1) m = fmaxf(m, __shfl_xor(m, off, 64));
    const float e = __expf(s - m);
    float ss = e;
    #pragma unroll
    for (int off = 32; off; off >>= 1) ss += __shfl_xor(ss, off, 64);
    als[r*64 + lane] = e / ss;
  }
  __syncthreads();
  // 4. agg (Qpk from LDS; conflict-free reads)
  {
    constexpr int RK = NR/4;
    const int cp = t & 127, rb4 = t >> 7;
    float Px[RK], Py[RK], A0[RK], A1[RK], a0[RK], a1[RK];
    #pragma unroll
    for (int k = 0; k < RK; ++k) {
      const float2 P = *(const float2*)&Pf[(size_t)(row0 + rb4*RK + k)*256 + cp*2];
      Px[k] = P.x; Py[k] = P.y;
      A0[k] = -1.702f * P.x; A1[k] = -1.702f * P.y;
      a0[k] = 0.f; a1[k] = 0.f;
    }
    const unsigned* qp = &Qst[cp];
    #pragma unroll 4
    for (int j = 0; j < 64; ++j) {
      const unsigned u = qp[j*128];
      const float q0 = __uint_as_float(u << 16);
      const float q1 = __uint_as_float(u & 0xffff0000u);
      #pragma unroll
      for (int k = 0; k < RK; ++k) {
        const float wgt = als[(rb4*RK + k)*64 + j];
        const float s0 = __builtin_amdgcn_rcpf(1.f + __expf(fmaf(1.702f, q0, A0[k])));
        const float s1 = __builtin_amdgcn_rcpf(1.f + __expf(fmaf(1.702f, q1, A1[k])));
        a0[k] = fmaf(wgt * (Px[k] - q0), s0, a0[k]);
        a1[k] = fmaf(wgt * (Py[k] - q1), s1, a1[k]);
      }
    }
    #pragma unroll
    for (int k = 0; k < RK; ++k) {
      qg[(rb4*RK + k)*256 + cp*2]     = a0[k];
      qg[(rb4*RK + k)*256 + cp*2 + 1] = a1[k];
    }
  }
  __syncthreads();                        // g (in qg) ready for k4_core
}

// ---------------------------------------------------------------------------
// k4 core (512 thr): agg=g@rw2^T+rb2; h=LN(xin+agg); out=xin+mlp(h)
// ---------------------------------------------------------------------------
__device__ __forceinline__ void k4_gemm8(
    f32x4 acc[2], const unsigned short (&aF)[2][4096],
    const unsigned short* __restrict__ wg, int w, int l64)
{
  acc[0] = (f32x4){0.f, 0.f, 0.f, 0.f};
  acc[1] = (f32x4){0.f, 0.f, 0.f, 0.f};
  for (int kt = 0; kt < 8; ++kt) {
    const bf16x8 ah = *(const bf16x8*)&aF[0][kt*512 + l64*8];
    const bf16x8 al = *(const bf16x8*)&aF[1][kt*512 + l64*8];
    #pragma unroll
    for (int nt = 0; nt < 2; ++nt) {
      const bf16x8 b = *(const bf16x8*)&wg[((kt*16 + (w*2 + nt))*64 + l64)*8];
      acc[nt] = __builtin_amdgcn_mfma_f32_16x16x32_bf16(ah, b, acc[nt], 0, 0, 0);
      acc[nt] = __builtin_amdgcn_mfma_f32_16x16x32_bf16(al, b, acc[nt], 0, 0, 0);
    }
  }
}

template<bool ADAPT, bool TAIL, int NR>
__device__ __forceinline__ void k4_core(
    const float* gl, const void* __restrict__ xin, int fl,
    float* __restrict__ xout, const unsigned short* __restrict__ wg,
    const float* __restrict__ bc, int l, int row0, int t, bool writeX,
    unsigned short (&aF)[2][4096], float* bufB, float (&mv)[16][2])
{
  const int w = t >> 6, l64 = t & 63;
  const int col = l64 & 15, quad = l64 >> 4;
  const float* rb2c = bc + 512  + l*256;
  const float* lngc = bc + 1024 + l*256;
  const float* lnbc = bc + 1536 + l*256;
  const float* mb1c = bc + 2048 + l*256;
  const float* mb2c = bc + 2560 + l*256;

  for (int i = t; i < NR*64; i += 512) {
    const int row = i >> 6, d0 = (i & 63) * 4;
    stage_split4(aF, row, d0, *(const float4*)&gl[row*256 + d0]);
  }
  if (ADAPT && fl) {
    for (int c = t; c < NR*128; c += 512) {
      const int row = c >> 7, dp = c & 127;
      const unsigned u = ((const unsigned*)xin)[(size_t)(row0 + row)*128 + dp];
      bufB[row*260 + dp*2]     = __uint_as_float(u << 16);
      bufB[row*260 + dp*2 + 1] = __uint_as_float(u & 0xffff0000u);
    }
  } else {
    for (int c = t; c < NR*64; c += 512) {
      const int row = c >> 6, d0 = (c & 63) * 4;
      *(float4*)&bufB[row*260 + d0] = *(const float4*)((const float*)xin + (size_t)(row0 + row)*256 + d0);
    }
  }
  __syncthreads();
  float xtr[2][4];
  #pragma unroll
  for (int nt = 0; nt < 2; ++nt) {
    const int cn = (w*2 + nt)*16 + col;
    #pragma unroll
    for (int r = 0; r < 4; ++r) xtr[nt][r] = bufB[(quad*4 + r)*260 + cn];
  }
  __syncthreads();

  f32x4 acc[2];
  k4_gemm8(acc, aF, wg, w, l64);               // GEMM1
  #pragma unroll
  for (int nt = 0; nt < 2; ++nt) {
    const int cn = (w*2 + nt)*16 + col;
    #pragma unroll
    for (int r = 0; r < 4; ++r)
      bufB[(quad*4 + r)*260 + cn] = acc[nt][r] + rb2c[cn] + xtr[nt][r];
  }
  __syncthreads();
  {                                            // LN stats
    const int row = t >> 5, part = t & 31;
    if (row < NR) {
      float s = 0.f, s2 = 0.f;
      #pragma unroll
      for (int kk = 0; kk < 8; ++kk) {
        const float v = bufB[row*260 + part + kk*32];
        s += v; s2 = fmaf(v, v, s2);
      }
      #pragma unroll
      for (int off = 16; off; off >>= 1) {
        s  += __shfl_xor(s, off, 32);
        s2 += __shfl_xor(s2, off, 32);
      }
      if (part == 0) {
        const float mu = s * (1.f/256.f);
        mv[row][0] = mu;
        mv[row][1] = rsqrtf(fmaf(-mu, mu, s2 * (1.f/256.f)) + 1e-5f);
      }
    }
  }
  __syncthreads();
  for (int i = t; i < NR*64; i += 512) {       // LN apply + restage
    const int row = i >> 6, d0 = (i & 63) * 4;
    float4 v = *(const float4*)&bufB[row*260 + d0];
    const float m = mv[row][0], iv = mv[row][1];
    v.x = (v.x - m)*iv*lngc[d0]   + lnbc[d0];
    v.y = (v.y - m)*iv*lngc[d0+1] + lnbc[d0+1];
    v.z = (v.z - m)*iv*lngc[d0+2] + lnbc[d0+2];
    v.w = (v.w - m)*iv*lngc[d0+3] + lnbc[d0+3];
    stage_split4(aF, row, d0, v);
  }
  __syncthreads();
  k4_gemm8(acc, aF, wg + 65536, w, l64);       // GEMM2 + gelu
  #pragma unroll
  for (int nt = 0; nt < 2; ++nt) {
    const int cn = (w*2 + nt)*16 + col;
    #pragma unroll
    for (int r = 0; r < 4; ++r)
      if (quad*4 + r < NR)
        bufB[(quad*4 + r)*260 + cn] = gelu_e(acc[nt][r] + mb1c[cn]);
  }
  __syncthreads();
  for (int i = t; i < NR*64; i += 512) {       // restage
    const int row = i >> 6, d0 = (i & 63) * 4;
    stage_split4(aF, row, d0, *(const float4*)&bufB[row*260 + d0]);
  }
  __syncthreads();
  k4_gemm8(acc, aF, wg + 2*65536, w, l64);     // GEMM3 + residual
  if (TAIL) {
    #pragma unroll
    for (int nt = 0; nt < 2; ++nt) {
      const int cn = (w*2 + nt)*16 + col;
      #pragma unroll
      for (int r = 0; r < 4; ++r)
        bufB[(quad*4 + r)*260 + cn] = acc[nt][r] + mb2c[cn] + xtr[nt][r];
    }
    __syncthreads();
    for (int i = t; i < NR*64; i += 512) {     // coalesced x write + restage
      const int row = i >> 6, d0 = (i & 63) * 4;
      const float4 v = *(const float4*)&bufB[row*260 + d0];
      if (writeX) *(float4*)&xout[(size_t)(row0 + row)*256 + d0] = v;
      stage_split4(aF, row, d0, v);
    }
    __syncthreads();
  } else {
    #pragma unroll
    for (int nt = 0; nt < 2; ++nt) {
      const int cn = (w*2 + nt)*16 + col;
      #pragma unroll
      for (int r = 0; r < 4; ++r)
        if (quad*4 + r < NR)
          xout[(size_t)(row0 + quad*4 + r)*256 + cn] = acc[nt][r] + mb2c[cn] + xtr[nt][r];
    }
  }
}

// ---------------------------------------------------------------------------
// kA': attn(l0) + layer-0 mix + layer-1 k1; 256 blocks x 8 rows, 512 thr.
// ---------------------------------------------------------------------------
__global__ __launch_bounds__(512) void kA_attn_mix_kq(
    const unsigned short* __restrict__ w3b, const unsigned short* __restrict__ wfb,
    const float* __restrict__ bc, const void* __restrict__ X, float* __restrict__ x,
    const float* __restrict__ kq, const float* __restrict__ Pf,
    const unsigned* __restrict__ Qpk,
    float* __restrict__ kq1, float* __restrict__ Pf1, unsigned* __restrict__ Qpk1)
{
  const int fl = block_detect(X);
  __shared__ __align__(16) unsigned short aF[2][4096];
  __shared__ __align__(16) float bufB[16*260];
  __shared__ float mv[16][2];
  __shared__ __align__(16) float qg[8*256];
  __shared__ float scp[8*64];
  __shared__ float als[8*64];
  __shared__ __align__(16) unsigned Kst[64*132];
  __shared__ __align__(16) unsigned Qst[64*128];
  const int t = threadIdx.x;
  const int row0 = (int)blockIdx.x * 8;
  attn_phase<8>(kq, Pf, Qpk, row0, t, qg, scp, als, Kst, Qst);
  k4_core<true, true, 8>(qg, X, fl, x, w3b, bc, 0, row0, t, true, aF, bufB, mv);
  k1_body<true, 8, 8>(aF, wfb, bc, kq1, Pf1, Qpk1, 1, row0, 0, t);
}

// ---------------------------------------------------------------------------
// kB: attn(l1) + layer-1 mix -> x; 256 blocks x 8 rows, 512 thr
// ---------------------------------------------------------------------------
__global__ __launch_bounds__(512) void kB_attn_fin(
    const unsigned short* __restrict__ w3b, const float* __restrict__ bc,
    float* __restrict__ x, const float* __restrict__ kq1,
    const float* __restrict__ Pf1, const unsigned* __restrict__ Qpk1)
{
  __shared__ __align__(16) unsigned short aF[2][4096];
  __shared__ __align__(16) float bufB[16*260];
  __shared__ float mv[16][2];
  __shared__ __align__(16) float qg[8*256];
  __shared__ float scp[8*64];
  __shared__ float als[8*64];
  __shared__ __align__(16) unsigned Kst[64*132];
  __shared__ __align__(16) unsigned Qst[64*128];
  const int t = threadIdx.x;
  const int row0 = (int)blockIdx.x * 8;
  attn_phase<8>(kq1, Pf1, Qpk1, row0, t, qg, scp, als, Kst, Qst);
  k4_core<false, false, 8>(qg, x, 0, x, w3b + 3*65536, bc, 1, row0, t, true, aF, bufB, mv);
}

// ---------------------------------------------------------------------------
// k5: s=sum_K x ; h=gelu(s@projT+pb) ; mu=h@muT+mb ; scale=softplus(h@spT+sb)
// row-sum now 4 independent accumulators (was a 64-deep serial chain).
// ---------------------------------------------------------------------------
__global__ __launch_bounds__(256) void k5_head(
    const float* __restrict__ x, const float* __restrict__ wh,
    const float* __restrict__ bc, const void* __restrict__ X,
    void* __restrict__ out)
{
  const int fl = block_detect(X);
  __shared__ float ss[256];
  __shared__ float hh[128];
  const int b = blockIdx.x, t = threadIdx.x;
  {
    const float* xp = x + (size_t)(b << 6)*256 + t;
    float s0 = 0.f, s1 = 0.f, s2 = 0.f, s3 = 0.f;
    for (int i = 0; i < 64; i += 4) {
      s0 += xp[(size_t)(i    )*256];
      s1 += xp[(size_t)(i + 1)*256];
      s2 += xp[(size_t)(i + 2)*256];
      s3 += xp[(size_t)(i + 3)*256];
    }
    ss[t] = (s0 + s1) + (s2 + s3);
  }
  __syncthreads();
  if (t < 128) {
    float acc = bc[3072 + t];
    const float* projT = wh;
    for (int d = 0; d < 256; ++d) acc = fmaf(ss[d], projT[d*128 + t], acc);
    hh[t] = gelu_e(acc);
  }
  __syncthreads();
  float v; int oidx;
  if (t < 128) {
    float acc = bc[3200 + t];
    const float* muT = wh + 32768;
    for (int c = 0; c < 128; ++c) acc = fmaf(hh[c], muT[c*128 + t], acc);
    v = acc; oidx = b*128 + t;
  } else {
    const int u = t - 128;
    float acc = bc[3328 + u];
    const float* spT = wh + 49152;
    for (int c = 0; c < 128; ++c) acc = fmaf(hh[c], spT[c*128 + u], acc);
    v = (acc > 20.f) ? acc : log1pf(__expf(acc));
    oidx = 4096 + b*128 + u;
  }
  if (fl) ((bf16*)out)[oidx] = __float2bfloat16(v);
  else    ((float*)out)[oidx] = v;
}

// ---------------------------------------------------------------------------
extern "C" void kernel_launch(void* const* d_in, const int* in_sizes, int n_in,
                              void* d_out, int out_size, void* d_ws, size_t ws_size,
                              hipStream_t stream)
{
  (void)in_sizes; (void)n_in; (void)out_size; (void)ws_size;
  float* ws    = (float*)d_ws;
  float* x     = ws + 16;                          // 524288
  float* kq    = x + 524288;                       // 1048576  (layer 0)
  float* Pf    = kq + 1048576;                     // 524288   (layer 0)
  unsigned* Qpk = (unsigned*)(Pf + 524288);        // 262144   (layer 0)
  float* g     = (float*)(Qpk + 262144);           // 524288   (unused)
  unsigned short* wfb = (unsigned short*)(g + 524288);   // 524288 shorts
  unsigned short* w3b = wfb + 524288;              // 393216 shorts
  float* wh    = (float*)(w3b + 393216);           // 65536
  float* bc    = wh + 65536;                       // 3456
  float* kq1   = bc + 4096;                        // 1048576  (layer 1)
  float* Pf1   = kq1 + 1048576;                    // 524288   (layer 1)
  unsigned* Qpk1 = (unsigned*)(Pf1 + 524288);      // 262144   (layer 1)

  prep_kernel<<<dim3(89), dim3(256), 0, stream>>>(
      d_in[0], d_in[1], d_in[2], d_in[3], d_in[5], d_in[9], d_in[11],
      d_in[13], d_in[15], d_in[17],
      d_in[4], d_in[6], d_in[7], d_in[8], d_in[10], d_in[12],
      d_in[14], d_in[16], d_in[18],
      wfb, w3b, wh, bc);
  k1l0<<<dim3(512), dim3(256), 0, stream>>>(d_in[0], wfb, bc, kq, Pf, Qpk);
  kA_attn_mix_kq<<<dim3(256), dim3(512), 0, stream>>>(
      w3b, wfb, bc, d_in[0], x, kq, Pf, Qpk, kq1, Pf1, Qpk1);
  kB_attn_fin<<<dim3(256), dim3(512), 0, stream>>>(w3b, bc, x, kq1, Pf1, Qpk1);
  k5_head<<<dim3(32), dim3(256), 0, stream>>>(x, wh, bc, d_in[0], (void*)d_out);
}

// Round 6
// 202.076 us; speedup vs baseline: 2.1203x; 1.0014x over previous
//
#include <hip/hip_runtime.h>
#include <hip/hip_bf16.h>

// B=32, K=64, D=256, LS=128, rows = 2048
// R18 = R17 + two kA/kB changes:
//   (1) LDS union: attn's Kst/Qst (66 KB) overlap k4's aF/bufB/mv (33 KB) in one
//       carved buffer -> 77 KB/block -> 2 blocks/CU (was 112 KB, 1 block/CU).
//   (2) XCD-aware block swizzle: all 8 row-blocks of a batch share bid%8 (same
//       XCD under round-robin) -> K/Qpk fetched once per batch per XCD
//       (R17 FETCH=20 MB ~ 7x unique data from cross-XCD refetch).

using bf16 = __hip_bfloat16;
typedef short bf16x8 __attribute__((ext_vector_type(8)));
typedef float f32x4 __attribute__((ext_vector_type(4)));

__device__ __forceinline__ float bfu(unsigned short u) { return __uint_as_float(((unsigned)u) << 16); }

__device__ __forceinline__ unsigned short bfr(float v) {   // RNE fp32->bf16 bits
  unsigned u = __float_as_uint(v);
  u += 0x7FFFu + ((u >> 16) & 1u);
  return (unsigned short)(u >> 16);
}

__device__ __forceinline__ float gelu_e(float x) {
  return 0.5f * x * (1.0f + erff(x * 0.7071067811865475f));
}

__device__ __forceinline__ float load_f(const void* p, int i, int fl) {
  if (fl) return bfu(((const unsigned short*)p)[i]);
  return ((const float*)p)[i];
}

// per-block inline dtype detect: 1 = inputs are bf16
__device__ __forceinline__ int block_detect(const void* X) {
  __shared__ int bad_s;
  if (threadIdx.x == 0) bad_s = 0;
  __syncthreads();
  if (threadIdx.x < 256) {
    const float v = bfu(((const unsigned short*)X)[threadIdx.x]);
    if (!(fabsf(v) < 1e6f)) atomicOr(&bad_s, 1);
  }
  __syncthreads();
  return bad_s ? 0 : 1;
}

// stage one float4 (row, d0) into hi/lo MFMA A-fragments
__device__ __forceinline__ void stage_split4(unsigned short (&aF)[2][4096], int row, int d0, float4 v) {
  ushort4 h, lo;
  h.x = bfr(v.x); h.y = bfr(v.y); h.z = bfr(v.z); h.w = bfr(v.w);
  lo.x = bfr(v.x - bfu(h.x)); lo.y = bfr(v.y - bfu(h.y));
  lo.z = bfr(v.z - bfu(h.z)); lo.w = bfr(v.w - bfu(h.w));
  const int kt = d0 >> 5, lane = row | (((d0 >> 3) & 3) << 4), j = d0 & 7;
  *(ushort4*)&aF[0][kt*512 + lane*8 + j] = h;
  *(ushort4*)&aF[1][kt*512 + lane*8 + j] = lo;
}

// ---------------------------------------------------------------------------
// prep (89 blocks x 256 thr): weights -> ws   [unchanged]
// ---------------------------------------------------------------------------
__global__ __launch_bounds__(256) void prep_kernel(
    const void* __restrict__ X, const void* __restrict__ kw, const void* __restrict__ qw,
    const void* __restrict__ rw1, const void* __restrict__ rw2, const void* __restrict__ mw1,
    const void* __restrict__ mw2, const void* __restrict__ pw, const void* __restrict__ muw,
    const void* __restrict__ spw,
    const void* __restrict__ rb1, const void* __restrict__ rb2, const void* __restrict__ lng,
    const void* __restrict__ lnb, const void* __restrict__ mb1, const void* __restrict__ mb2,
    const void* __restrict__ pb, const void* __restrict__ mub, const void* __restrict__ spb,
    unsigned short* __restrict__ wfb, unsigned short* __restrict__ w3b,
    float* __restrict__ wh, float* __restrict__ bc)
{
  __shared__ __align__(16) char psm[65536];
  const int fl = block_detect(X);
  const int t = threadIdx.x;
  int blk = blockIdx.x;

  if (blk < 16) {   // ---- A: wfb (l,kt)
    unsigned short* ls = (unsigned short*)psm;
    unsigned* lsu = (unsigned*)psm;
    const int l = blk >> 3, kt = blk & 7;
    if (fl) {
      #pragma unroll
      for (int s = 0; s < 4; ++s) {
        const unsigned* sp = (const unsigned*)((s == 0) ? kw : (s == 1) ? qw : rw1);
        const int rstr = (s < 2) ? 128 : 256;
        const int coff = ((s == 3) ? 128 : 0) + kt*16;
        for (int i = t; i < 4096; i += 256) {
          const int e = i >> 4, d2 = i & 15;
          lsu[s*4096 + i] = sp[(l*256 + e)*rstr + coff + d2];
        }
      }
    } else {
      #pragma unroll
      for (int s = 0; s < 4; ++s) {
        const float* sp = (const float*)((s == 0) ? kw : (s == 1) ? qw : rw1);
        const int rstr = (s < 2) ? 256 : 512;
        const int coff = ((s == 3) ? 256 : 0) + kt*32;
        for (int i = t; i < 4096; i += 256) {
          const int e = i >> 4, d2 = i & 15;
          const float f0 = sp[(l*256 + e)*rstr + coff + d2*2];
          const float f1 = sp[(l*256 + e)*rstr + coff + d2*2 + 1];
          lsu[s*4096 + i] = (unsigned)bfr(f0) | ((unsigned)bfr(f1) << 16);
        }
      }
    }
    __syncthreads();
    unsigned* outp = (unsigned*)wfb + (l*8 + kt)*16384;
    for (int f2 = t; f2 < 16384; f2 += 256) {
      const int j2 = f2 & 3, lane = (f2 >> 2) & 63, ntg = f2 >> 8;
      const int seg = ntg >> 4;
      const int e = (ntg & 15)*16 + (lane & 15);
      const int dl = ((lane >> 4) & 3)*8 + j2*2;
      unsigned short r0 = ls[seg*8192 + e*32 + dl];
      unsigned short r1 = ls[seg*8192 + e*32 + dl + 1];
      if (seg == 1) { r0 = bfr(bfu(r0)*0.0625f); r1 = bfr(bfu(r1)*0.0625f); }
      else if (seg == 2) {
        const unsigned short w0 = ls[3*8192 + e*32 + dl];
        const unsigned short w1 = ls[3*8192 + e*32 + dl + 1];
        r0 = bfr(bfu(r0) + bfu(w0)); r1 = bfr(bfu(r1) + bfu(w1));
      }
      outp[f2] = (unsigned)r0 | ((unsigned)r1 << 16);
    }
    return;
  }
  blk -= 16;
  if (blk < 48) {   // ---- B: w3b (l,gm,kt)
    unsigned short* ls = (unsigned short*)psm;
    unsigned* lsu = (unsigned*)psm;
    const int l3 = blk >> 3, kt = blk & 7;
    const int l = l3 / 3, gm = l3 % 3;
    const void* src = (gm == 0) ? rw2 : (gm == 1) ? mw1 : mw2;
    if (fl) {
      const unsigned* sp = (const unsigned*)src;
      for (int i = t; i < 4096; i += 256) {
        const int e = i >> 4, d2 = i & 15;
        lsu[i] = sp[(l*256 + e)*128 + kt*16 + d2];
      }
    } else {
      const float* sp = (const float*)src;
      for (int i = t; i < 4096; i += 256) {
        const int e = i >> 4, d2 = i & 15;
        const float f0 = sp[(l*256 + e)*256 + kt*32 + d2*2];
        const float f1 = sp[(l*256 + e)*256 + kt*32 + d2*2 + 1];
        lsu[i] = (unsigned)bfr(f0) | ((unsigned)bfr(f1) << 16);
      }
    }
    __syncthreads();
    unsigned* outp = (unsigned*)w3b + (l3*8 + kt)*4096;
    for (int f2 = t; f2 < 4096; f2 += 256) {
      const int j2 = f2 & 3, lane = (f2 >> 2) & 63, nt = f2 >> 8;
      const int e = nt*16 + (lane & 15);
      const int dl = ((lane >> 4) & 3)*8 + j2*2;
      outp[f2] = (unsigned)ls[e*32 + dl] | ((unsigned)ls[e*32 + dl + 1] << 16);
    }
    return;
  }
  blk -= 48;
  if (blk < 24) {   // ---- D: wh transposes
    float* lsf = (float*)psm;
    if (blk < 8) {          // projT
      const int l0 = blk*16;
      if (fl) {
        const unsigned* sp = (const unsigned*)pw;
        for (int i = t; i < 2048; i += 256) {
          const int ll = i >> 7, d2 = i & 127;
          const unsigned u = sp[(l0 + ll)*128 + d2];
          lsf[ll*256 + d2*2]     = __uint_as_float(u << 16);
          lsf[ll*256 + d2*2 + 1] = __uint_as_float(u & 0xffff0000u);
        }
      } else {
        const float* sp = (const float*)pw;
        for (int i = t; i < 4096; i += 256) {
          const int ll = i >> 8, d = i & 255;
          lsf[ll*256 + d] = sp[(l0 + ll)*256 + d];
        }
      }
      __syncthreads();
      for (int i = t; i < 4096; i += 256) {
        const int d = i >> 4, ll = i & 15;
        wh[d*128 + l0 + ll] = lsf[ll*256 + d];
      }
    } else {                // muT / spT
      const int grp2 = blk - 8;
      const int isSp = grp2 >> 3;
      const int l0 = (grp2 & 7)*16;
      const void* src = isSp ? spw : muw;
      const int off = isSp ? 49152 : 32768;
      if (fl) {
        const unsigned* sp = (const unsigned*)src;
        for (int i = t; i < 1024; i += 256) {
          const int ll = i >> 6, c2 = i & 63;
          const unsigned u = sp[(l0 + ll)*64 + c2];
          lsf[ll*128 + c2*2]     = __uint_as_float(u << 16);
          lsf[ll*128 + c2*2 + 1] = __uint_as_float(u & 0xffff0000u);
        }
      } else {
        const float* sp = (const float*)src;
        for (int i = t; i < 2048; i += 256) {
          const int ll = i >> 7, c = i & 127;
          lsf[ll*128 + c] = sp[(l0 + ll)*128 + c];
        }
      }
      __syncthreads();
      for (int i = t; i < 2048; i += 256) {
        const int c = i >> 4, ll = i & 15;
        wh[off + c*128 + l0 + ll] = lsf[ll*128 + c];
      }
    }
    return;
  }
  // ---- E: bc
  for (int i = t; i < 3456; i += 256) {
    const void* src; int off;
    if (i < 512)       { src = rb1; off = i; }
    else if (i < 1024) { src = rb2; off = i - 512; }
    else if (i < 1536) { src = lng; off = i - 1024; }
    else if (i < 2048) { src = lnb; off = i - 1536; }
    else if (i < 2560) { src = mb1; off = i - 2048; }
    else if (i < 3072) { src = mb2; off = i - 2560; }
    else if (i < 3200) { src = pb;  off = i - 3072; }
    else if (i < 3328) { src = mub; off = i - 3200; }
    else               { src = spb; off = i - 3328; }
    bc[i] = load_f(src, off, fl);
  }
}

// ---------------------------------------------------------------------------
// k1 body: NRR rows x (waves*NTG*16) cols from staged A-frags.
// ---------------------------------------------------------------------------
template<bool SPLIT, int NTG, int NRR>
__device__ __forceinline__ void k1_body(
    const unsigned short (&aF)[2][4096],
    const unsigned short* __restrict__ wfb, const float* __restrict__ bc,
    float* __restrict__ kq, float* __restrict__ Pf, unsigned* __restrict__ Qpk,
    int l, int row0, int ntg0, int t)
{
  const int w = t >> 6, l64 = t & 63;
  const int col = l64 & 15, quad = l64 >> 4;
  f32x4 acc[NTG];
  #pragma unroll
  for (int i = 0; i < NTG; ++i) acc[i] = (f32x4){0.f, 0.f, 0.f, 0.f};
  for (int kt = 0; kt < 8; ++kt) {
    const bf16x8 ah = *(const bf16x8*)&aF[0][kt*512 + l64*8];
    bf16x8 al;
    if (SPLIT) al = *(const bf16x8*)&aF[1][kt*512 + l64*8];
    #pragma unroll
    for (int i = 0; i < NTG; ++i) {
      const int ntg = ntg0 + w*NTG + i;
      const bf16x8 b = *(const bf16x8*)&wfb[((l*8 + kt)*64 + ntg)*512 + l64*8];
      acc[i] = __builtin_amdgcn_mfma_f32_16x16x32_bf16(ah, b, acc[i], 0, 0, 0);
      if (SPLIT) acc[i] = __builtin_amdgcn_mfma_f32_16x16x32_bf16(al, b, acc[i], 0, 0, 0);
    }
  }
  #pragma unroll
  for (int i = 0; i < NTG; ++i) {
    const int ntg = ntg0 + w*NTG + i;
    if (ntg < 32) {
      const int n = ntg*16 + col;
      #pragma unroll
      for (int r = 0; r < 4; ++r)
        if (NRR == 16 || quad*4 + r < NRR)
          kq[(size_t)(row0 + quad*4 + r)*512 + n] = acc[i][r];
    } else if (ntg < 48) {
      const int c = (ntg - 32)*16 + col;
      const float bias = bc[l*256 + c];
      #pragma unroll
      for (int r = 0; r < 4; ++r)
        if (NRR == 16 || quad*4 + r < NRR)
          Pf[(size_t)(row0 + quad*4 + r)*256 + c] = acc[i][r] + bias;
    } else {
      #pragma unroll
      for (int r = 0; r < 4; ++r) {
        const float v = acc[i][r];
        const float pv = __shfl_xor(v, 1, 64);
        if (!(col & 1) && (NRR == 16 || quad*4 + r < NRR)) {
          const unsigned uu = (unsigned)bfr(v) | ((unsigned)bfr(pv) << 16);
          Qpk[(size_t)(row0 + quad*4 + r)*128 + (ntg - 48)*8 + (col >> 1)] = uu;
        }
      }
    }
  }
}

// ---------------------------------------------------------------------------
// k1 layer-0: 512 blocks (128 m x 4 n) x 256 thr   [unchanged]
// ---------------------------------------------------------------------------
__global__ __launch_bounds__(256) void k1l0(
    const void* __restrict__ X, const unsigned short* __restrict__ wfb,
    const float* __restrict__ bc, float* __restrict__ kq, float* __restrict__ Pf,
    unsigned* __restrict__ Qpk)
{
  const int fl = block_detect(X);
  __shared__ __align__(16) unsigned short aF[2][4096];
  const int t = threadIdx.x;
  const int mb = (int)blockIdx.x >> 2, nb4 = (int)blockIdx.x & 3;
  const int row0 = mb * 16, ntg0 = nb4 * 16;
  if (fl) {
    for (int i = t; i < 512; i += 256) {
      const int row = i >> 5, d0 = (i & 31) * 8;
      const uint4 u = *(const uint4*)((const unsigned*)X + (size_t)(row0 + row)*128 + (i & 31)*4);
      const int kt = d0 >> 5, lane = row | (((d0 >> 3) & 3) << 4);
      *(uint4*)&aF[0][kt*512 + lane*8] = u;
    }
  } else {
    for (int i = t; i < 1024; i += 256) {
      const int row = i >> 6, d0 = (i & 63) * 4;
      stage_split4(aF, row, d0, *(const float4*)((const float*)X + (size_t)(row0 + row)*256 + d0));
    }
  }
  __syncthreads();
  if (fl) k1_body<false, 4, 16>(aF, wfb, bc, kq, Pf, Qpk, 0, row0, ntg0, t);
  else    k1_body<true,  4, 16>(aF, wfb, bc, kq, Pf, Qpk, 0, row0, ntg0, t);
}

// ---------------------------------------------------------------------------
// attn_phase<NR>: scores + softmax + gelu-weighted agg for OWN NR rows.
// [unchanged from R17: K/Qpk staged to LDS, scores+agg LDS-only]
// ---------------------------------------------------------------------------
template<int NR>
__device__ __forceinline__ void attn_phase(
    const float* __restrict__ kq, const float* __restrict__ Pf,
    const unsigned* __restrict__ Qpk,
    int row0, int t, float* qg, float* scp, float* als,
    unsigned* Kst, unsigned* Qst)
{
  const int base = row0 & ~63;               // b*64
  // 1a. stage own q rows (fp32)
  for (int i = t; i < NR*64; i += 512) {
    const int il = i >> 6, d0 = (i & 63)*4;
    *(float4*)&qg[il*256 + d0] = *(const float4*)&kq[(size_t)(row0 + il)*512 + 256 + d0];
  }
  // 1b. stage K rows bf16-packed: Kst[64][132] u32 (132-stride breaks banks)
  for (int i = t; i < 4096; i += 512) {
    const int row = i >> 6, c4 = i & 63;
    const float4 v = *(const float4*)&kq[(size_t)(base + row)*512 + c4*4];
    Kst[row*132 + c4*2]     = (unsigned)bfr(v.x) | ((unsigned)bfr(v.y) << 16);
    Kst[row*132 + c4*2 + 1] = (unsigned)bfr(v.z) | ((unsigned)bfr(v.w) << 16);
  }
  // 1c. stage Qpk block: Qst[64][128] u32
  for (int i = t; i < 2048; i += 512) {
    const int row = i >> 5, c4 = i & 31;
    *(uint4*)&Qst[row*128 + c4*4] = *(const uint4*)&Qpk[(size_t)(base + row)*128 + c4*4];
  }
  __syncthreads();
  const int w = t >> 6, lane = t & 63;
  // 2. scores (K bf16 from LDS; q fp32 from LDS)
  {
    const int jl = lane & 15, part = lane >> 4;
    const int j = (w & 3)*16 + jl;
    for (int p = 0; p < NR/4; ++p) {
      const int i0 = (p*2 + (w >> 2))*2;
      const unsigned* kr = &Kst[j*132 + part*32];
      const float* q0p = &qg[i0*256 + part*64];
      const float* q1p = &qg[(i0+1)*256 + part*64];
      float s0 = 0.f, s1 = 0.f;
      #pragma unroll
      for (int d2 = 0; d2 < 32; d2 += 2) {
        const unsigned ka = kr[d2], kb = kr[d2 + 1];
        const float4 q0 = *(const float4*)&q0p[d2*2];
        const float4 q1 = *(const float4*)&q1p[d2*2];
        const float k0 = bfu((unsigned short)ka), k1 = bfu((unsigned short)(ka >> 16));
        const float k2 = bfu((unsigned short)kb), k3 = bfu((unsigned short)(kb >> 16));
        s0 = fmaf(k0, q0.x, s0); s0 = fmaf(k1, q0.y, s0);
        s0 = fmaf(k2, q0.z, s0); s0 = fmaf(k3, q0.w, s0);
        s1 = fmaf(k0, q1.x, s1); s1 = fmaf(k1, q1.y, s1);
        s1 = fmaf(k2, q1.z, s1); s1 = fmaf(k3, q1.w, s1);
      }
      s0 += __shfl_xor(s0, 16, 64); s0 += __shfl_xor(s0, 32, 64);
      s1 += __shfl_xor(s1, 16, 64); s1 += __shfl_xor(s1, 32, 64);
      if (part == 0) { scp[i0*64 + j] = s0; scp[(i0+1)*64 + j] = s1; }
    }
  }
  __syncthreads();
  // 3. softmax per row
  for (int r = w; r < NR; r += 8) {
    float s = scp[r*64 + lane];
    float m = s;
    #pragma unroll
    for (int off = 32; off; off >>= 1) m = fmaxf(m, __shfl_xor(m, off, 64));
    const float e = __expf(s - m);
    float ss = e;
    #pragma unroll
    for (int off = 32; off; off >>= 1) ss += __shfl_xor(ss, off, 64);
    als[r*64 + lane] = e / ss;
  }
  __syncthreads();
  // 4. agg (Qpk from LDS; conflict-free reads)
  {
    constexpr int RK = NR/4;
    const int cp = t & 127, rb4 = t >> 7;
    float Px[RK], Py[RK], A0[RK], A1[RK], a0[RK], a1[RK];
    #pragma unroll
    for (int k = 0; k < RK; ++k) {
      const float2 P = *(const float2*)&Pf[(size_t)(row0 + rb4*RK + k)*256 + cp*2];
      Px[k] = P.x; Py[k] = P.y;
      A0[k] = -1.702f * P.x; A1[k] = -1.702f * P.y;
      a0[k] = 0.f; a1[k] = 0.f;
    }
    const unsigned* qp = &Qst[cp];
    #pragma unroll 4
    for (int j = 0; j < 64; ++j) {
      const unsigned u = qp[j*128];
      const float q0 = __uint_as_float(u << 16);
      const float q1 = __uint_as_float(u & 0xffff0000u);
      #pragma unroll
      for (int k = 0; k < RK; ++k) {
        const float wgt = als[(rb4*RK + k)*64 + j];
        const float s0 = __builtin_amdgcn_rcpf(1.f + __expf(fmaf(1.702f, q0, A0[k])));
        const float s1 = __builtin_amdgcn_rcpf(1.f + __expf(fmaf(1.702f, q1, A1[k])));
        a0[k] = fmaf(wgt * (Px[k] - q0), s0, a0[k]);
        a1[k] = fmaf(wgt * (Py[k] - q1), s1, a1[k]);
      }
    }
    #pragma unroll
    for (int k = 0; k < RK; ++k) {
      qg[(rb4*RK + k)*256 + cp*2]     = a0[k];
      qg[(rb4*RK + k)*256 + cp*2 + 1] = a1[k];
    }
  }
  __syncthreads();                        // g (in qg) ready for k4_core
}

// ---------------------------------------------------------------------------
// k4 core (512 thr): agg=g@rw2^T+rb2; h=LN(xin+agg); out=xin+mlp(h)
// ---------------------------------------------------------------------------
__device__ __forceinline__ void k4_gemm8(
    f32x4 acc[2], const unsigned short (&aF)[2][4096],
    const unsigned short* __restrict__ wg, int w, int l64)
{
  acc[0] = (f32x4){0.f, 0.f, 0.f, 0.f};
  acc[1] = (f32x4){0.f, 0.f, 0.f, 0.f};
  for (int kt = 0; kt < 8; ++kt) {
    const bf16x8 ah = *(const bf16x8*)&aF[0][kt*512 + l64*8];
    const bf16x8 al = *(const bf16x8*)&aF[1][kt*512 + l64*8];
    #pragma unroll
    for (int nt = 0; nt < 2; ++nt) {
      const bf16x8 b = *(const bf16x8*)&wg[((kt*16 + (w*2 + nt))*64 + l64)*8];
      acc[nt] = __builtin_amdgcn_mfma_f32_16x16x32_bf16(ah, b, acc[nt], 0, 0, 0);
      acc[nt] = __builtin_amdgcn_mfma_f32_16x16x32_bf16(al, b, acc[nt], 0, 0, 0);
    }
  }
}

template<bool ADAPT, bool TAIL, int NR>
__device__ __forceinline__ void k4_core(
    const float* gl, const void* __restrict__ xin, int fl,
    float* __restrict__ xout, const unsigned short* __restrict__ wg,
    const float* __restrict__ bc, int l, int row0, int t, bool writeX,
    unsigned short (&aF)[2][4096], float* bufB, float (&mv)[16][2])
{
  const int w = t >> 6, l64 = t & 63;
  const int col = l64 & 15, quad = l64 >> 4;
  const float* rb2c = bc + 512  + l*256;
  const float* lngc = bc + 1024 + l*256;
  const float* lnbc = bc + 1536 + l*256;
  const float* mb1c = bc + 2048 + l*256;
  const float* mb2c = bc + 2560 + l*256;

  for (int i = t; i < NR*64; i += 512) {
    const int row = i >> 6, d0 = (i & 63) * 4;
    stage_split4(aF, row, d0, *(const float4*)&gl[row*256 + d0]);
  }
  if (ADAPT && fl) {
    for (int c = t; c < NR*128; c += 512) {
      const int row = c >> 7, dp = c & 127;
      const unsigned u = ((const unsigned*)xin)[(size_t)(row0 + row)*128 + dp];
      bufB[row*260 + dp*2]     = __uint_as_float(u << 16);
      bufB[row*260 + dp*2 + 1] = __uint_as_float(u & 0xffff0000u);
    }
  } else {
    for (int c = t; c < NR*64; c += 512) {
      const int row = c >> 6, d0 = (c & 63) * 4;
      *(float4*)&bufB[row*260 + d0] = *(const float4*)((const float*)xin + (size_t)(row0 + row)*256 + d0);
    }
  }
  __syncthreads();
  float xtr[2][4];
  #pragma unroll
  for (int nt = 0; nt < 2; ++nt) {
    const int cn = (w*2 + nt)*16 + col;
    #pragma unroll
    for (int r = 0; r < 4; ++r) xtr[nt][r] = bufB[(quad*4 + r)*260 + cn];
  }
  __syncthreads();

  f32x4 acc[2];
  k4_gemm8(acc, aF, wg, w, l64);               // GEMM1
  #pragma unroll
  for (int nt = 0; nt < 2; ++nt) {
    const int cn = (w*2 + nt)*16 + col;
    #pragma unroll
    for (int r = 0; r < 4; ++r)
      bufB[(quad*4 + r)*260 + cn] = acc[nt][r] + rb2c[cn] + xtr[nt][r];
  }
  __syncthreads();
  {                                            // LN stats
    const int row = t >> 5, part = t & 31;
    if (row < NR) {
      float s = 0.f, s2 = 0.f;
      #pragma unroll
      for (int kk = 0; kk < 8; ++kk) {
        const float v = bufB[row*260 + part + kk*32];
        s += v; s2 = fmaf(v, v, s2);
      }
      #pragma unroll
      for (int off = 16; off; off >>= 1) {
        s  += __shfl_xor(s, off, 32);
        s2 += __shfl_xor(s2, off, 32);
      }
      if (part == 0) {
        const float mu = s * (1.f/256.f);
        mv[row][0] = mu;
        mv[row][1] = rsqrtf(fmaf(-mu, mu, s2 * (1.f/256.f)) + 1e-5f);
      }
    }
  }
  __syncthreads();
  for (int i = t; i < NR*64; i += 512) {       // LN apply + restage
    const int row = i >> 6, d0 = (i & 63) * 4;
    float4 v = *(const float4*)&bufB[row*260 + d0];
    const float m = mv[row][0], iv = mv[row][1];
    v.x = (v.x - m)*iv*lngc[d0]   + lnbc[d0];
    v.y = (v.y - m)*iv*lngc[d0+1] + lnbc[d0+1];
    v.z = (v.z - m)*iv*lngc[d0+2] + lnbc[d0+2];
    v.w = (v.w - m)*iv*lngc[d0+3] + lnbc[d0+3];
    stage_split4(aF, row, d0, v);
  }
  __syncthreads();
  k4_gemm8(acc, aF, wg + 65536, w, l64);       // GEMM2 + gelu
  #pragma unroll
  for (int nt = 0; nt < 2; ++nt) {
    const int cn = (w*2 + nt)*16 + col;
    #pragma unroll
    for (int r = 0; r < 4; ++r)
      if (quad*4 + r < NR)
        bufB[(quad*4 + r)*260 + cn] = gelu_e(acc[nt][r] + mb1c[cn]);
  }
  __syncthreads();
  for (int i = t; i < NR*64; i += 512) {       // restage
    const int row = i >> 6, d0 = (i & 63) * 4;
    stage_split4(aF, row, d0, *(const float4*)&bufB[row*260 + d0]);
  }
  __syncthreads();
  k4_gemm8(acc, aF, wg + 2*65536, w, l64);     // GEMM3 + residual
  if (TAIL) {
    #pragma unroll
    for (int nt = 0; nt < 2; ++nt) {
      const int cn = (w*2 + nt)*16 + col;
      #pragma unroll
      for (int r = 0; r < 4; ++r)
        bufB[(quad*4 + r)*260 + cn] = acc[nt][r] + mb2c[cn] + xtr[nt][r];
    }
    __syncthreads();
    for (int i = t; i < NR*64; i += 512) {     // coalesced x write + restage
      const int row = i >> 6, d0 = (i & 63) * 4;
      const float4 v = *(const float4*)&bufB[row*260 + d0];
      if (writeX) *(float4*)&xout[(size_t)(row0 + row)*256 + d0] = v;
      stage_split4(aF, row, d0, v);
    }
    __syncthreads();
  } else {
    #pragma unroll
    for (int nt = 0; nt < 2; ++nt) {
      const int cn = (w*2 + nt)*16 + col;
      #pragma unroll
      for (int r = 0; r < 4; ++r)
        if (quad*4 + r < NR)
          xout[(size_t)(row0 + quad*4 + r)*256 + cn] = acc[nt][r] + mb2c[cn] + xtr[nt][r];
    }
  }
}

// LDS union layout (77 KB): attn {Kst,Qst} overlaps k4 {aF,bufB,mv}; qg/scp/als
// live across both. Offsets in bytes.
#define SM_QG    0        // float[2048]  (8192 B)
#define SM_SCP   8192     // float[512]   (2048 B)
#define SM_ALS   10240    // float[512]   (2048 B)
#define SM_UNION 12288    // attn: Kst u32[64*132] (33792) + Qst u32[64*128] (32768)
#define SM_QST   46080    //      -> end 78848
#define SM_AF    12288    // k4:  ushort[2][4096] (16384)
#define SM_BUFB  28672    //      float[16*260]   (16640)
#define SM_MV    45312    //      float[16][2]    (128) -> end 45440
#define SM_TOTAL 78848

// XCD-aware swizzle: all 8 row-blocks of a batch share bid%8 (same XCD under
// round-robin dispatch). Bijective over 256 blocks.
__device__ __forceinline__ int swz_row0(int bid) {
  const int xcd = bid & 7, j = bid >> 3;
  const int batch = (j & 3)*8 + xcd;
  const int rsub = j >> 2;
  return batch*64 + rsub*8;
}

// ---------------------------------------------------------------------------
// kA': attn(l0) + layer-0 mix + layer-1 k1; 256 blocks x 8 rows, 512 thr.
// ---------------------------------------------------------------------------
__global__ __launch_bounds__(512) void kA_attn_mix_kq(
    const unsigned short* __restrict__ w3b, const unsigned short* __restrict__ wfb,
    const float* __restrict__ bc, const void* __restrict__ X, float* __restrict__ x,
    const float* __restrict__ kq, const float* __restrict__ Pf,
    const unsigned* __restrict__ Qpk,
    float* __restrict__ kq1, float* __restrict__ Pf1, unsigned* __restrict__ Qpk1)
{
  const int fl = block_detect(X);
  __shared__ __align__(16) char sm[SM_TOTAL];
  float* qg  = (float*)(sm + SM_QG);
  float* scp = (float*)(sm + SM_SCP);
  float* als = (float*)(sm + SM_ALS);
  unsigned* Kst = (unsigned*)(sm + SM_UNION);
  unsigned* Qst = (unsigned*)(sm + SM_QST);
  unsigned short (&aF)[2][4096] = *reinterpret_cast<unsigned short (*)[2][4096]>(sm + SM_AF);
  float* bufB = (float*)(sm + SM_BUFB);
  float (&mv)[16][2] = *reinterpret_cast<float (*)[16][2]>(sm + SM_MV);
  const int t = threadIdx.x;
  const int row0 = swz_row0((int)blockIdx.x);
  attn_phase<8>(kq, Pf, Qpk, row0, t, qg, scp, als, Kst, Qst);
  k4_core<true, true, 8>(qg, X, fl, x, w3b, bc, 0, row0, t, true, aF, bufB, mv);
  k1_body<true, 8, 8>(aF, wfb, bc, kq1, Pf1, Qpk1, 1, row0, 0, t);
}

// ---------------------------------------------------------------------------
// kB: attn(l1) + layer-1 mix -> x; 256 blocks x 8 rows, 512 thr
// ---------------------------------------------------------------------------
__global__ __launch_bounds__(512) void kB_attn_fin(
    const unsigned short* __restrict__ w3b, const float* __restrict__ bc,
    float* __restrict__ x, const float* __restrict__ kq1,
    const float* __restrict__ Pf1, const unsigned* __restrict__ Qpk1)
{
  __shared__ __align__(16) char sm[SM_TOTAL];
  float* qg  = (float*)(sm + SM_QG);
  float* scp = (float*)(sm + SM_SCP);
  float* als = (float*)(sm + SM_ALS);
  unsigned* Kst = (unsigned*)(sm + SM_UNION);
  unsigned* Qst = (unsigned*)(sm + SM_QST);
  unsigned short (&aF)[2][4096] = *reinterpret_cast<unsigned short (*)[2][4096]>(sm + SM_AF);
  float* bufB = (float*)(sm + SM_BUFB);
  float (&mv)[16][2] = *reinterpret_cast<float (*)[16][2]>(sm + SM_MV);
  const int t = threadIdx.x;
  const int row0 = swz_row0((int)blockIdx.x);
  attn_phase<8>(kq1, Pf1, Qpk1, row0, t, qg, scp, als, Kst, Qst);
  k4_core<false, false, 8>(qg, x, 0, x, w3b + 3*65536, bc, 1, row0, t, true, aF, bufB, mv);
}

// ---------------------------------------------------------------------------
// k5: s=sum_K x ; h=gelu(s@projT+pb) ; mu=h@muT+mb ; scale=softplus(h@spT+sb)
// [unchanged from R17]
// ---------------------------------------------------------------------------
__global__ __launch_bounds__(256) void k5_head(
    const float* __restrict__ x, const float* __restrict__ wh,
    const float* __restrict__ bc, const void* __restrict__ X,
    void* __restrict__ out)
{
  const int fl = block_detect(X);
  __shared__ float ss[256];
  __shared__ float hh[128];
  const int b = blockIdx.x, t = threadIdx.x;
  {
    const float* xp = x + (size_t)(b << 6)*256 + t;
    float s0 = 0.f, s1 = 0.f, s2 = 0.f, s3 = 0.f;
    for (int i = 0; i < 64; i += 4) {
      s0 += xp[(size_t)(i    )*256];
      s1 += xp[(size_t)(i + 1)*256];
      s2 += xp[(size_t)(i + 2)*256];
      s3 += xp[(size_t)(i + 3)*256];
    }
    ss[t] = (s0 + s1) + (s2 + s3);
  }
  __syncthreads();
  if (t < 128) {
    float acc = bc[3072 + t];
    const float* projT = wh;
    for (int d = 0; d < 256; ++d) acc = fmaf(ss[d], projT[d*128 + t], acc);
    hh[t] = gelu_e(acc);
  }
  __syncthreads();
  float v; int oidx;
  if (t < 128) {
    float acc = bc[3200 + t];
    const float* muT = wh + 32768;
    for (int c = 0; c < 128; ++c) acc = fmaf(hh[c], muT[c*128 + t], acc);
    v = acc; oidx = b*128 + t;
  } else {
    const int u = t - 128;
    float acc = bc[3328 + u];
    const float* spT = wh + 49152;
    for (int c = 0; c < 128; ++c) acc = fmaf(hh[c], spT[c*128 + u], acc);
    v = (acc > 20.f) ? acc : log1pf(__expf(acc));
    oidx = 4096 + b*128 + u;
  }
  if (fl) ((bf16*)out)[oidx] = __float2bfloat16(v);
  else    ((float*)out)[oidx] = v;
}

// ---------------------------------------------------------------------------
extern "C" void kernel_launch(void* const* d_in, const int* in_sizes, int n_in,
                              void* d_out, int out_size, void* d_ws, size_t ws_size,
                              hipStream_t stream)
{
  (void)in_sizes; (void)n_in; (void)out_size; (void)ws_size;
  float* ws    = (float*)d_ws;
  float* x     = ws + 16;                          // 524288
  float* kq    = x + 524288;                       // 1048576  (layer 0)
  float* Pf    = kq + 1048576;                     // 524288   (layer 0)
  unsigned* Qpk = (unsigned*)(Pf + 524288);        // 262144   (layer 0)
  float* g     = (float*)(Qpk + 262144);           // 524288   (unused)
  unsigned short* wfb = (unsigned short*)(g + 524288);   // 524288 shorts
  unsigned short* w3b = wfb + 524288;              // 393216 shorts
  float* wh    = (float*)(w3b + 393216);           // 65536
  float* bc    = wh + 65536;                       // 3456
  float* kq1   = bc + 4096;                        // 1048576  (layer 1)
  float* Pf1   = kq1 + 1048576;                    // 524288   (layer 1)
  unsigned* Qpk1 = (unsigned*)(Pf1 + 524288);      // 262144   (layer 1)

  prep_kernel<<<dim3(89), dim3(256), 0, stream>>>(
      d_in[0], d_in[1], d_in[2], d_in[3], d_in[5], d_in[9], d_in[11],
      d_in[13], d_in[15], d_in[17],
      d_in[4], d_in[6], d_in[7], d_in[8], d_in[10], d_in[12],
      d_in[14], d_in[16], d_in[18],
      wfb, w3b, wh, bc);
  k1l0<<<dim3(512), dim3(256), 0, stream>>>(d_in[0], wfb, bc, kq, Pf, Qpk);
  kA_attn_mix_kq<<<dim3(256), dim3(512), 0, stream>>>(
      w3b, wfb, bc, d_in[0], x, kq, Pf, Qpk, kq1, Pf1, Qpk1);
  kB_attn_fin<<<dim3(256), dim3(512), 0, stream>>>(w3b, bc, x, kq1, Pf1, Qpk1);
  k5_head<<<dim3(32), dim3(256), 0, stream>>>(x, wh, bc, d_in[0], (void*)d_out);
}

// Round 7
// 186.853 us; speedup vs baseline: 2.2930x; 1.0815x over previous
//
#include <hip/hip_runtime.h>
#include <hip/hip_bf16.h>

// B=32, K=64, D=256, LS=128, rows = 2048
// R19 = R18 with kA/kB widened to 1024 threads (16 waves/CU, was 8):
//       same 256-block grid, same 8 rows/block, same work + LDS + FP order —
//       each phase spread over 2x waves (R18 lesson: grid=256 caps blocks/CU
//       at 1, so occupancy must come from bigger blocks).

using bf16 = __hip_bfloat16;
typedef short bf16x8 __attribute__((ext_vector_type(8)));
typedef float f32x4 __attribute__((ext_vector_type(4)));

__device__ __forceinline__ float bfu(unsigned short u) { return __uint_as_float(((unsigned)u) << 16); }

__device__ __forceinline__ unsigned short bfr(float v) {   // RNE fp32->bf16 bits
  unsigned u = __float_as_uint(v);
  u += 0x7FFFu + ((u >> 16) & 1u);
  return (unsigned short)(u >> 16);
}

__device__ __forceinline__ float gelu_e(float x) {
  return 0.5f * x * (1.0f + erff(x * 0.7071067811865475f));
}

__device__ __forceinline__ float load_f(const void* p, int i, int fl) {
  if (fl) return bfu(((const unsigned short*)p)[i]);
  return ((const float*)p)[i];
}

// per-block inline dtype detect: 1 = inputs are bf16
__device__ __forceinline__ int block_detect(const void* X) {
  __shared__ int bad_s;
  if (threadIdx.x == 0) bad_s = 0;
  __syncthreads();
  if (threadIdx.x < 256) {
    const float v = bfu(((const unsigned short*)X)[threadIdx.x]);
    if (!(fabsf(v) < 1e6f)) atomicOr(&bad_s, 1);
  }
  __syncthreads();
  return bad_s ? 0 : 1;
}

// stage one float4 (row, d0) into hi/lo MFMA A-fragments
__device__ __forceinline__ void stage_split4(unsigned short (&aF)[2][4096], int row, int d0, float4 v) {
  ushort4 h, lo;
  h.x = bfr(v.x); h.y = bfr(v.y); h.z = bfr(v.z); h.w = bfr(v.w);
  lo.x = bfr(v.x - bfu(h.x)); lo.y = bfr(v.y - bfu(h.y));
  lo.z = bfr(v.z - bfu(h.z)); lo.w = bfr(v.w - bfu(h.w));
  const int kt = d0 >> 5, lane = row | (((d0 >> 3) & 3) << 4), j = d0 & 7;
  *(ushort4*)&aF[0][kt*512 + lane*8 + j] = h;
  *(ushort4*)&aF[1][kt*512 + lane*8 + j] = lo;
}

// ---------------------------------------------------------------------------
// prep (89 blocks x 256 thr): weights -> ws   [unchanged]
// ---------------------------------------------------------------------------
__global__ __launch_bounds__(256) void prep_kernel(
    const void* __restrict__ X, const void* __restrict__ kw, const void* __restrict__ qw,
    const void* __restrict__ rw1, const void* __restrict__ rw2, const void* __restrict__ mw1,
    const void* __restrict__ mw2, const void* __restrict__ pw, const void* __restrict__ muw,
    const void* __restrict__ spw,
    const void* __restrict__ rb1, const void* __restrict__ rb2, const void* __restrict__ lng,
    const void* __restrict__ lnb, const void* __restrict__ mb1, const void* __restrict__ mb2,
    const void* __restrict__ pb, const void* __restrict__ mub, const void* __restrict__ spb,
    unsigned short* __restrict__ wfb, unsigned short* __restrict__ w3b,
    float* __restrict__ wh, float* __restrict__ bc)
{
  __shared__ __align__(16) char psm[65536];
  const int fl = block_detect(X);
  const int t = threadIdx.x;
  int blk = blockIdx.x;

  if (blk < 16) {   // ---- A: wfb (l,kt)
    unsigned short* ls = (unsigned short*)psm;
    unsigned* lsu = (unsigned*)psm;
    const int l = blk >> 3, kt = blk & 7;
    if (fl) {
      #pragma unroll
      for (int s = 0; s < 4; ++s) {
        const unsigned* sp = (const unsigned*)((s == 0) ? kw : (s == 1) ? qw : rw1);
        const int rstr = (s < 2) ? 128 : 256;
        const int coff = ((s == 3) ? 128 : 0) + kt*16;
        for (int i = t; i < 4096; i += 256) {
          const int e = i >> 4, d2 = i & 15;
          lsu[s*4096 + i] = sp[(l*256 + e)*rstr + coff + d2];
        }
      }
    } else {
      #pragma unroll
      for (int s = 0; s < 4; ++s) {
        const float* sp = (const float*)((s == 0) ? kw : (s == 1) ? qw : rw1);
        const int rstr = (s < 2) ? 256 : 512;
        const int coff = ((s == 3) ? 256 : 0) + kt*32;
        for (int i = t; i < 4096; i += 256) {
          const int e = i >> 4, d2 = i & 15;
          const float f0 = sp[(l*256 + e)*rstr + coff + d2*2];
          const float f1 = sp[(l*256 + e)*rstr + coff + d2*2 + 1];
          lsu[s*4096 + i] = (unsigned)bfr(f0) | ((unsigned)bfr(f1) << 16);
        }
      }
    }
    __syncthreads();
    unsigned* outp = (unsigned*)wfb + (l*8 + kt)*16384;
    for (int f2 = t; f2 < 16384; f2 += 256) {
      const int j2 = f2 & 3, lane = (f2 >> 2) & 63, ntg = f2 >> 8;
      const int seg = ntg >> 4;
      const int e = (ntg & 15)*16 + (lane & 15);
      const int dl = ((lane >> 4) & 3)*8 + j2*2;
      unsigned short r0 = ls[seg*8192 + e*32 + dl];
      unsigned short r1 = ls[seg*8192 + e*32 + dl + 1];
      if (seg == 1) { r0 = bfr(bfu(r0)*0.0625f); r1 = bfr(bfu(r1)*0.0625f); }
      else if (seg == 2) {
        const unsigned short w0 = ls[3*8192 + e*32 + dl];
        const unsigned short w1 = ls[3*8192 + e*32 + dl + 1];
        r0 = bfr(bfu(r0) + bfu(w0)); r1 = bfr(bfu(r1) + bfu(w1));
      }
      outp[f2] = (unsigned)r0 | ((unsigned)r1 << 16);
    }
    return;
  }
  blk -= 16;
  if (blk < 48) {   // ---- B: w3b (l,gm,kt)
    unsigned short* ls = (unsigned short*)psm;
    unsigned* lsu = (unsigned*)psm;
    const int l3 = blk >> 3, kt = blk & 7;
    const int l = l3 / 3, gm = l3 % 3;
    const void* src = (gm == 0) ? rw2 : (gm == 1) ? mw1 : mw2;
    if (fl) {
      const unsigned* sp = (const unsigned*)src;
      for (int i = t; i < 4096; i += 256) {
        const int e = i >> 4, d2 = i & 15;
        lsu[i] = sp[(l*256 + e)*128 + kt*16 + d2];
      }
    } else {
      const float* sp = (const float*)src;
      for (int i = t; i < 4096; i += 256) {
        const int e = i >> 4, d2 = i & 15;
        const float f0 = sp[(l*256 + e)*256 + kt*32 + d2*2];
        const float f1 = sp[(l*256 + e)*256 + kt*32 + d2*2 + 1];
        lsu[i] = (unsigned)bfr(f0) | ((unsigned)bfr(f1) << 16);
      }
    }
    __syncthreads();
    unsigned* outp = (unsigned*)w3b + (l3*8 + kt)*4096;
    for (int f2 = t; f2 < 4096; f2 += 256) {
      const int j2 = f2 & 3, lane = (f2 >> 2) & 63, nt = f2 >> 8;
      const int e = nt*16 + (lane & 15);
      const int dl = ((lane >> 4) & 3)*8 + j2*2;
      outp[f2] = (unsigned)ls[e*32 + dl] | ((unsigned)ls[e*32 + dl + 1] << 16);
    }
    return;
  }
  blk -= 48;
  if (blk < 24) {   // ---- D: wh transposes
    float* lsf = (float*)psm;
    if (blk < 8) {          // projT
      const int l0 = blk*16;
      if (fl) {
        const unsigned* sp = (const unsigned*)pw;
        for (int i = t; i < 2048; i += 256) {
          const int ll = i >> 7, d2 = i & 127;
          const unsigned u = sp[(l0 + ll)*128 + d2];
          lsf[ll*256 + d2*2]     = __uint_as_float(u << 16);
          lsf[ll*256 + d2*2 + 1] = __uint_as_float(u & 0xffff0000u);
        }
      } else {
        const float* sp = (const float*)pw;
        for (int i = t; i < 4096; i += 256) {
          const int ll = i >> 8, d = i & 255;
          lsf[ll*256 + d] = sp[(l0 + ll)*256 + d];
        }
      }
      __syncthreads();
      for (int i = t; i < 4096; i += 256) {
        const int d = i >> 4, ll = i & 15;
        wh[d*128 + l0 + ll] = lsf[ll*256 + d];
      }
    } else {                // muT / spT
      const int grp2 = blk - 8;
      const int isSp = grp2 >> 3;
      const int l0 = (grp2 & 7)*16;
      const void* src = isSp ? spw : muw;
      const int off = isSp ? 49152 : 32768;
      if (fl) {
        const unsigned* sp = (const unsigned*)src;
        for (int i = t; i < 1024; i += 256) {
          const int ll = i >> 6, c2 = i & 63;
          const unsigned u = sp[(l0 + ll)*64 + c2];
          lsf[ll*128 + c2*2]     = __uint_as_float(u << 16);
          lsf[ll*128 + c2*2 + 1] = __uint_as_float(u & 0xffff0000u);
        }
      } else {
        const float* sp = (const float*)src;
        for (int i = t; i < 2048; i += 256) {
          const int ll = i >> 7, c = i & 127;
          lsf[ll*128 + c] = sp[(l0 + ll)*128 + c];
        }
      }
      __syncthreads();
      for (int i = t; i < 2048; i += 256) {
        const int c = i >> 4, ll = i & 15;
        wh[off + c*128 + l0 + ll] = lsf[ll*128 + c];
      }
    }
    return;
  }
  // ---- E: bc
  for (int i = t; i < 3456; i += 256) {
    const void* src; int off;
    if (i < 512)       { src = rb1; off = i; }
    else if (i < 1024) { src = rb2; off = i - 512; }
    else if (i < 1536) { src = lng; off = i - 1024; }
    else if (i < 2048) { src = lnb; off = i - 1536; }
    else if (i < 2560) { src = mb1; off = i - 2048; }
    else if (i < 3072) { src = mb2; off = i - 2560; }
    else if (i < 3200) { src = pb;  off = i - 3072; }
    else if (i < 3328) { src = mub; off = i - 3200; }
    else               { src = spb; off = i - 3328; }
    bc[i] = load_f(src, off, fl);
  }
}

// ---------------------------------------------------------------------------
// k1 body (256-thr form, for k1l0): 16 rows x (4 waves * NTG * 16) cols
// ---------------------------------------------------------------------------
template<bool SPLIT, int NTG>
__device__ __forceinline__ void k1_body(
    const unsigned short (&aF)[2][4096],
    const unsigned short* __restrict__ wfb, const float* __restrict__ bc,
    float* __restrict__ kq, float* __restrict__ Pf, unsigned* __restrict__ Qpk,
    int l, int row0, int ntg0, int t)
{
  const int w = t >> 6, l64 = t & 63;
  const int col = l64 & 15, quad = l64 >> 4;
  f32x4 acc[NTG];
  #pragma unroll
  for (int i = 0; i < NTG; ++i) acc[i] = (f32x4){0.f, 0.f, 0.f, 0.f};
  for (int kt = 0; kt < 8; ++kt) {
    const bf16x8 ah = *(const bf16x8*)&aF[0][kt*512 + l64*8];
    bf16x8 al;
    if (SPLIT) al = *(const bf16x8*)&aF[1][kt*512 + l64*8];
    #pragma unroll
    for (int i = 0; i < NTG; ++i) {
      const int ntg = ntg0 + w*NTG + i;
      const bf16x8 b = *(const bf16x8*)&wfb[((l*8 + kt)*64 + ntg)*512 + l64*8];
      acc[i] = __builtin_amdgcn_mfma_f32_16x16x32_bf16(ah, b, acc[i], 0, 0, 0);
      if (SPLIT) acc[i] = __builtin_amdgcn_mfma_f32_16x16x32_bf16(al, b, acc[i], 0, 0, 0);
    }
  }
  #pragma unroll
  for (int i = 0; i < NTG; ++i) {
    const int ntg = ntg0 + w*NTG + i;
    if (ntg < 32) {
      const int n = ntg*16 + col;
      #pragma unroll
      for (int r = 0; r < 4; ++r)
        kq[(size_t)(row0 + quad*4 + r)*512 + n] = acc[i][r];
    } else if (ntg < 48) {
      const int c = (ntg - 32)*16 + col;
      const float bias = bc[l*256 + c];
      #pragma unroll
      for (int r = 0; r < 4; ++r)
        Pf[(size_t)(row0 + quad*4 + r)*256 + c] = acc[i][r] + bias;
    } else {
      #pragma unroll
      for (int r = 0; r < 4; ++r) {
        const float v = acc[i][r];
        const float pv = __shfl_xor(v, 1, 64);
        if (!(col & 1)) {
          const unsigned uu = (unsigned)bfr(v) | ((unsigned)bfr(pv) << 16);
          Qpk[(size_t)(row0 + quad*4 + r)*128 + (ntg - 48)*8 + (col >> 1)] = uu;
        }
      }
    }
  }
}

// ---------------------------------------------------------------------------
// k1 body (1024-thr form): 16 waves x NTG=4 -> all 64 ntg; NRR rows valid
// ---------------------------------------------------------------------------
template<bool SPLIT, int NRR>
__device__ __forceinline__ void k1_body16(
    const unsigned short (&aF)[2][4096],
    const unsigned short* __restrict__ wfb, const float* __restrict__ bc,
    float* __restrict__ kq, float* __restrict__ Pf, unsigned* __restrict__ Qpk,
    int l, int row0, int t)
{
  const int w = t >> 6, l64 = t & 63;
  const int col = l64 & 15, quad = l64 >> 4;
  f32x4 acc[4];
  #pragma unroll
  for (int i = 0; i < 4; ++i) acc[i] = (f32x4){0.f, 0.f, 0.f, 0.f};
  for (int kt = 0; kt < 8; ++kt) {
    const bf16x8 ah = *(const bf16x8*)&aF[0][kt*512 + l64*8];
    bf16x8 al;
    if (SPLIT) al = *(const bf16x8*)&aF[1][kt*512 + l64*8];
    #pragma unroll
    for (int i = 0; i < 4; ++i) {
      const int ntg = w*4 + i;
      const bf16x8 b = *(const bf16x8*)&wfb[((l*8 + kt)*64 + ntg)*512 + l64*8];
      acc[i] = __builtin_amdgcn_mfma_f32_16x16x32_bf16(ah, b, acc[i], 0, 0, 0);
      if (SPLIT) acc[i] = __builtin_amdgcn_mfma_f32_16x16x32_bf16(al, b, acc[i], 0, 0, 0);
    }
  }
  #pragma unroll
  for (int i = 0; i < 4; ++i) {
    const int ntg = w*4 + i;
    if (ntg < 32) {
      const int n = ntg*16 + col;
      #pragma unroll
      for (int r = 0; r < 4; ++r)
        if (NRR == 16 || quad*4 + r < NRR)
          kq[(size_t)(row0 + quad*4 + r)*512 + n] = acc[i][r];
    } else if (ntg < 48) {
      const int c = (ntg - 32)*16 + col;
      const float bias = bc[l*256 + c];
      #pragma unroll
      for (int r = 0; r < 4; ++r)
        if (NRR == 16 || quad*4 + r < NRR)
          Pf[(size_t)(row0 + quad*4 + r)*256 + c] = acc[i][r] + bias;
    } else {
      #pragma unroll
      for (int r = 0; r < 4; ++r) {
        const float v = acc[i][r];
        const float pv = __shfl_xor(v, 1, 64);
        if (!(col & 1) && (NRR == 16 || quad*4 + r < NRR)) {
          const unsigned uu = (unsigned)bfr(v) | ((unsigned)bfr(pv) << 16);
          Qpk[(size_t)(row0 + quad*4 + r)*128 + (ntg - 48)*8 + (col >> 1)] = uu;
        }
      }
    }
  }
}

// ---------------------------------------------------------------------------
// k1 layer-0: 512 blocks (128 m x 4 n) x 256 thr   [unchanged]
// ---------------------------------------------------------------------------
__global__ __launch_bounds__(256) void k1l0(
    const void* __restrict__ X, const unsigned short* __restrict__ wfb,
    const float* __restrict__ bc, float* __restrict__ kq, float* __restrict__ Pf,
    unsigned* __restrict__ Qpk)
{
  const int fl = block_detect(X);
  __shared__ __align__(16) unsigned short aF[2][4096];
  const int t = threadIdx.x;
  const int mb = (int)blockIdx.x >> 2, nb4 = (int)blockIdx.x & 3;
  const int row0 = mb * 16, ntg0 = nb4 * 16;
  if (fl) {
    for (int i = t; i < 512; i += 256) {
      const int row = i >> 5, d0 = (i & 31) * 8;
      const uint4 u = *(const uint4*)((const unsigned*)X + (size_t)(row0 + row)*128 + (i & 31)*4);
      const int kt = d0 >> 5, lane = row | (((d0 >> 3) & 3) << 4);
      *(uint4*)&aF[0][kt*512 + lane*8] = u;
    }
  } else {
    for (int i = t; i < 1024; i += 256) {
      const int row = i >> 6, d0 = (i & 63) * 4;
      stage_split4(aF, row, d0, *(const float4*)((const float*)X + (size_t)(row0 + row)*256 + d0));
    }
  }
  __syncthreads();
  if (fl) k1_body<false, 4>(aF, wfb, bc, kq, Pf, Qpk, 0, row0, ntg0, t);
  else    k1_body<true,  4>(aF, wfb, bc, kq, Pf, Qpk, 0, row0, ntg0, t);
}

// ---------------------------------------------------------------------------
// attn_phase1k<NR=8>: 1024-thr attn. Same math/order as the 512-thr version,
// each phase spread over 16 waves.
// ---------------------------------------------------------------------------
template<int NR>
__device__ __forceinline__ void attn_phase1k(
    const float* __restrict__ kq, const float* __restrict__ Pf,
    const unsigned* __restrict__ Qpk,
    int row0, int t, float* qg, float* scp, float* als,
    unsigned* Kst, unsigned* Qst)
{
  const int base = row0 & ~63;               // b*64
  // 1a. stage own q rows (fp32)
  for (int i = t; i < NR*64; i += 1024) {
    const int il = i >> 6, d0 = (i & 63)*4;
    *(float4*)&qg[il*256 + d0] = *(const float4*)&kq[(size_t)(row0 + il)*512 + 256 + d0];
  }
  // 1b. stage K rows bf16-packed: Kst[64][132]
  for (int i = t; i < 4096; i += 1024) {
    const int row = i >> 6, c4 = i & 63;
    const float4 v = *(const float4*)&kq[(size_t)(base + row)*512 + c4*4];
    Kst[row*132 + c4*2]     = (unsigned)bfr(v.x) | ((unsigned)bfr(v.y) << 16);
    Kst[row*132 + c4*2 + 1] = (unsigned)bfr(v.z) | ((unsigned)bfr(v.w) << 16);
  }
  // 1c. stage Qpk block: Qst[64][128]
  for (int i = t; i < 2048; i += 1024) {
    const int row = i >> 5, c4 = i & 31;
    *(uint4*)&Qst[row*128 + c4*4] = *(const uint4*)&Qpk[(size_t)(base + row)*128 + c4*4];
  }
  __syncthreads();
  const int w = t >> 6, lane = t & 63;
  // 2. scores: wave = (j-tile = w&3, i-pair = w>>2); one pass
  {
    const int jl = lane & 15, part = lane >> 4;
    const int j = (w & 3)*16 + jl;
    const int i0 = (w >> 2) * 2;             // pairs 0..3 -> rows 0..7
    const unsigned* kr = &Kst[j*132 + part*32];
    const float* q0p = &qg[i0*256 + part*64];
    const float* q1p = &qg[(i0+1)*256 + part*64];
    float s0 = 0.f, s1 = 0.f;
    #pragma unroll
    for (int d2 = 0; d2 < 32; d2 += 2) {
      const unsigned ka = kr[d2], kb = kr[d2 + 1];
      const float4 q0 = *(const float4*)&q0p[d2*2];
      const float4 q1 = *(const float4*)&q1p[d2*2];
      const float k0 = bfu((unsigned short)ka), k1 = bfu((unsigned short)(ka >> 16));
      const float k2 = bfu((unsigned short)kb), k3 = bfu((unsigned short)(kb >> 16));
      s0 = fmaf(k0, q0.x, s0); s0 = fmaf(k1, q0.y, s0);
      s0 = fmaf(k2, q0.z, s0); s0 = fmaf(k3, q0.w, s0);
      s1 = fmaf(k0, q1.x, s1); s1 = fmaf(k1, q1.y, s1);
      s1 = fmaf(k2, q1.z, s1); s1 = fmaf(k3, q1.w, s1);
    }
    s0 += __shfl_xor(s0, 16, 64); s0 += __shfl_xor(s0, 32, 64);
    s1 += __shfl_xor(s1, 16, 64); s1 += __shfl_xor(s1, 32, 64);
    if (part == 0) { scp[i0*64 + j] = s0; scp[(i0+1)*64 + j] = s1; }
  }
  __syncthreads();
  // 3. softmax: one row per wave (waves 0..NR-1)
  if (w < NR) {
    const int r = w;
    float s = scp[r*64 + lane];
    float m = s;
    #pragma unroll
    for (int off = 32; off; off >>= 1) m = fmaxf(m, __shfl_xor(m, off, 64));
    const float e = __expf(s - m);
    float ss = e;
    #pragma unroll
    for (int off = 32; off; off >>= 1) ss += __shfl_xor(ss, off, 64);
    als[r*64 + lane] = e / ss;
  }
  __syncthreads();
  // 4. agg: thread = (row = t>>7, col-pair = t&127); one row per thread
  {
    const int cp = t & 127, rb = t >> 7;     // rb 0..7
    const float2 P = *(const float2*)&Pf[(size_t)(row0 + rb)*256 + cp*2];
    const float A0 = -1.702f * P.x, A1 = -1.702f * P.y;
    float a0 = 0.f, a1 = 0.f;
    const unsigned* qp = &Qst[cp];
    const float* ap = &als[rb*64];
    #pragma unroll 4
    for (int j = 0; j < 64; ++j) {
      const unsigned u = qp[j*128];
      const float wgt = ap[j];
      const float q0 = __uint_as_float(u << 16);
      const float q1 = __uint_as_float(u & 0xffff0000u);
      const float s0 = __builtin_amdgcn_rcpf(1.f + __expf(fmaf(1.702f, q0, A0)));
      const float s1 = __builtin_amdgcn_rcpf(1.f + __expf(fmaf(1.702f, q1, A1)));
      a0 = fmaf(wgt * (P.x - q0), s0, a0);
      a1 = fmaf(wgt * (P.y - q1), s1, a1);
    }
    qg[rb*256 + cp*2]     = a0;
    qg[rb*256 + cp*2 + 1] = a1;
  }
  __syncthreads();                        // g (in qg) ready for k4_core
}

// ---------------------------------------------------------------------------
// k4 core (1024-thr form): one 16-col tile per wave per GEMM
// ---------------------------------------------------------------------------
__device__ __forceinline__ f32x4 k4_gemm16(
    const unsigned short (&aF)[2][4096],
    const unsigned short* __restrict__ wg, int w, int l64)
{
  f32x4 acc = (f32x4){0.f, 0.f, 0.f, 0.f};
  for (int kt = 0; kt < 8; ++kt) {
    const bf16x8 ah = *(const bf16x8*)&aF[0][kt*512 + l64*8];
    const bf16x8 al = *(const bf16x8*)&aF[1][kt*512 + l64*8];
    const bf16x8 b = *(const bf16x8*)&wg[((kt*16 + w)*64 + l64)*8];
    acc = __builtin_amdgcn_mfma_f32_16x16x32_bf16(ah, b, acc, 0, 0, 0);
    acc = __builtin_amdgcn_mfma_f32_16x16x32_bf16(al, b, acc, 0, 0, 0);
  }
  return acc;
}

template<bool ADAPT, bool TAIL, int NR>
__device__ __forceinline__ void k4_core1k(
    const float* gl, const void* __restrict__ xin, int fl,
    float* __restrict__ xout, const unsigned short* __restrict__ wg,
    const float* __restrict__ bc, int l, int row0, int t, bool writeX,
    unsigned short (&aF)[2][4096], float* bufB, float (&mv)[16][2])
{
  const int w = t >> 6, l64 = t & 63;       // w 0..15
  const int col = l64 & 15, quad = l64 >> 4;
  const int cn = w*16 + col;
  const float* rb2c = bc + 512  + l*256;
  const float* lngc = bc + 1024 + l*256;
  const float* lnbc = bc + 1536 + l*256;
  const float* mb1c = bc + 2048 + l*256;
  const float* mb2c = bc + 2560 + l*256;

  for (int i = t; i < NR*64; i += 1024) {
    const int row = i >> 6, d0 = (i & 63) * 4;
    stage_split4(aF, row, d0, *(const float4*)&gl[row*256 + d0]);
  }
  if (ADAPT && fl) {
    for (int c = t; c < NR*128; c += 1024) {
      const int row = c >> 7, dp = c & 127;
      const unsigned u = ((const unsigned*)xin)[(size_t)(row0 + row)*128 + dp];
      bufB[row*260 + dp*2]     = __uint_as_float(u << 16);
      bufB[row*260 + dp*2 + 1] = __uint_as_float(u & 0xffff0000u);
    }
  } else {
    for (int c = t; c < NR*64; c += 1024) {
      const int row = c >> 6, d0 = (c & 63) * 4;
      *(float4*)&bufB[row*260 + d0] = *(const float4*)((const float*)xin + (size_t)(row0 + row)*256 + d0);
    }
  }
  __syncthreads();
  float xtr[4];
  #pragma unroll
  for (int r = 0; r < 4; ++r) xtr[r] = bufB[(quad*4 + r)*260 + cn];
  __syncthreads();

  f32x4 acc = k4_gemm16(aF, wg, w, l64);       // GEMM1
  #pragma unroll
  for (int r = 0; r < 4; ++r)
    bufB[(quad*4 + r)*260 + cn] = acc[r] + rb2c[cn] + xtr[r];
  __syncthreads();
  {                                            // LN stats
    const int row = t >> 5, part = t & 31;
    if (row < NR) {
      float s = 0.f, s2 = 0.f;
      #pragma unroll
      for (int kk = 0; kk < 8; ++kk) {
        const float v = bufB[row*260 + part + kk*32];
        s += v; s2 = fmaf(v, v, s2);
      }
      #pragma unroll
      for (int off = 16; off; off >>= 1) {
        s  += __shfl_xor(s, off, 32);
        s2 += __shfl_xor(s2, off, 32);
      }
      if (part == 0) {
        const float mu = s * (1.f/256.f);
        mv[row][0] = mu;
        mv[row][1] = rsqrtf(fmaf(-mu, mu, s2 * (1.f/256.f)) + 1e-5f);
      }
    }
  }
  __syncthreads();
  for (int i = t; i < NR*64; i += 1024) {      // LN apply + restage
    const int row = i >> 6, d0 = (i & 63) * 4;
    float4 v = *(const float4*)&bufB[row*260 + d0];
    const float m = mv[row][0], iv = mv[row][1];
    v.x = (v.x - m)*iv*lngc[d0]   + lnbc[d0];
    v.y = (v.y - m)*iv*lngc[d0+1] + lnbc[d0+1];
    v.z = (v.z - m)*iv*lngc[d0+2] + lnbc[d0+2];
    v.w = (v.w - m)*iv*lngc[d0+3] + lnbc[d0+3];
    stage_split4(aF, row, d0, v);
  }
  __syncthreads();
  acc = k4_gemm16(aF, wg + 65536, w, l64);     // GEMM2 + gelu
  #pragma unroll
  for (int r = 0; r < 4; ++r)
    if (quad*4 + r < NR)
      bufB[(quad*4 + r)*260 + cn] = gelu_e(acc[r] + mb1c[cn]);
  __syncthreads();
  for (int i = t; i < NR*64; i += 1024) {      // restage
    const int row = i >> 6, d0 = (i & 63) * 4;
    stage_split4(aF, row, d0, *(const float4*)&bufB[row*260 + d0]);
  }
  __syncthreads();
  acc = k4_gemm16(aF, wg + 2*65536, w, l64);   // GEMM3 + residual
  if (TAIL) {
    #pragma unroll
    for (int r = 0; r < 4; ++r)
      bufB[(quad*4 + r)*260 + cn] = acc[r] + mb2c[cn] + xtr[r];
    __syncthreads();
    for (int i = t; i < NR*64; i += 1024) {    // coalesced x write + restage
      const int row = i >> 6, d0 = (i & 63) * 4;
      const float4 v = *(const float4*)&bufB[row*260 + d0];
      if (writeX) *(float4*)&xout[(size_t)(row0 + row)*256 + d0] = v;
      stage_split4(aF, row, d0, v);
    }
    __syncthreads();
  } else {
    #pragma unroll
    for (int r = 0; r < 4; ++r)
      if (quad*4 + r < NR)
        xout[(size_t)(row0 + quad*4 + r)*256 + cn] = acc[r] + mb2c[cn] + xtr[r];
  }
}

// LDS union layout (77 KB), unchanged from R18.
#define SM_QG    0        // float[2048]  (8192 B)
#define SM_SCP   8192     // float[512]   (2048 B)
#define SM_ALS   10240    // float[512]   (2048 B)
#define SM_UNION 12288    // attn: Kst u32[64*132] (33792) + Qst u32[64*128] (32768)
#define SM_QST   46080    //      -> end 78848
#define SM_AF    12288    // k4:  ushort[2][4096] (16384)
#define SM_BUFB  28672    //      float[16*260]   (16640)
#define SM_MV    45312    //      float[16][2]    (128) -> end 45440
#define SM_TOTAL 78848

// XCD-aware swizzle (unchanged): batch's 8 row-blocks share bid%8.
__device__ __forceinline__ int swz_row0(int bid) {
  const int xcd = bid & 7, j = bid >> 3;
  const int batch = (j & 3)*8 + xcd;
  const int rsub = j >> 2;
  return batch*64 + rsub*8;
}

// ---------------------------------------------------------------------------
// kA: attn(l0) + layer-0 mix + layer-1 k1; 256 blocks x 8 rows, 1024 thr.
// ---------------------------------------------------------------------------
__global__ __launch_bounds__(1024) void kA_attn_mix_kq(
    const unsigned short* __restrict__ w3b, const unsigned short* __restrict__ wfb,
    const float* __restrict__ bc, const void* __restrict__ X, float* __restrict__ x,
    const float* __restrict__ kq, const float* __restrict__ Pf,
    const unsigned* __restrict__ Qpk,
    float* __restrict__ kq1, float* __restrict__ Pf1, unsigned* __restrict__ Qpk1)
{
  const int fl = block_detect(X);
  __shared__ __align__(16) char sm[SM_TOTAL];
  float* qg  = (float*)(sm + SM_QG);
  float* scp = (float*)(sm + SM_SCP);
  float* als = (float*)(sm + SM_ALS);
  unsigned* Kst = (unsigned*)(sm + SM_UNION);
  unsigned* Qst = (unsigned*)(sm + SM_QST);
  unsigned short (&aF)[2][4096] = *reinterpret_cast<unsigned short (*)[2][4096]>(sm + SM_AF);
  float* bufB = (float*)(sm + SM_BUFB);
  float (&mv)[16][2] = *reinterpret_cast<float (*)[16][2]>(sm + SM_MV);
  const int t = threadIdx.x;
  const int row0 = swz_row0((int)blockIdx.x);
  attn_phase1k<8>(kq, Pf, Qpk, row0, t, qg, scp, als, Kst, Qst);
  k4_core1k<true, true, 8>(qg, X, fl, x, w3b, bc, 0, row0, t, true, aF, bufB, mv);
  k1_body16<true, 8>(aF, wfb, bc, kq1, Pf1, Qpk1, 1, row0, t);
}

// ---------------------------------------------------------------------------
// kB: attn(l1) + layer-1 mix -> x; 256 blocks x 8 rows, 1024 thr
// ---------------------------------------------------------------------------
__global__ __launch_bounds__(1024) void kB_attn_fin(
    const unsigned short* __restrict__ w3b, const float* __restrict__ bc,
    float* __restrict__ x, const float* __restrict__ kq1,
    const float* __restrict__ Pf1, const unsigned* __restrict__ Qpk1)
{
  __shared__ __align__(16) char sm[SM_TOTAL];
  float* qg  = (float*)(sm + SM_QG);
  float* scp = (float*)(sm + SM_SCP);
  float* als = (float*)(sm + SM_ALS);
  unsigned* Kst = (unsigned*)(sm + SM_UNION);
  unsigned* Qst = (unsigned*)(sm + SM_QST);
  unsigned short (&aF)[2][4096] = *reinterpret_cast<unsigned short (*)[2][4096]>(sm + SM_AF);
  float* bufB = (float*)(sm + SM_BUFB);
  float (&mv)[16][2] = *reinterpret_cast<float (*)[16][2]>(sm + SM_MV);
  const int t = threadIdx.x;
  const int row0 = swz_row0((int)blockIdx.x);
  attn_phase1k<8>(kq1, Pf1, Qpk1, row0, t, qg, scp, als, Kst, Qst);
  k4_core1k<false, false, 8>(qg, x, 0, x, w3b + 3*65536, bc, 1, row0, t, true, aF, bufB, mv);
}

// ---------------------------------------------------------------------------
// k5: s=sum_K x ; h=gelu(s@projT+pb) ; mu=h@muT+mb ; scale=softplus(h@spT+sb)
// [unchanged]
// ---------------------------------------------------------------------------
__global__ __launch_bounds__(256) void k5_head(
    const float* __restrict__ x, const float* __restrict__ wh,
    const float* __restrict__ bc, const void* __restrict__ X,
    void* __restrict__ out)
{
  const int fl = block_detect(X);
  __shared__ float ss[256];
  __shared__ float hh[128];
  const int b = blockIdx.x, t = threadIdx.x;
  {
    const float* xp = x + (size_t)(b << 6)*256 + t;
    float s0 = 0.f, s1 = 0.f, s2 = 0.f, s3 = 0.f;
    for (int i = 0; i < 64; i += 4) {
      s0 += xp[(size_t)(i    )*256];
      s1 += xp[(size_t)(i + 1)*256];
      s2 += xp[(size_t)(i + 2)*256];
      s3 += xp[(size_t)(i + 3)*256];
    }
    ss[t] = (s0 + s1) + (s2 + s3);
  }
  __syncthreads();
  if (t < 128) {
    float acc = bc[3072 + t];
    const float* projT = wh;
    for (int d = 0; d < 256; ++d) acc = fmaf(ss[d], projT[d*128 + t], acc);
    hh[t] = gelu_e(acc);
  }
  __syncthreads();
  float v; int oidx;
  if (t < 128) {
    float acc = bc[3200 + t];
    const float* muT = wh + 32768;
    for (int c = 0; c < 128; ++c) acc = fmaf(hh[c], muT[c*128 + t], acc);
    v = acc; oidx = b*128 + t;
  } else {
    const int u = t - 128;
    float acc = bc[3328 + u];
    const float* spT = wh + 49152;
    for (int c = 0; c < 128; ++c) acc = fmaf(hh[c], spT[c*128 + u], acc);
    v = (acc > 20.f) ? acc : log1pf(__expf(acc));
    oidx = 4096 + b*128 + u;
  }
  if (fl) ((bf16*)out)[oidx] = __float2bfloat16(v);
  else    ((float*)out)[oidx] = v;
}

// ---------------------------------------------------------------------------
extern "C" void kernel_launch(void* const* d_in, const int* in_sizes, int n_in,
                              void* d_out, int out_size, void* d_ws, size_t ws_size,
                              hipStream_t stream)
{
  (void)in_sizes; (void)n_in; (void)out_size; (void)ws_size;
  float* ws    = (float*)d_ws;
  float* x     = ws + 16;                          // 524288
  float* kq    = x + 524288;                       // 1048576  (layer 0)
  float* Pf    = kq + 1048576;                     // 524288   (layer 0)
  unsigned* Qpk = (unsigned*)(Pf + 524288);        // 262144   (layer 0)
  float* g     = (float*)(Qpk + 262144);           // 524288   (unused)
  unsigned short* wfb = (unsigned short*)(g + 524288);   // 524288 shorts
  unsigned short* w3b = wfb + 524288;              // 393216 shorts
  float* wh    = (float*)(w3b + 393216);           // 65536
  float* bc    = wh + 65536;                       // 3456
  float* kq1   = bc + 4096;                        // 1048576  (layer 1)
  float* Pf1   = kq1 + 1048576;                    // 524288   (layer 1)
  unsigned* Qpk1 = (unsigned*)(Pf1 + 524288);      // 262144   (layer 1)

  prep_kernel<<<dim3(89), dim3(256), 0, stream>>>(
      d_in[0], d_in[1], d_in[2], d_in[3], d_in[5], d_in[9], d_in[11],
      d_in[13], d_in[15], d_in[17],
      d_in[4], d_in[6], d_in[7], d_in[8], d_in[10], d_in[12],
      d_in[14], d_in[16], d_in[18],
      wfb, w3b, wh, bc);
  k1l0<<<dim3(512), dim3(256), 0, stream>>>(d_in[0], wfb, bc, kq, Pf, Qpk);
  kA_attn_mix_kq<<<dim3(256), dim3(1024), 0, stream>>>(
      w3b, wfb, bc, d_in[0], x, kq, Pf, Qpk, kq1, Pf1, Qpk1);
  kB_attn_fin<<<dim3(256), dim3(1024), 0, stream>>>(w3b, bc, x, kq1, Pf1, Qpk1);
  k5_head<<<dim3(32), dim3(256), 0, stream>>>(x, wh, bc, d_in[0], (void*)d_out);
}